// Round 1
// baseline (2309.104 us; speedup 1.0000x reference)
//
#include <hip/hip_runtime.h>
#include <math.h>

#define NN 10000
#define NE 160000
#define NB 128
#define NH 4
#define DOUT 512
#define NEG 0.2f

__device__ __forceinline__ float leakyf(float v){ return v > 0.f ? v : NEG*v; }

__device__ __forceinline__ void atomicMaxF(float* addr, float val){
  int* ia = (int*)addr;
  int old = *ia;
  while (__int_as_float(old) < val) {
    int assumed = old;
    old = atomicCAS(ia, assumed, __float_as_int(val));
    if (old == assumed) break;
  }
}

// ---------------- degree ----------------
__global__ void k_deg(const int* __restrict__ dst, float* __restrict__ deg){
  int e = blockIdx.x*blockDim.x + threadIdx.x;
  if (e < NE) atomicAdd(&deg[dst[e]], 1.f);
}
__global__ void k_dinv(float* __restrict__ deg){
  int n = blockIdx.x*blockDim.x + threadIdx.x;
  if (n < NN) deg[n] = 1.f / sqrtf(deg[n] + 1.f);
}

// ---------------- generic tiled GEMM: C[N,M] = A[N,K] @ B[K,M] ----------------
#define TS 16
__global__ void k_gemm(const float* __restrict__ A, const float* __restrict__ B,
                       float* __restrict__ C, int N, int K, int M){
  __shared__ float As[TS][TS];
  __shared__ float Bs[TS][TS+1];
  int tx = threadIdx.x, ty = threadIdx.y;
  int row = blockIdx.y*TS + ty;
  int col = blockIdx.x*TS + tx;
  float acc = 0.f;
  for (int k0 = 0; k0 < K; k0 += TS){
    As[ty][tx] = (row < N && (k0+tx) < K) ? A[(size_t)row*K + k0 + tx] : 0.f;
    Bs[ty][tx] = ((k0+ty) < K && col < M) ? B[(size_t)(k0+ty)*M + col] : 0.f;
    __syncthreads();
#pragma unroll
    for (int kk = 0; kk < TS; kk++) acc += As[ty][kk]*Bs[kk][tx];
    __syncthreads();
  }
  if (row < N && col < M) C[(size_t)row*M + col] = acc;
}

// ---------------- GCN ----------------
// agg init: self-loop message + bias
__global__ void k_gcn_init(const float* __restrict__ hw, const float* __restrict__ dinv,
                           const float* __restrict__ b, float* __restrict__ agg, int M){
  int idx = blockIdx.x*blockDim.x + threadIdx.x;
  if (idx >= NN*M) return;
  int n = idx / M, m = idx % M;
  float di = dinv[n];
  agg[idx] = hw[idx]*di*di + b[m];
}
// one block per edge, threads over feature dim
__global__ void k_gcn_scatter(const float* __restrict__ hw, const float* __restrict__ dinv,
                              const int* __restrict__ src, const int* __restrict__ dst,
                              float* __restrict__ agg, int M){
  int e = blockIdx.x, m = threadIdx.x;
  int s = src[e], d = dst[e];
  float w = dinv[s]*dinv[d];
  atomicAdd(&agg[(size_t)d*M + m], hw[(size_t)s*M + m]*w);
}
__global__ void k_relu(float* __restrict__ a, int n){
  int i = blockIdx.x*blockDim.x + threadIdx.x;
  if (i < n) a[i] = fmaxf(a[i], 0.f);
}

// ---------------- GAT ----------------
// per (node, head): alpha_src/alpha_dst dot products; init segment-max with self-loop logit
__global__ void k_gat_alpha(const float* __restrict__ hg, const float* __restrict__ a_s,
                            const float* __restrict__ a_d, float* __restrict__ as_,
                            float* __restrict__ ad_, float* __restrict__ mmax, int M, int C){
  int idx = blockIdx.x*blockDim.x + threadIdx.x;
  if (idx >= NN*NH) return;
  int n = idx / NH, hd = idx % NH;
  float ss = 0.f, dd = 0.f;
  const float* row = hg + (size_t)n*M + hd*C;
  const float* ws = a_s + hd*C;
  const float* wd = a_d + hd*C;
  for (int c = 0; c < C; c++){ float v = row[c]; ss += v*ws[c]; dd += v*wd[c]; }
  as_[idx] = ss; ad_[idx] = dd;
  mmax[idx] = leakyf(ss + dd);   // self-loop logit
}
__global__ void k_gat_max(const int* __restrict__ src, const int* __restrict__ dst,
                          const float* __restrict__ as_, const float* __restrict__ ad_,
                          float* __restrict__ mmax){
  int gid = blockIdx.x*blockDim.x + threadIdx.x;
  if (gid >= NE*NH) return;
  int e = gid / NH, hd = gid % NH;
  int s = src[e], d = dst[e];
  atomicMaxF(&mmax[d*NH + hd], leakyf(as_[s*NH + hd] + ad_[d*NH + hd]));
}
__global__ void k_gat_den_init(const float* __restrict__ as_, const float* __restrict__ ad_,
                               const float* __restrict__ mmax, float* __restrict__ den){
  int idx = blockIdx.x*blockDim.x + threadIdx.x;
  if (idx >= NN*NH) return;
  den[idx] = expf(leakyf(as_[idx] + ad_[idx]) - mmax[idx]);   // self-loop term
}
__global__ void k_gat_den(const int* __restrict__ src, const int* __restrict__ dst,
                          const float* __restrict__ as_, const float* __restrict__ ad_,
                          const float* __restrict__ mmax, float* __restrict__ den){
  int gid = blockIdx.x*blockDim.x + threadIdx.x;
  if (gid >= NE*NH) return;
  int e = gid / NH, hd = gid % NH;
  int s = src[e], d = dst[e];
  int ai = d*NH + hd;
  atomicAdd(&den[ai], expf(leakyf(as_[s*NH + hd] + ad_[ai]) - mmax[ai]));
}
// xout = hg*alpha_self + h (residual h + gat) + bias
__global__ void k_gat_out_init(const float* __restrict__ hg, const float* __restrict__ h,
                               const float* __restrict__ as_, const float* __restrict__ ad_,
                               const float* __restrict__ mmax, const float* __restrict__ den,
                               const float* __restrict__ bias, float* __restrict__ xout,
                               int M, int C){
  int idx = blockIdx.x*blockDim.x + threadIdx.x;
  if (idx >= NN*M) return;
  int n = idx / M, m = idx % M, hd = m / C;
  int ai = n*NH + hd;
  float alpha = expf(leakyf(as_[ai] + ad_[ai]) - mmax[ai]) / den[ai];
  xout[idx] = hg[idx]*alpha + h[idx] + bias[m];
}
__global__ void k_gat_out_scatter(const float* __restrict__ hg,
                                  const int* __restrict__ src, const int* __restrict__ dst,
                                  const float* __restrict__ as_, const float* __restrict__ ad_,
                                  const float* __restrict__ mmax, const float* __restrict__ den,
                                  float* __restrict__ xout, int M, int C){
  int e = blockIdx.x, m = threadIdx.x, hd = m / C;
  int s = src[e], d = dst[e];
  int ai = d*NH + hd;
  float alpha = expf(leakyf(as_[s*NH + hd] + ad_[ai]) - mmax[ai]) / den[ai];
  atomicAdd(&xout[(size_t)d*M + m], hg[(size_t)s*M + m]*alpha);
}

// ---------------- attention pooling ----------------
// apre[n] = tanh(t1[n,:] + b1) . w2 + b2   (t1 = x @ ap_w1, 256 cols)
__global__ void k_tanh_dot(const float* __restrict__ t1, const float* __restrict__ b1,
                           const float* __restrict__ w2, const float* __restrict__ b2,
                           float* __restrict__ apre){
  __shared__ float sred[256];
  int n = blockIdx.x, c = threadIdx.x;
  float v = tanhf(t1[(size_t)n*256 + c] + b1[c]) * w2[c];
  sred[c] = v; __syncthreads();
  for (int o = 128; o > 0; o >>= 1){
    if (c < o) sred[c] += sred[c + o];
    __syncthreads();
  }
  if (c == 0) apre[n] = sred[0] + b2[0];
}
__global__ void k_init_pool(float* __restrict__ smax, float* __restrict__ red){
  int idx = blockIdx.x*blockDim.x + threadIdx.x;
  if (idx < NB*DOUT) smax[idx] = -INFINITY;
  if (idx == 0){ red[0] = -INFINITY; red[1] = 0.f; }
}
__global__ void k_gmax(const float* __restrict__ apre, float* __restrict__ red){
  int n = blockIdx.x*blockDim.x + threadIdx.x;
  if (n < NN) atomicMaxF(&red[0], apre[n]);
}
__global__ void k_gsum(const float* __restrict__ apre, float* __restrict__ red){
  int n = blockIdx.x*blockDim.x + threadIdx.x;
  if (n < NN) atomicAdd(&red[1], expf(apre[n] - red[0]));
}
// p = global softmax value; per-graph denom + node counts
__global__ void k_gdenom(float* __restrict__ apre, const int* __restrict__ batch,
                         const float* __restrict__ red, float* __restrict__ dg,
                         float* __restrict__ cnt){
  int n = blockIdx.x*blockDim.x + threadIdx.x;
  if (n >= NN) return;
  float p = expf(apre[n] - red[0]) / red[1];
  apre[n] = p;
  atomicAdd(&dg[batch[n]], p);
  atomicAdd(&cnt[batch[n]], 1.f);
}
__global__ void k_pool_scatter(const float* __restrict__ x, const float* __restrict__ apre,
                               const int* __restrict__ batch, const float* __restrict__ dg,
                               float* __restrict__ ssum, float* __restrict__ smax,
                               float* __restrict__ gemb){
  int n = blockIdx.x, d = threadIdx.x;
  int g = batch[n];
  float xv = x[(size_t)n*DOUT + d];
  atomicAdd(&ssum[g*DOUT + d], xv);
  atomicMaxF(&smax[g*DOUT + d], xv);
  float w = apre[n] / (dg[g] + 1e-8f);
  atomicAdd(&gemb[g*DOUT + d], w*xv);
}
__global__ void k_final(const float* __restrict__ gemb, const float* __restrict__ ssum,
                        const float* __restrict__ smax, const float* __restrict__ cnt,
                        float* __restrict__ out){
  int idx = blockIdx.x*blockDim.x + threadIdx.x;
  if (idx >= NB*DOUT) return;
  int g = idx / DOUT, d = idx % DOUT;
  float sv = ssum[idx];
  float* o = out + (size_t)g*4*DOUT;
  o[d]            = gemb[idx];
  o[DOUT + d]     = sv / fmaxf(cnt[g], 1.f);
  o[2*DOUT + d]   = smax[idx];
  o[3*DOUT + d]   = sv;
}

extern "C" void kernel_launch(void* const* d_in, const int* in_sizes, int n_in,
                              void* d_out, int out_size, void* d_ws, size_t ws_size,
                              hipStream_t stream) {
  const float* x0   = (const float*)d_in[0];
  const int*   ei   = (const int*)d_in[1];
  const int*   src  = ei;
  const int*   dst  = ei + NE;
  const int*   batch= (const int*)d_in[2];
  const float* gw[3]  = {(const float*)d_in[3],  (const float*)d_in[9],  (const float*)d_in[15]};
  const float* gb[3]  = {(const float*)d_in[4],  (const float*)d_in[10], (const float*)d_in[16]};
  const float* aw[3]  = {(const float*)d_in[5],  (const float*)d_in[11], (const float*)d_in[17]};
  const float* asw[3] = {(const float*)d_in[6],  (const float*)d_in[12], (const float*)d_in[18]};
  const float* adw[3] = {(const float*)d_in[7],  (const float*)d_in[13], (const float*)d_in[19]};
  const float* ab[3]  = {(const float*)d_in[8],  (const float*)d_in[14], (const float*)d_in[20]};
  const float* apw1 = (const float*)d_in[21];
  const float* apb1 = (const float*)d_in[22];
  const float* apw2 = (const float*)d_in[23];
  const float* apb2 = (const float*)d_in[24];
  float* out = (float*)d_out;

  // ---- workspace layout (floats) ----
  float* f0   = (float*)d_ws;                 // h (relu gcn out)          [NN*512]
  float* f1   = f0 + (size_t)NN*512;          // gemm out (hw / hg / t1)   [NN*512]
  float* f2   = f1 + (size_t)NN*512;          // x_cur / x_next            [NN*512]
  float* dinv = f2 + (size_t)NN*512;          // [NN]
  float* as_  = dinv + NN;                    // [NN*NH]
  float* ad_  = as_ + NN*NH;                  // [NN*NH]
  float* mmax = ad_ + NN*NH;                  // [NN*NH]
  float* den  = mmax + NN*NH;                 // [NN*NH]
  float* apre = den + NN*NH;                  // [NN]
  float* red  = apre + NN;                    // [2] global max, sum
  float* dg   = red + 2;                      // [NB]
  float* cnt  = dg + NB;                      // [NB]
  float* ssum = cnt + NB;                     // [NB*512]
  float* smax = ssum + (size_t)NB*512;        // [NB*512]
  float* gemb = smax + (size_t)NB*512;        // [NB*512]

  // degrees (in-degree over dst, +1 self-loop)
  hipMemsetAsync(dinv, 0, NN*sizeof(float), stream);
  k_deg<<<(NE+255)/256, 256, 0, stream>>>(dst, dinv);
  k_dinv<<<(NN+255)/256, 256, 0, stream>>>(dinv);

  const int dims[4] = {36, 128, 256, 512};
  const float* xcur = x0;
  for (int i = 0; i < 3; i++){
    int K = dims[i], M = dims[i+1], C = M/NH;
    dim3 gg((M+TS-1)/TS, (NN+TS-1)/TS);
    // GCN: hw = x @ gw
    k_gemm<<<gg, dim3(TS,TS), 0, stream>>>(xcur, gw[i], f1, NN, K, M);
    k_gcn_init<<<(NN*M+255)/256, 256, 0, stream>>>(f1, dinv, gb[i], f0, M);
    k_gcn_scatter<<<NE, M, 0, stream>>>(f1, dinv, src, dst, f0, M);
    k_relu<<<(NN*M+255)/256, 256, 0, stream>>>(f0, NN*M);
    // GAT: hg = h @ aw  (note residual x = h + gat; x_in residual never fires for these dims)
    k_gemm<<<gg, dim3(TS,TS), 0, stream>>>(f0, aw[i], f1, NN, M, M);
    k_gat_alpha<<<(NN*NH+255)/256, 256, 0, stream>>>(f1, asw[i], adw[i], as_, ad_, mmax, M, C);
    k_gat_max<<<(NE*NH+255)/256, 256, 0, stream>>>(src, dst, as_, ad_, mmax);
    k_gat_den_init<<<(NN*NH+255)/256, 256, 0, stream>>>(as_, ad_, mmax, den);
    k_gat_den<<<(NE*NH+255)/256, 256, 0, stream>>>(src, dst, as_, ad_, mmax, den);
    k_gat_out_init<<<(NN*M+255)/256, 256, 0, stream>>>(f1, f0, as_, ad_, mmax, den, ab[i], f2, M, C);
    k_gat_out_scatter<<<NE, M, 0, stream>>>(f1, src, dst, as_, ad_, mmax, den, f2, M, C);
    xcur = f2;
  }

  // attention pooling + segment stats
  k_gemm<<<dim3(256/TS, (NN+TS-1)/TS), dim3(TS,TS), 0, stream>>>(f2, apw1, f1, NN, 512, 256);
  k_tanh_dot<<<NN, 256, 0, stream>>>(f1, apb1, apw2, apb2, apre);

  hipMemsetAsync(dg, 0, (2*NB + NB*512)*sizeof(float), stream);   // dg, cnt, ssum
  hipMemsetAsync(gemb, 0, (size_t)NB*512*sizeof(float), stream);
  k_init_pool<<<(NB*DOUT+255)/256, 256, 0, stream>>>(smax, red);
  k_gmax<<<(NN+255)/256, 256, 0, stream>>>(apre, red);
  k_gsum<<<(NN+255)/256, 256, 0, stream>>>(apre, red);
  k_gdenom<<<(NN+255)/256, 256, 0, stream>>>(apre, batch, red, dg, cnt);
  k_pool_scatter<<<NN, DOUT, 0, stream>>>(f2, apre, batch, dg, ssum, smax, gemb);
  k_final<<<(NB*DOUT+255)/256, 256, 0, stream>>>(gemb, ssum, smax, cnt, out);
}

// Round 2
// 973.247 us; speedup vs baseline: 2.3726x; 2.3726x over previous
//
#include <hip/hip_runtime.h>
#include <math.h>

#define NN 10000
#define NE 160000
#define NB 128
#define NH 4
#define DOUT 512
#define NEG 0.2f

__device__ __forceinline__ float leakyf(float v){ return v > 0.f ? v : NEG*v; }

__device__ __forceinline__ void atomicMaxF(float* addr, float val){
  int* ia = (int*)addr;
  int old = *ia;
  while (__int_as_float(old) < val) {
    int assumed = old;
    old = atomicCAS(ia, assumed, __float_as_int(val));
    if (old == assumed) break;
  }
}

// ================= CSR build =================
__global__ void k_count(const int* __restrict__ dst, int* __restrict__ cnt){
  int e = blockIdx.x*blockDim.x + threadIdx.x;
  if (e < NE) atomicAdd(&cnt[dst[e]], 1);
}
__global__ void k_dinv(const int* __restrict__ cnt, float* __restrict__ dinv){
  int n = blockIdx.x*blockDim.x + threadIdx.x;
  if (n < NN) dinv[n] = rsqrtf((float)cnt[n] + 1.f);
}
// exclusive scan of cnt[NN] -> rowptr[NN+1], single block of 256
__global__ void k_scan(const int* __restrict__ cnt, int* __restrict__ rowptr){
  __shared__ int part[256];
  const int CH = (NN + 255) / 256;   // 40
  int t = threadIdx.x;
  int base = t * CH;
  int s = 0;
  for (int i = 0; i < CH; i++){ int idx = base + i; if (idx < NN) s += cnt[idx]; }
  part[t] = s; __syncthreads();
  for (int o = 1; o < 256; o <<= 1){
    int v = 0;
    if (t >= o) v = part[t - o];
    __syncthreads();
    if (t >= o) part[t] += v;
    __syncthreads();
  }
  int pre = (t == 0) ? 0 : part[t - 1];
  for (int i = 0; i < CH; i++){
    int idx = base + i;
    if (idx < NN){ rowptr[idx] = pre; pre += cnt[idx]; }
  }
  if (t == 255) rowptr[NN] = part[255];
}
__global__ void k_fill(const int* __restrict__ src, const int* __restrict__ dst,
                       const int* __restrict__ rowptr, int* __restrict__ cursor,
                       int* __restrict__ colidx){
  int e = blockIdx.x*blockDim.x + threadIdx.x;
  if (e >= NE) return;
  int d = dst[e];
  int pos = atomicAdd(&cursor[d], 1);
  colidx[rowptr[d] + pos] = src[e];
}

// ================= GEMM: C[N,M] = A[N,K] @ B[K,M] =================
// 64x64 tile, 4x4 micro-tile, 256 threads. M must be multiple of 64.
#define BM 64
#define BN 64
#define BK 16
__global__ __launch_bounds__(256) void k_gemm(const float* __restrict__ A,
                                              const float* __restrict__ B,
                                              float* __restrict__ C,
                                              int N, int K, int M){
  __shared__ float As[BK][BM+4];   // k-major (transposed)
  __shared__ float Bs[BK][BN+4];
  int t  = threadIdx.x;
  int tx = t & 15, ty = t >> 4;
  int row0 = blockIdx.y * BM;
  int col0 = blockIdx.x * BN;
  // A staging indices
  int am = t >> 2;            // 0..63
  int ak = (t & 3) * 4;       // 0,4,8,12
  // B staging indices
  int bk = t >> 4;            // 0..15
  int bn = (t & 15) * 4;
  float acc[4][4];
#pragma unroll
  for (int i = 0; i < 4; i++)
#pragma unroll
    for (int j = 0; j < 4; j++) acc[i][j] = 0.f;

  for (int k0 = 0; k0 < K; k0 += BK){
    float4 av = make_float4(0.f,0.f,0.f,0.f);
    int arow = row0 + am;
    if (arow < N){
      if (k0 + ak + 3 < K){
        av = *(const float4*)&A[(size_t)arow*K + k0 + ak];
      } else {
        float* avp = (float*)&av;
        for (int i = 0; i < 4; i++)
          if (k0 + ak + i < K) avp[i] = A[(size_t)arow*K + k0 + ak + i];
      }
    }
    As[ak+0][am] = av.x; As[ak+1][am] = av.y;
    As[ak+2][am] = av.z; As[ak+3][am] = av.w;

    float4 bv = make_float4(0.f,0.f,0.f,0.f);
    if (k0 + bk < K) bv = *(const float4*)&B[(size_t)(k0+bk)*M + col0 + bn];
    *(float4*)&Bs[bk][bn] = bv;
    __syncthreads();

#pragma unroll
    for (int kk = 0; kk < BK; kk++){
      float4 a4 = *(const float4*)&As[kk][ty*4];
      float4 b4 = *(const float4*)&Bs[kk][tx*4];
      const float* ap = (const float*)&a4;
      const float* bp = (const float*)&b4;
#pragma unroll
      for (int i = 0; i < 4; i++)
#pragma unroll
        for (int j = 0; j < 4; j++) acc[i][j] += ap[i]*bp[j];
    }
    __syncthreads();
  }
#pragma unroll
  for (int i = 0; i < 4; i++){
    int r = row0 + ty*4 + i;
    if (r < N){
      float4 o; float* op = (float*)&o;
#pragma unroll
      for (int j = 0; j < 4; j++) op[j] = acc[i][j];
      *(float4*)&C[(size_t)r*M + col0 + tx*4] = o;
    }
  }
}

// ================= GCN gather (fused self + bias + relu) =================
__global__ void k_gcn_gather(const float* __restrict__ hw, const float* __restrict__ dinv,
                             const int* __restrict__ rowptr, const int* __restrict__ colidx,
                             const float* __restrict__ gb, float* __restrict__ h, int M){
  int n = blockIdx.x;
  int b = rowptr[n], e = rowptr[n+1];
  float dn = dinv[n];
  int f0i = threadIdx.x, f1i = threadIdx.x + 256;
  float acc0 = 0.f, acc1 = 0.f;
  for (int j = b; j < e; j++){
    int s = colidx[j];
    float w = dinv[s]*dn;
    const float* row = hw + (size_t)s*M;
    if (f0i < M) acc0 += row[f0i]*w;
    if (f1i < M) acc1 += row[f1i]*w;
  }
  const float* self = hw + (size_t)n*M;
  float dn2 = dn*dn;
  if (f0i < M) h[(size_t)n*M + f0i] = fmaxf(acc0 + self[f0i]*dn2 + gb[f0i], 0.f);
  if (f1i < M) h[(size_t)n*M + f1i] = fmaxf(acc1 + self[f1i]*dn2 + gb[f1i], 0.f);
}

// ================= GAT =================
__global__ void k_gat_alpha(const float* __restrict__ hg, const float* __restrict__ a_s,
                            const float* __restrict__ a_d, float* __restrict__ as_,
                            float* __restrict__ ad_, int M, int C){
  int idx = blockIdx.x*blockDim.x + threadIdx.x;
  if (idx >= NN*NH) return;
  int n = idx >> 2, hd = idx & 3;
  float ss = 0.f, dd = 0.f;
  const float* row = hg + (size_t)n*M + hd*C;
  const float* ws = a_s + hd*C;
  const float* wd = a_d + hd*C;
  for (int c = 0; c < C; c++){ float v = row[c]; ss += v*ws[c]; dd += v*wd[c]; }
  as_[idx] = ss; ad_[idx] = dd;
}
// per (node, head): segment max, exp-sum, per-edge unnormalized alpha (CSR order)
__global__ void k_gat_maxden(const int* __restrict__ rowptr, const int* __restrict__ colidx,
                             const float* __restrict__ as_, const float* __restrict__ ad_,
                             float* __restrict__ eself, float* __restrict__ den,
                             float* __restrict__ ealpha){
  int idx = blockIdx.x*blockDim.x + threadIdx.x;
  if (idx >= NN*NH) return;
  int n = idx >> 2, hd = idx & 3;
  float adn = ad_[idx];
  float selflog = leakyf(as_[idx] + adn);
  float m = selflog;
  int b = rowptr[n], e = rowptr[n+1];
  for (int j = b; j < e; j++){
    int s = colidx[j];
    m = fmaxf(m, leakyf(as_[s*NH + hd] + adn));
  }
  float es = expf(selflog - m);
  float dsum = es;
  for (int j = b; j < e; j++){
    int s = colidx[j];
    float v = expf(leakyf(as_[s*NH + hd] + adn) - m);
    ealpha[(size_t)j*NH + hd] = v;
    dsum += v;
  }
  eself[idx] = es;
  den[idx] = dsum;
}
// fused: x = h + bias + (hg_self*eself + sum_edges hg_src*ealpha)/den
__global__ void k_gat_gather(const float* __restrict__ hg, const float* __restrict__ h,
                             const int* __restrict__ rowptr, const int* __restrict__ colidx,
                             const float* __restrict__ ealpha, const float* __restrict__ eself,
                             const float* __restrict__ den, const float* __restrict__ ab,
                             float* __restrict__ xout, int M, int C){
  int n = blockIdx.x;
  int b = rowptr[n], e = rowptr[n+1];
  int f0i = threadIdx.x, f1i = threadIdx.x + 256;
  int h0 = (f0i < M) ? f0i / C : 0;
  int h1 = (f1i < M) ? f1i / C : 0;
  float acc0 = 0.f, acc1 = 0.f;
  for (int j = b; j < e; j++){
    int s = colidx[j];
    const float* row = hg + (size_t)s*M;
    const float* ea = ealpha + (size_t)j*NH;
    if (f0i < M) acc0 += row[f0i]*ea[h0];
    if (f1i < M) acc1 += row[f1i]*ea[h1];
  }
  const float* self = hg + (size_t)n*M;
  const float* hrow = h + (size_t)n*M;
  if (f0i < M){
    int ai = n*NH + h0;
    xout[(size_t)n*M + f0i] = hrow[f0i] + ab[f0i] + (self[f0i]*eself[ai] + acc0)/den[ai];
  }
  if (f1i < M){
    int ai = n*NH + h1;
    xout[(size_t)n*M + f1i] = hrow[f1i] + ab[f1i] + (self[f1i]*eself[ai] + acc1)/den[ai];
  }
}

// ================= attention pooling =================
__global__ void k_tanh_dot(const float* __restrict__ t1, const float* __restrict__ b1,
                           const float* __restrict__ w2, const float* __restrict__ b2,
                           float* __restrict__ apre){
  __shared__ float sred[256];
  int n = blockIdx.x, c = threadIdx.x;
  float v = tanhf(t1[(size_t)n*256 + c] + b1[c]) * w2[c];
  sred[c] = v; __syncthreads();
  for (int o = 128; o > 0; o >>= 1){
    if (c < o) sred[c] += sred[c + o];
    __syncthreads();
  }
  if (c == 0) apre[n] = sred[0] + b2[0];
}
__global__ void k_red_init(float* __restrict__ red){ red[0] = -INFINITY; }
__global__ void k_gmax(const float* __restrict__ apre, float* __restrict__ red){
  int n = blockIdx.x*blockDim.x + threadIdx.x;
  if (n < NN) atomicMaxF(&red[0], apre[n]);
}
__global__ void k_starts_init(int* __restrict__ starts){
  int g = threadIdx.x;
  if (g <= NB) starts[g] = NN;
}
__global__ void k_starts_min(const int* __restrict__ batch, int* __restrict__ starts){
  int n = blockIdx.x*blockDim.x + threadIdx.x;
  if (n < NN) atomicMin(&starts[batch[n]], n);
}
__global__ void k_starts_fix(int* __restrict__ starts){
  starts[NB] = NN;
  for (int g = NB-1; g >= 0; g--) starts[g] = min(starts[g], starts[g+1]);
}
// per-graph gather over contiguous [starts[g], starts[g+1]) node range
__global__ void k_pool(const float* __restrict__ x, const float* __restrict__ apre,
                       const float* __restrict__ red, const int* __restrict__ starts,
                       float* __restrict__ out){
  int g = blockIdx.x;
  int f = threadIdx.x + blockIdx.y*256;   // 0..511
  int b = starts[g], e = starts[g+1];
  float gm = red[0];
  float sum = 0.f, mx = -INFINITY, wacc = 0.f, psum = 0.f;
  for (int n = b; n < e; n++){
    float xv = x[(size_t)n*DOUT + f];
    float p = expf(apre[n] - gm);
    sum += xv; mx = fmaxf(mx, xv);
    wacc += p*xv; psum += p;
  }
  float cntf = (float)(e - b);
  float* o = out + (size_t)g*4*DOUT;
  o[f]          = wacc / (psum + 1e-8f);
  o[DOUT + f]   = sum / fmaxf(cntf, 1.f);
  o[2*DOUT + f] = mx;
  o[3*DOUT + f] = sum;
}

extern "C" void kernel_launch(void* const* d_in, const int* in_sizes, int n_in,
                              void* d_out, int out_size, void* d_ws, size_t ws_size,
                              hipStream_t stream) {
  const float* x0   = (const float*)d_in[0];
  const int*   ei   = (const int*)d_in[1];
  const int*   src  = ei;
  const int*   dst  = ei + NE;
  const int*   batch= (const int*)d_in[2];
  const float* gw[3]  = {(const float*)d_in[3],  (const float*)d_in[9],  (const float*)d_in[15]};
  const float* gb[3]  = {(const float*)d_in[4],  (const float*)d_in[10], (const float*)d_in[16]};
  const float* aw[3]  = {(const float*)d_in[5],  (const float*)d_in[11], (const float*)d_in[17]};
  const float* asw[3] = {(const float*)d_in[6],  (const float*)d_in[12], (const float*)d_in[18]};
  const float* adw[3] = {(const float*)d_in[7],  (const float*)d_in[13], (const float*)d_in[19]};
  const float* ab[3]  = {(const float*)d_in[8],  (const float*)d_in[14], (const float*)d_in[20]};
  const float* apw1 = (const float*)d_in[21];
  const float* apb1 = (const float*)d_in[22];
  const float* apw2 = (const float*)d_in[23];
  const float* apb2 = (const float*)d_in[24];
  float* out = (float*)d_out;

  // ---- workspace layout ----
  float* f0   = (float*)d_ws;                  // h                 [NN*512]
  float* f1   = f0 + (size_t)NN*512;           // gemm out          [NN*512]
  float* f2   = f1 + (size_t)NN*512;           // x                 [NN*512]
  float* ealpha = f2 + (size_t)NN*512;         // [NE*NH]
  float* dinv = ealpha + (size_t)NE*NH;        // [NN]
  float* as_  = dinv + NN;                     // [NN*NH]
  float* ad_  = as_ + NN*NH;                   // [NN*NH]
  float* eself= ad_ + NN*NH;                   // [NN*NH]
  float* den  = eself + NN*NH;                 // [NN*NH]
  float* apre = den + NN*NH;                   // [NN]
  float* red  = apre + NN;                     // [1]
  int* rowptr = (int*)(red + 1);               // [NN+1]
  int* colidx = rowptr + NN + 1;               // [NE]
  int* cnt    = colidx + NE;                   // [NN]
  int* cursor = cnt + NN;                      // [NN]
  int* starts = cursor + NN;                   // [NB+1]

  // ---- CSR build + degrees ----
  hipMemsetAsync(cnt, 0, NN*sizeof(int), stream);
  k_count<<<(NE+255)/256, 256, 0, stream>>>(dst, cnt);
  k_dinv<<<(NN+255)/256, 256, 0, stream>>>(cnt, dinv);
  k_scan<<<1, 256, 0, stream>>>(cnt, rowptr);
  hipMemsetAsync(cursor, 0, NN*sizeof(int), stream);
  k_fill<<<(NE+255)/256, 256, 0, stream>>>(src, dst, rowptr, cursor, colidx);

  const int dims[4] = {36, 128, 256, 512};
  const float* xcur = x0;
  for (int i = 0; i < 3; i++){
    int K = dims[i], M = dims[i+1], C = M/NH;
    dim3 gg(M/BN, (NN+BM-1)/BM);
    // GCN
    k_gemm<<<gg, 256, 0, stream>>>(xcur, gw[i], f1, NN, K, M);
    k_gcn_gather<<<NN, 256, 0, stream>>>(f1, dinv, rowptr, colidx, gb[i], f0, M);
    // GAT
    k_gemm<<<gg, 256, 0, stream>>>(f0, aw[i], f1, NN, M, M);
    k_gat_alpha<<<(NN*NH+255)/256, 256, 0, stream>>>(f1, asw[i], adw[i], as_, ad_, M, C);
    k_gat_maxden<<<(NN*NH+255)/256, 256, 0, stream>>>(rowptr, colidx, as_, ad_, eself, den, ealpha);
    k_gat_gather<<<NN, 256, 0, stream>>>(f1, f0, rowptr, colidx, ealpha, eself, den, ab[i], f2, M, C);
    xcur = f2;
  }

  // ---- pooling ----
  k_gemm<<<dim3(256/BN, (NN+BM-1)/BM), 256, 0, stream>>>(f2, apw1, f1, NN, 512, 256);
  k_tanh_dot<<<NN, 256, 0, stream>>>(f1, apb1, apw2, apb2, apre);
  k_red_init<<<1, 1, 0, stream>>>(red);
  k_gmax<<<(NN+255)/256, 256, 0, stream>>>(apre, red);
  k_starts_init<<<1, 256, 0, stream>>>(starts);
  k_starts_min<<<(NN+255)/256, 256, 0, stream>>>(batch, starts);
  k_starts_fix<<<1, 1, 0, stream>>>(starts);
  k_pool<<<dim3(NB, 2), 256, 0, stream>>>(f2, apre, red, starts, out);
}

// Round 3
// 861.664 us; speedup vs baseline: 2.6798x; 1.1295x over previous
//
#include <hip/hip_runtime.h>
#include <math.h>

#define NN 10000
#define NE 160000
#define NB 128
#define NH 4
#define DOUT 512
#define NEG 0.2f

__device__ __forceinline__ float leakyf(float v){ return v > 0.f ? v : NEG*v; }

// ================= CSR build =================
__global__ void k_count(const int* __restrict__ dst, int* __restrict__ cnt){
  int e = blockIdx.x*blockDim.x + threadIdx.x;
  if (e < NE) atomicAdd(&cnt[dst[e]], 1);
}
__global__ void k_dinv(const int* __restrict__ cnt, float* __restrict__ dinv){
  int n = blockIdx.x*blockDim.x + threadIdx.x;
  if (n < NN) dinv[n] = rsqrtf((float)cnt[n] + 1.f);
}
// exclusive scan of cnt[NN] -> rowptr[NN+1], single block of 256
__global__ void k_scan(const int* __restrict__ cnt, int* __restrict__ rowptr){
  __shared__ int part[256];
  const int CH = (NN + 255) / 256;   // 40
  int t = threadIdx.x;
  int base = t * CH;
  int s = 0;
  for (int i = 0; i < CH; i++){ int idx = base + i; if (idx < NN) s += cnt[idx]; }
  part[t] = s; __syncthreads();
  for (int o = 1; o < 256; o <<= 1){
    int v = 0;
    if (t >= o) v = part[t - o];
    __syncthreads();
    if (t >= o) part[t] += v;
    __syncthreads();
  }
  int pre = (t == 0) ? 0 : part[t - 1];
  for (int i = 0; i < CH; i++){
    int idx = base + i;
    if (idx < NN){ rowptr[idx] = pre; pre += cnt[idx]; }
  }
  if (t == 255) rowptr[NN] = part[255];
}
__global__ void k_fill(const int* __restrict__ src, const int* __restrict__ dst,
                       const int* __restrict__ rowptr, int* __restrict__ cursor,
                       int* __restrict__ colidx){
  int e = blockIdx.x*blockDim.x + threadIdx.x;
  if (e >= NE) return;
  int d = dst[e];
  int pos = atomicAdd(&cursor[d], 1);
  colidx[rowptr[d] + pos] = src[e];
}

// ================= GEMM: C[N,M] = A[N,K] @ B[K,M] =================
// 128x64 tile, 8x4 micro-tile, 256 threads. M must be multiple of 64.
#define BM 128
#define BN 64
#define BK 16
__global__ __launch_bounds__(256) void k_gemm(const float* __restrict__ A,
                                              const float* __restrict__ B,
                                              float* __restrict__ C,
                                              int N, int K, int M){
  __shared__ float As[BK][BM+4];   // k-major (transposed)
  __shared__ float Bs[BK][BN+4];
  int t  = threadIdx.x;
  int tx = t & 15, ty = t >> 4;
  int row0 = blockIdx.y * BM;
  int col0 = blockIdx.x * BN;
  // A staging: each thread loads 8 consecutive K values for one row
  int am = t >> 1;            // 0..127
  int ak = (t & 1) * 8;       // 0 or 8
  // B staging: each thread loads one float4
  int bk = t >> 4;            // 0..15
  int bn = (t & 15) * 4;
  float acc[8][4];
#pragma unroll
  for (int i = 0; i < 8; i++)
#pragma unroll
    for (int j = 0; j < 4; j++) acc[i][j] = 0.f;

  for (int k0 = 0; k0 < K; k0 += BK){
    float av[8];
#pragma unroll
    for (int i = 0; i < 8; i++) av[i] = 0.f;
    int arow = row0 + am;
    if (arow < N){
      if (k0 + ak + 7 < K){
        float4 v0 = *(const float4*)&A[(size_t)arow*K + k0 + ak];
        float4 v1 = *(const float4*)&A[(size_t)arow*K + k0 + ak + 4];
        av[0]=v0.x; av[1]=v0.y; av[2]=v0.z; av[3]=v0.w;
        av[4]=v1.x; av[5]=v1.y; av[6]=v1.z; av[7]=v1.w;
      } else {
        for (int i = 0; i < 8; i++)
          if (k0 + ak + i < K) av[i] = A[(size_t)arow*K + k0 + ak + i];
      }
    }
#pragma unroll
    for (int i = 0; i < 8; i++) As[ak+i][am] = av[i];

    float4 bv = make_float4(0.f,0.f,0.f,0.f);
    if (k0 + bk < K) bv = *(const float4*)&B[(size_t)(k0+bk)*M + col0 + bn];
    *(float4*)&Bs[bk][bn] = bv;
    __syncthreads();

#pragma unroll
    for (int kk = 0; kk < BK; kk++){
      float4 a0 = *(const float4*)&As[kk][ty*8];
      float4 a1 = *(const float4*)&As[kk][ty*8+4];
      float4 b4 = *(const float4*)&Bs[kk][tx*4];
      const float* ap0 = (const float*)&a0;
      const float* ap1 = (const float*)&a1;
      const float* bp  = (const float*)&b4;
#pragma unroll
      for (int i = 0; i < 4; i++)
#pragma unroll
        for (int j = 0; j < 4; j++){
          acc[i][j]   += ap0[i]*bp[j];
          acc[i+4][j] += ap1[i]*bp[j];
        }
    }
    __syncthreads();
  }
#pragma unroll
  for (int i = 0; i < 8; i++){
    int r = row0 + ty*8 + i;
    if (r < N){
      float4 o; float* op = (float*)&o;
#pragma unroll
      for (int j = 0; j < 4; j++) op[j] = acc[i][j];
      *(float4*)&C[(size_t)r*M + col0 + tx*4] = o;
    }
  }
}

// ================= GCN gather (fused self + bias + relu) =================
__global__ void k_gcn_gather(const float* __restrict__ hw, const float* __restrict__ dinv,
                             const int* __restrict__ rowptr, const int* __restrict__ colidx,
                             const float* __restrict__ gb, float* __restrict__ h, int M){
  int n = blockIdx.x;
  int b = rowptr[n], e = rowptr[n+1];
  float dn = dinv[n];
  int f0i = threadIdx.x, f1i = threadIdx.x + 256;
  float acc0 = 0.f, acc1 = 0.f;
  for (int j = b; j < e; j++){
    int s = colidx[j];
    float w = dinv[s]*dn;
    const float* row = hw + (size_t)s*M;
    if (f0i < M) acc0 += row[f0i]*w;
    if (f1i < M) acc1 += row[f1i]*w;
  }
  const float* self = hw + (size_t)n*M;
  float dn2 = dn*dn;
  if (f0i < M) h[(size_t)n*M + f0i] = fmaxf(acc0 + self[f0i]*dn2 + gb[f0i], 0.f);
  if (f1i < M) h[(size_t)n*M + f1i] = fmaxf(acc1 + self[f1i]*dn2 + gb[f1i], 0.f);
}

// ================= GAT =================
__global__ void k_gat_alpha(const float* __restrict__ hg, const float* __restrict__ a_s,
                            const float* __restrict__ a_d, float* __restrict__ as_,
                            float* __restrict__ ad_, int M, int C){
  int idx = blockIdx.x*blockDim.x + threadIdx.x;
  if (idx >= NN*NH) return;
  int n = idx >> 2, hd = idx & 3;
  float ss = 0.f, dd = 0.f;
  const float* row = hg + (size_t)n*M + hd*C;
  const float* ws = a_s + hd*C;
  const float* wd = a_d + hd*C;
  for (int c = 0; c < C; c++){ float v = row[c]; ss += v*ws[c]; dd += v*wd[c]; }
  as_[idx] = ss; ad_[idx] = dd;
}
// per (node, head): segment max, exp-sum, per-edge unnormalized alpha (CSR order)
__global__ void k_gat_maxden(const int* __restrict__ rowptr, const int* __restrict__ colidx,
                             const float* __restrict__ as_, const float* __restrict__ ad_,
                             float* __restrict__ eself, float* __restrict__ den,
                             float* __restrict__ ealpha){
  int idx = blockIdx.x*blockDim.x + threadIdx.x;
  if (idx >= NN*NH) return;
  int n = idx >> 2, hd = idx & 3;
  float adn = ad_[idx];
  float selflog = leakyf(as_[idx] + adn);
  float m = selflog;
  int b = rowptr[n], e = rowptr[n+1];
  for (int j = b; j < e; j++){
    int s = colidx[j];
    m = fmaxf(m, leakyf(as_[s*NH + hd] + adn));
  }
  float es = expf(selflog - m);
  float dsum = es;
  for (int j = b; j < e; j++){
    int s = colidx[j];
    float v = expf(leakyf(as_[s*NH + hd] + adn) - m);
    ealpha[(size_t)j*NH + hd] = v;
    dsum += v;
  }
  eself[idx] = es;
  den[idx] = dsum;
}
// fused: x = h + bias + (hg_self*eself + sum_edges hg_src*ealpha)/den
__global__ void k_gat_gather(const float* __restrict__ hg, const float* __restrict__ h,
                             const int* __restrict__ rowptr, const int* __restrict__ colidx,
                             const float* __restrict__ ealpha, const float* __restrict__ eself,
                             const float* __restrict__ den, const float* __restrict__ ab,
                             float* __restrict__ xout, int M, int C){
  int n = blockIdx.x;
  int b = rowptr[n], e = rowptr[n+1];
  int f0i = threadIdx.x, f1i = threadIdx.x + 256;
  int h0 = (f0i < M) ? f0i / C : 0;
  int h1 = (f1i < M) ? f1i / C : 0;
  float acc0 = 0.f, acc1 = 0.f;
  for (int j = b; j < e; j++){
    int s = colidx[j];
    const float* row = hg + (size_t)s*M;
    const float* ea = ealpha + (size_t)j*NH;
    if (f0i < M) acc0 += row[f0i]*ea[h0];
    if (f1i < M) acc1 += row[f1i]*ea[h1];
  }
  const float* self = hg + (size_t)n*M;
  const float* hrow = h + (size_t)n*M;
  if (f0i < M){
    int ai = n*NH + h0;
    xout[(size_t)n*M + f0i] = hrow[f0i] + ab[f0i] + (self[f0i]*eself[ai] + acc0)/den[ai];
  }
  if (f1i < M){
    int ai = n*NH + h1;
    xout[(size_t)n*M + f1i] = hrow[f1i] + ab[f1i] + (self[f1i]*eself[ai] + acc1)/den[ai];
  }
}

// ================= attention pooling =================
__global__ void k_tanh_dot(const float* __restrict__ t1, const float* __restrict__ b1,
                           const float* __restrict__ w2, const float* __restrict__ b2,
                           float* __restrict__ apre){
  __shared__ float sred[256];
  int n = blockIdx.x, c = threadIdx.x;
  float v = tanhf(t1[(size_t)n*256 + c] + b1[c]) * w2[c];
  sred[c] = v; __syncthreads();
  for (int o = 128; o > 0; o >>= 1){
    if (c < o) sred[c] += sred[c + o];
    __syncthreads();
  }
  if (c == 0) apre[n] = sred[0] + b2[0];
}
// segment starts via binary search (batch is sorted)
__global__ void k_starts(const int* __restrict__ batch, int* __restrict__ starts){
  int g = threadIdx.x;
  if (g > NB) return;
  int lo = 0, hi = NN;
  while (lo < hi){ int mid = (lo + hi) >> 1; if (batch[mid] < g) lo = mid + 1; else hi = mid; }
  starts[g] = lo;
}
// per-graph softmax weights (global softmax denominator cancels in renorm)
__global__ void k_pool_prep(const float* __restrict__ apre, const int* __restrict__ starts,
                            float* __restrict__ pw){
  int g = blockIdx.x, t = threadIdx.x;
  int b = starts[g], e = starts[g+1];
  float m = -INFINITY;
  for (int n = b + t; n < e; n += 64) m = fmaxf(m, apre[n]);
  for (int o = 32; o > 0; o >>= 1) m = fmaxf(m, __shfl_xor(m, o));
  float s = 0.f;
  for (int n = b + t; n < e; n += 64) s += expf(apre[n] - m);
  for (int o = 32; o > 0; o >>= 1) s += __shfl_xor(s, o);
  float inv = 1.f / (s + 1e-8f);
  for (int n = b + t; n < e; n += 64) pw[n] = expf(apre[n] - m) * inv;
}
// per-graph gather over contiguous [starts[g], starts[g+1]) node range
__global__ void k_pool(const float* __restrict__ x, const float* __restrict__ pw,
                       const int* __restrict__ starts, float* __restrict__ out){
  int g = blockIdx.x;
  int f = threadIdx.x + blockIdx.y*256;   // 0..511
  int b = starts[g], e = starts[g+1];
  float sum = 0.f, mx = -INFINITY, wacc = 0.f;
  for (int n = b; n < e; n++){
    float xv = x[(size_t)n*DOUT + f];
    sum += xv; mx = fmaxf(mx, xv);
    wacc += pw[n]*xv;
  }
  float cntf = (float)(e - b);
  float* o = out + (size_t)g*4*DOUT;
  o[f]          = wacc;
  o[DOUT + f]   = sum / fmaxf(cntf, 1.f);
  o[2*DOUT + f] = mx;
  o[3*DOUT + f] = sum;
}

extern "C" void kernel_launch(void* const* d_in, const int* in_sizes, int n_in,
                              void* d_out, int out_size, void* d_ws, size_t ws_size,
                              hipStream_t stream) {
  const float* x0   = (const float*)d_in[0];
  const int*   ei   = (const int*)d_in[1];
  const int*   src  = ei;
  const int*   dst  = ei + NE;
  const int*   batch= (const int*)d_in[2];
  const float* gw[3]  = {(const float*)d_in[3],  (const float*)d_in[9],  (const float*)d_in[15]};
  const float* gb[3]  = {(const float*)d_in[4],  (const float*)d_in[10], (const float*)d_in[16]};
  const float* aw[3]  = {(const float*)d_in[5],  (const float*)d_in[11], (const float*)d_in[17]};
  const float* asw[3] = {(const float*)d_in[6],  (const float*)d_in[12], (const float*)d_in[18]};
  const float* adw[3] = {(const float*)d_in[7],  (const float*)d_in[13], (const float*)d_in[19]};
  const float* ab[3]  = {(const float*)d_in[8],  (const float*)d_in[14], (const float*)d_in[20]};
  const float* apw1 = (const float*)d_in[21];
  const float* apb1 = (const float*)d_in[22];
  const float* apw2 = (const float*)d_in[23];
  const float* apb2 = (const float*)d_in[24];
  float* out = (float*)d_out;

  // ---- workspace layout ----
  float* f0   = (float*)d_ws;                  // h                 [NN*512]
  float* f1   = f0 + (size_t)NN*512;           // gemm out          [NN*512]
  float* f2   = f1 + (size_t)NN*512;           // x                 [NN*512]
  float* ealpha = f2 + (size_t)NN*512;         // [NE*NH]
  float* dinv = ealpha + (size_t)NE*NH;        // [NN]
  float* as_  = dinv + NN;                     // [NN*NH]
  float* ad_  = as_ + NN*NH;                   // [NN*NH]
  float* eself= ad_ + NN*NH;                   // [NN*NH]
  float* den  = eself + NN*NH;                 // [NN*NH]
  float* apre = den + NN*NH;                   // [NN]
  float* pw   = apre + NN;                     // [NN]
  int* rowptr = (int*)(pw + NN);               // [NN+1]
  int* colidx = rowptr + NN + 1;               // [NE]
  int* cnt    = colidx + NE;                   // [NN]
  int* cursor = cnt + NN;                      // [NN]
  int* starts = cursor + NN;                   // [NB+1]

  // ---- CSR build + degrees + segment starts ----
  hipMemsetAsync(cnt, 0, NN*sizeof(int), stream);
  k_count<<<(NE+255)/256, 256, 0, stream>>>(dst, cnt);
  k_dinv<<<(NN+255)/256, 256, 0, stream>>>(cnt, dinv);
  k_scan<<<1, 256, 0, stream>>>(cnt, rowptr);
  hipMemsetAsync(cursor, 0, NN*sizeof(int), stream);
  k_fill<<<(NE+255)/256, 256, 0, stream>>>(src, dst, rowptr, cursor, colidx);
  k_starts<<<1, 256, 0, stream>>>(batch, starts);

  const int dims[4] = {36, 128, 256, 512};
  const float* xcur = x0;
  for (int i = 0; i < 3; i++){
    int K = dims[i], M = dims[i+1], C = M/NH;
    dim3 gg(M/BN, (NN+BM-1)/BM);
    // GCN
    k_gemm<<<gg, 256, 0, stream>>>(xcur, gw[i], f1, NN, K, M);
    k_gcn_gather<<<NN, 256, 0, stream>>>(f1, dinv, rowptr, colidx, gb[i], f0, M);
    // GAT
    k_gemm<<<gg, 256, 0, stream>>>(f0, aw[i], f1, NN, M, M);
    k_gat_alpha<<<(NN*NH+255)/256, 256, 0, stream>>>(f1, asw[i], adw[i], as_, ad_, M, C);
    k_gat_maxden<<<(NN*NH+255)/256, 256, 0, stream>>>(rowptr, colidx, as_, ad_, eself, den, ealpha);
    k_gat_gather<<<NN, 256, 0, stream>>>(f1, f0, rowptr, colidx, ealpha, eself, den, ab[i], f2, M, C);
    xcur = f2;
  }

  // ---- pooling ----
  k_gemm<<<dim3(256/BN, (NN+BM-1)/BM), 256, 0, stream>>>(f2, apw1, f1, NN, 512, 256);
  k_tanh_dot<<<NN, 256, 0, stream>>>(f1, apb1, apw2, apb2, apre);
  k_pool_prep<<<NB, 64, 0, stream>>>(apre, starts, pw);
  k_pool<<<dim3(NB, 2), 256, 0, stream>>>(f2, pw, starts, out);
}

// Round 4
// 858.563 us; speedup vs baseline: 2.6895x; 1.0036x over previous
//
#include <hip/hip_runtime.h>
#include <math.h>

#define NN 10000
#define NE 160000
#define NB 128
#define NH 4
#define DOUT 512
#define NEG 0.2f

__device__ __forceinline__ float leakyf(float v){ return v > 0.f ? v : NEG*v; }
__device__ __forceinline__ void fma4(float4& a, const float4 v, float w){
  a.x += v.x*w; a.y += v.y*w; a.z += v.z*w; a.w += v.w*w;
}

// ================= CSR build =================
__global__ void k_count(const int* __restrict__ dst, int* __restrict__ cnt){
  int e = blockIdx.x*blockDim.x + threadIdx.x;
  if (e < NE) atomicAdd(&cnt[dst[e]], 1);
}
__global__ void k_dinv(const int* __restrict__ cnt, float* __restrict__ dinv){
  int n = blockIdx.x*blockDim.x + threadIdx.x;
  if (n < NN) dinv[n] = rsqrtf((float)cnt[n] + 1.f);
}
__global__ void k_scan(const int* __restrict__ cnt, int* __restrict__ rowptr){
  __shared__ int part[256];
  const int CH = (NN + 255) / 256;
  int t = threadIdx.x;
  int base = t * CH;
  int s = 0;
  for (int i = 0; i < CH; i++){ int idx = base + i; if (idx < NN) s += cnt[idx]; }
  part[t] = s; __syncthreads();
  for (int o = 1; o < 256; o <<= 1){
    int v = 0;
    if (t >= o) v = part[t - o];
    __syncthreads();
    if (t >= o) part[t] += v;
    __syncthreads();
  }
  int pre = (t == 0) ? 0 : part[t - 1];
  for (int i = 0; i < CH; i++){
    int idx = base + i;
    if (idx < NN){ rowptr[idx] = pre; pre += cnt[idx]; }
  }
  if (t == 255) rowptr[NN] = part[255];
}
__global__ void k_fill(const int* __restrict__ src, const int* __restrict__ dst,
                       const int* __restrict__ rowptr, int* __restrict__ cursor,
                       int* __restrict__ colidx){
  int e = blockIdx.x*blockDim.x + threadIdx.x;
  if (e >= NE) return;
  int d = dst[e];
  int pos = atomicAdd(&cursor[d], 1);
  colidx[rowptr[d] + pos] = src[e];
}

// ================= GEMM: C[N,M] = A[N,K] @ B[K,M] =================
// 128x64 tile, 8x4 micro-tile, 256 threads, double-buffered LDS,
// L2-aware swizzle (groups of 8 row-blocks share B; A-band stays hot).
#define BM 128
#define BN 64
#define BK 16
__global__ __launch_bounds__(256) void k_gemm(const float* __restrict__ A,
                                              const float* __restrict__ B,
                                              float* __restrict__ C,
                                              int N, int K, int M){
  __shared__ float As[2][BK][BM+4];
  __shared__ float Bs[2][BK][BN+4];
  int gx = M / BN;
  int gy = (N + BM - 1) / BM;
  const int G = 8;
  int bid = blockIdx.x;
  int full = gy / G;
  int bid_full = full * G * gx;
  int by, bx;
  if (bid < bid_full){
    int g = bid / (G*gx); int rem = bid % (G*gx);
    by = g*G + rem % G; bx = rem / G;
  } else {
    int rem = bid - bid_full; int rows = gy - full*G;
    by = full*G + rem % rows; bx = rem / rows;
  }
  int t  = threadIdx.x;
  int tx = t & 15, ty = t >> 4;
  int row0 = by * BM, col0 = bx * BN;
  int am = t >> 1, ak = (t & 1) * 8;
  int bk = t >> 4, bn = (t & 15) * 4;
  float acc[8][4];
#pragma unroll
  for (int i = 0; i < 8; i++)
#pragma unroll
    for (int j = 0; j < 4; j++) acc[i][j] = 0.f;

  float av[8]; float4 bv;
  int arow = row0 + am;
  auto loadT = [&](int k0){
#pragma unroll
    for (int i = 0; i < 8; i++) av[i] = 0.f;
    if (arow < N){
      if (k0 + ak + 7 < K){
        float4 v0 = *(const float4*)&A[(size_t)arow*K + k0 + ak];
        float4 v1 = *(const float4*)&A[(size_t)arow*K + k0 + ak + 4];
        av[0]=v0.x; av[1]=v0.y; av[2]=v0.z; av[3]=v0.w;
        av[4]=v1.x; av[5]=v1.y; av[6]=v1.z; av[7]=v1.w;
      } else {
        for (int i = 0; i < 8; i++)
          if (k0 + ak + i < K) av[i] = A[(size_t)arow*K + k0 + ak + i];
      }
    }
    bv = make_float4(0.f,0.f,0.f,0.f);
    if (k0 + bk < K) bv = *(const float4*)&B[(size_t)(k0+bk)*M + col0 + bn];
  };
  auto storeT = [&](int buf){
#pragma unroll
    for (int i = 0; i < 8; i++) As[buf][ak+i][am] = av[i];
    *(float4*)&Bs[buf][bk][bn] = bv;
  };

  int nk = (K + BK - 1) / BK;
  loadT(0);
  storeT(0);
  __syncthreads();
  for (int it = 0; it < nk; it++){
    int cur = it & 1;
    if (it + 1 < nk) loadT((it + 1) * BK);   // prefetch overlaps compute
#pragma unroll
    for (int kk = 0; kk < BK; kk++){
      float4 a0 = *(const float4*)&As[cur][kk][ty*8];
      float4 a1 = *(const float4*)&As[cur][kk][ty*8+4];
      float4 b4 = *(const float4*)&Bs[cur][kk][tx*4];
      const float* ap0 = (const float*)&a0;
      const float* ap1 = (const float*)&a1;
      const float* bp  = (const float*)&b4;
#pragma unroll
      for (int i = 0; i < 4; i++)
#pragma unroll
        for (int j = 0; j < 4; j++){
          acc[i][j]   += ap0[i]*bp[j];
          acc[i+4][j] += ap1[i]*bp[j];
        }
    }
    if (it + 1 < nk){
      storeT(cur ^ 1);      // write other buffer (safe: readers use cur)
      __syncthreads();
    }
  }
#pragma unroll
  for (int i = 0; i < 8; i++){
    int r = row0 + ty*8 + i;
    if (r < N){
      float4 o; float* op = (float*)&o;
#pragma unroll
      for (int j = 0; j < 4; j++) op[j] = acc[i][j];
      *(float4*)&C[(size_t)r*M + col0 + tx*4] = o;
    }
  }
}

// ================= GCN gather: wave per node, float4 =================
__global__ void k_gcn_gather(const float* __restrict__ hw, const float* __restrict__ dinv,
                             const int* __restrict__ rowptr, const int* __restrict__ colidx,
                             const float* __restrict__ gb, float* __restrict__ h, int M){
  int n = blockIdx.x, t = threadIdx.x;      // 64 threads
  int b = rowptr[n], e = rowptr[n+1];
  float dn = dinv[n];
  int FV = M >> 2;
  bool a0 = t < FV, a1 = (t + 64) < FV;
  float4 acc0 = make_float4(0,0,0,0), acc1 = make_float4(0,0,0,0);
  for (int j = b; j < e; j++){
    int s = colidx[j];
    float w = dinv[s]*dn;
    const float4* row = (const float4*)(hw + (size_t)s*M);
    if (a0) fma4(acc0, row[t], w);
    if (a1) fma4(acc1, row[t+64], w);
  }
  const float4* self = (const float4*)(hw + (size_t)n*M);
  const float4* gb4  = (const float4*)gb;
  float4* out = (float4*)(h + (size_t)n*M);
  float dn2 = dn*dn;
  if (a0){
    float4 v = self[t], bb = gb4[t];
    out[t] = make_float4(fmaxf(acc0.x + v.x*dn2 + bb.x, 0.f),
                         fmaxf(acc0.y + v.y*dn2 + bb.y, 0.f),
                         fmaxf(acc0.z + v.z*dn2 + bb.z, 0.f),
                         fmaxf(acc0.w + v.w*dn2 + bb.w, 0.f));
  }
  if (a1){
    float4 v = self[t+64], bb = gb4[t+64];
    out[t+64] = make_float4(fmaxf(acc1.x + v.x*dn2 + bb.x, 0.f),
                            fmaxf(acc1.y + v.y*dn2 + bb.y, 0.f),
                            fmaxf(acc1.z + v.z*dn2 + bb.z, 0.f),
                            fmaxf(acc1.w + v.w*dn2 + bb.w, 0.f));
  }
}

// ================= GAT =================
__global__ void k_gat_alpha(const float* __restrict__ hg, const float* __restrict__ a_s,
                            const float* __restrict__ a_d, float* __restrict__ as_,
                            float* __restrict__ ad_, int M, int C){
  int idx = blockIdx.x*blockDim.x + threadIdx.x;
  if (idx >= NN*NH) return;
  int n = idx >> 2, hd = idx & 3;
  float ss = 0.f, dd = 0.f;
  const float* row = hg + (size_t)n*M + hd*C;
  const float* ws = a_s + hd*C;
  const float* wd = a_d + hd*C;
  for (int c = 0; c < C; c++){ float v = row[c]; ss += v*ws[c]; dd += v*wd[c]; }
  as_[idx] = ss; ad_[idx] = dd;
}
__global__ void k_gat_maxden(const int* __restrict__ rowptr, const int* __restrict__ colidx,
                             const float* __restrict__ as_, const float* __restrict__ ad_,
                             float* __restrict__ eself, float* __restrict__ den,
                             float* __restrict__ ealpha){
  int idx = blockIdx.x*blockDim.x + threadIdx.x;
  if (idx >= NN*NH) return;
  int n = idx >> 2, hd = idx & 3;
  float adn = ad_[idx];
  float selflog = leakyf(as_[idx] + adn);
  float m = selflog;
  int b = rowptr[n], e = rowptr[n+1];
  for (int j = b; j < e; j++){
    int s = colidx[j];
    m = fmaxf(m, leakyf(as_[s*NH + hd] + adn));
  }
  float es = expf(selflog - m);
  float dsum = es;
  for (int j = b; j < e; j++){
    int s = colidx[j];
    float v = expf(leakyf(as_[s*NH + hd] + adn) - m);
    ealpha[(size_t)j*NH + hd] = v;
    dsum += v;
  }
  eself[idx] = es;
  den[idx] = dsum;
}
// fused: x = h + bias + (hg_self*eself + sum_edges hg_src*ealpha)/den ; wave per node
__global__ void k_gat_gather(const float* __restrict__ hg, const float* __restrict__ h,
                             const int* __restrict__ rowptr, const int* __restrict__ colidx,
                             const float* __restrict__ ealpha, const float* __restrict__ eself,
                             const float* __restrict__ den, const float* __restrict__ ab,
                             float* __restrict__ xout, int M, int C){
  int n = blockIdx.x, t = threadIdx.x;      // 64 threads
  int b = rowptr[n], e = rowptr[n+1];
  int FV = M >> 2, C4 = C >> 2;
  bool a0 = t < FV, a1 = (t + 64) < FV;
  int hd0 = a0 ? t / C4 : 0;
  int hd1 = a1 ? (t + 64) / C4 : 0;
  float4 acc0 = make_float4(0,0,0,0), acc1 = make_float4(0,0,0,0);
  for (int j = b; j < e; j++){
    int s = colidx[j];
    const float4* row = (const float4*)(hg + (size_t)s*M);
    const float* ea = ealpha + (size_t)j*NH;
    if (a0) fma4(acc0, row[t], ea[hd0]);
    if (a1) fma4(acc1, row[t+64], ea[hd1]);
  }
  const float4* self = (const float4*)(hg + (size_t)n*M);
  const float4* hrow = (const float4*)(h + (size_t)n*M);
  const float4* ab4  = (const float4*)ab;
  float4* out = (float4*)(xout + (size_t)n*M);
  if (a0){
    int ai = n*NH + hd0;
    float es = eself[ai], inv = 1.f/den[ai];
    float4 sv = self[t], hv = hrow[t], bb = ab4[t];
    out[t] = make_float4(hv.x + bb.x + (sv.x*es + acc0.x)*inv,
                         hv.y + bb.y + (sv.y*es + acc0.y)*inv,
                         hv.z + bb.z + (sv.z*es + acc0.z)*inv,
                         hv.w + bb.w + (sv.w*es + acc0.w)*inv);
  }
  if (a1){
    int ai = n*NH + hd1;
    float es = eself[ai], inv = 1.f/den[ai];
    float4 sv = self[t+64], hv = hrow[t+64], bb = ab4[t+64];
    out[t+64] = make_float4(hv.x + bb.x + (sv.x*es + acc1.x)*inv,
                            hv.y + bb.y + (sv.y*es + acc1.y)*inv,
                            hv.z + bb.z + (sv.z*es + acc1.z)*inv,
                            hv.w + bb.w + (sv.w*es + acc1.w)*inv);
  }
}

// ================= attention pooling =================
// one wave per node, float4 + shuffle reduce
__global__ void k_tanh_dot(const float* __restrict__ t1, const float* __restrict__ b1,
                           const float* __restrict__ w2, const float* __restrict__ b2,
                           float* __restrict__ apre){
  int n = blockIdx.x, t = threadIdx.x;   // 64 threads, 256 cols
  float4 v  = ((const float4*)(t1 + (size_t)n*256))[t];
  float4 bb = ((const float4*)b1)[t];
  float4 ww = ((const float4*)w2)[t];
  float s = tanhf(v.x+bb.x)*ww.x + tanhf(v.y+bb.y)*ww.y
          + tanhf(v.z+bb.z)*ww.z + tanhf(v.w+bb.w)*ww.w;
  for (int o = 32; o > 0; o >>= 1) s += __shfl_xor(s, o);
  if (t == 0) apre[n] = s + b2[0];
}
__global__ void k_starts(const int* __restrict__ batch, int* __restrict__ starts){
  int g = threadIdx.x;
  if (g > NB) return;
  int lo = 0, hi = NN;
  while (lo < hi){ int mid = (lo + hi) >> 1; if (batch[mid] < g) lo = mid + 1; else hi = mid; }
  starts[g] = lo;
}
__global__ void k_pool_prep(const float* __restrict__ apre, const int* __restrict__ starts,
                            float* __restrict__ pw){
  int g = blockIdx.x, t = threadIdx.x;
  int b = starts[g], e = starts[g+1];
  float m = -INFINITY;
  for (int n = b + t; n < e; n += 64) m = fmaxf(m, apre[n]);
  for (int o = 32; o > 0; o >>= 1) m = fmaxf(m, __shfl_xor(m, o));
  float s = 0.f;
  for (int n = b + t; n < e; n += 64) s += expf(apre[n] - m);
  for (int o = 32; o > 0; o >>= 1) s += __shfl_xor(s, o);
  float inv = 1.f / (s + 1e-8f);
  for (int n = b + t; n < e; n += 64) pw[n] = expf(apre[n] - m) * inv;
}
// 128 threads x float4 covers 512 features; per-graph contiguous node range
__global__ void k_pool(const float* __restrict__ x, const float* __restrict__ pw,
                       const int* __restrict__ starts, float* __restrict__ out){
  int g = blockIdx.x, t = threadIdx.x;   // 128 threads
  int b = starts[g], e = starts[g+1];
  float4 sum = make_float4(0,0,0,0), wacc = make_float4(0,0,0,0);
  float4 mx = make_float4(-INFINITY,-INFINITY,-INFINITY,-INFINITY);
  for (int n = b; n < e; n++){
    float4 xv = ((const float4*)(x + (size_t)n*DOUT))[t];
    float p = pw[n];
    sum.x += xv.x; sum.y += xv.y; sum.z += xv.z; sum.w += xv.w;
    mx.x = fmaxf(mx.x, xv.x); mx.y = fmaxf(mx.y, xv.y);
    mx.z = fmaxf(mx.z, xv.z); mx.w = fmaxf(mx.w, xv.w);
    fma4(wacc, xv, p);
  }
  float ic = 1.f / fmaxf((float)(e - b), 1.f);
  float4* o = (float4*)(out + (size_t)g*4*DOUT);
  o[t]       = wacc;
  o[128 + t] = make_float4(sum.x*ic, sum.y*ic, sum.z*ic, sum.w*ic);
  o[256 + t] = mx;
  o[384 + t] = sum;
}

extern "C" void kernel_launch(void* const* d_in, const int* in_sizes, int n_in,
                              void* d_out, int out_size, void* d_ws, size_t ws_size,
                              hipStream_t stream) {
  const float* x0   = (const float*)d_in[0];
  const int*   ei   = (const int*)d_in[1];
  const int*   src  = ei;
  const int*   dst  = ei + NE;
  const int*   batch= (const int*)d_in[2];
  const float* gw[3]  = {(const float*)d_in[3],  (const float*)d_in[9],  (const float*)d_in[15]};
  const float* gb[3]  = {(const float*)d_in[4],  (const float*)d_in[10], (const float*)d_in[16]};
  const float* aw[3]  = {(const float*)d_in[5],  (const float*)d_in[11], (const float*)d_in[17]};
  const float* asw[3] = {(const float*)d_in[6],  (const float*)d_in[12], (const float*)d_in[18]};
  const float* adw[3] = {(const float*)d_in[7],  (const float*)d_in[13], (const float*)d_in[19]};
  const float* ab[3]  = {(const float*)d_in[8],  (const float*)d_in[14], (const float*)d_in[20]};
  const float* apw1 = (const float*)d_in[21];
  const float* apb1 = (const float*)d_in[22];
  const float* apw2 = (const float*)d_in[23];
  const float* apb2 = (const float*)d_in[24];
  float* out = (float*)d_out;

  // ---- workspace layout ----
  float* f0   = (float*)d_ws;                  // h                 [NN*512]
  float* f1   = f0 + (size_t)NN*512;           // gemm out          [NN*512]
  float* f2   = f1 + (size_t)NN*512;           // x                 [NN*512]
  float* ealpha = f2 + (size_t)NN*512;         // [NE*NH]
  float* dinv = ealpha + (size_t)NE*NH;        // [NN]
  float* as_  = dinv + NN;                     // [NN*NH]
  float* ad_  = as_ + NN*NH;                   // [NN*NH]
  float* eself= ad_ + NN*NH;                   // [NN*NH]
  float* den  = eself + NN*NH;                 // [NN*NH]
  float* apre = den + NN*NH;                   // [NN]
  float* pw   = apre + NN;                     // [NN]
  int* rowptr = (int*)(pw + NN);               // [NN+1]
  int* colidx = rowptr + NN + 1;               // [NE]
  int* cnt    = colidx + NE;                   // [NN]
  int* cursor = cnt + NN;                      // [NN]
  int* starts = cursor + NN;                   // [NB+1]

  // ---- CSR build + degrees + segment starts ----
  hipMemsetAsync(cnt, 0, NN*sizeof(int), stream);
  k_count<<<(NE+255)/256, 256, 0, stream>>>(dst, cnt);
  k_dinv<<<(NN+255)/256, 256, 0, stream>>>(cnt, dinv);
  k_scan<<<1, 256, 0, stream>>>(cnt, rowptr);
  hipMemsetAsync(cursor, 0, NN*sizeof(int), stream);
  k_fill<<<(NE+255)/256, 256, 0, stream>>>(src, dst, rowptr, cursor, colidx);
  k_starts<<<1, 256, 0, stream>>>(batch, starts);

  const int dims[4] = {36, 128, 256, 512};
  const float* xcur = x0;
  for (int i = 0; i < 3; i++){
    int K = dims[i], M = dims[i+1], C = M/NH;
    int nblk = (M/BN) * ((NN+BM-1)/BM);
    // GCN
    k_gemm<<<nblk, 256, 0, stream>>>(xcur, gw[i], f1, NN, K, M);
    k_gcn_gather<<<NN, 64, 0, stream>>>(f1, dinv, rowptr, colidx, gb[i], f0, M);
    // GAT
    k_gemm<<<nblk, 256, 0, stream>>>(f0, aw[i], f1, NN, M, M);
    k_gat_alpha<<<(NN*NH+255)/256, 256, 0, stream>>>(f1, asw[i], adw[i], as_, ad_, M, C);
    k_gat_maxden<<<(NN*NH+255)/256, 256, 0, stream>>>(rowptr, colidx, as_, ad_, eself, den, ealpha);
    k_gat_gather<<<NN, 64, 0, stream>>>(f1, f0, rowptr, colidx, ealpha, eself, den, ab[i], f2, M, C);
    xcur = f2;
  }

  // ---- pooling ----
  int nblk_p = (256/BN) * ((NN+BM-1)/BM);
  k_gemm<<<nblk_p, 256, 0, stream>>>(f2, apw1, f1, NN, 512, 256);
  k_tanh_dot<<<NN, 64, 0, stream>>>(f1, apb1, apw2, apb2, apre);
  k_pool_prep<<<NB, 64, 0, stream>>>(apre, starts, pw);
  k_pool<<<NB, 128, 0, stream>>>(f2, pw, starts, out);
}

// Round 5
// 628.468 us; speedup vs baseline: 3.6742x; 1.3661x over previous
//
#include <hip/hip_runtime.h>
#include <math.h>

#define NN 10000
#define NE 160000
#define NB 128
#define NH 4
#define DOUT 512
#define NEG 0.2f

typedef __attribute__((ext_vector_type(8))) short short8;
typedef __attribute__((ext_vector_type(4))) float f32x4;
typedef __attribute__((ext_vector_type(4))) unsigned short us4;

__device__ __forceinline__ float leakyf(float v){ return v > 0.f ? v : NEG*v; }
__device__ __forceinline__ void fma4(float4& a, const float4 v, float w){
  a.x += v.x*w; a.y += v.y*w; a.z += v.z*w; a.w += v.w*w;
}
__device__ __forceinline__ unsigned short f2bf(float f){
  unsigned int u = __float_as_uint(f);
  u += 0x7FFFu + ((u >> 16) & 1u);
  return (unsigned short)(u >> 16);
}
__device__ __forceinline__ float bf2f(unsigned short h){
  return __uint_as_float(((unsigned int)h) << 16);
}
__device__ __forceinline__ void split2(float v, unsigned short& h, unsigned short& l){
  h = f2bf(v);
  l = f2bf(v - bf2f(h));
}
__device__ __forceinline__ void store_hl(unsigned short* H, unsigned short* L,
                                         size_t base, float4 v){
  us4 h, l; unsigned short hh, ll;
  split2(v.x, hh, ll); h[0]=hh; l[0]=ll;
  split2(v.y, hh, ll); h[1]=hh; l[1]=ll;
  split2(v.z, hh, ll); h[2]=hh; l[2]=ll;
  split2(v.w, hh, ll); h[3]=hh; l[3]=ll;
  *(us4*)&H[base] = h;
  *(us4*)&L[base] = l;
}

// ================= CSR build =================
__global__ void k_count(const int* __restrict__ dst, int* __restrict__ cnt){
  int e = blockIdx.x*blockDim.x + threadIdx.x;
  if (e < NE) atomicAdd(&cnt[dst[e]], 1);
}
__global__ void k_dinv(const int* __restrict__ cnt, float* __restrict__ dinv){
  int n = blockIdx.x*blockDim.x + threadIdx.x;
  if (n < NN) dinv[n] = rsqrtf((float)cnt[n] + 1.f);
}
__global__ void k_scan(const int* __restrict__ cnt, int* __restrict__ rowptr){
  __shared__ int part[256];
  const int CH = (NN + 255) / 256;
  int t = threadIdx.x;
  int base = t * CH;
  int s = 0;
  for (int i = 0; i < CH; i++){ int idx = base + i; if (idx < NN) s += cnt[idx]; }
  part[t] = s; __syncthreads();
  for (int o = 1; o < 256; o <<= 1){
    int v = 0;
    if (t >= o) v = part[t - o];
    __syncthreads();
    if (t >= o) part[t] += v;
    __syncthreads();
  }
  int pre = (t == 0) ? 0 : part[t - 1];
  for (int i = 0; i < CH; i++){
    int idx = base + i;
    if (idx < NN){ rowptr[idx] = pre; pre += cnt[idx]; }
  }
  if (t == 255) rowptr[NN] = part[255];
}
__global__ void k_fill(const int* __restrict__ src, const int* __restrict__ dst,
                       const int* __restrict__ rowptr, int* __restrict__ cursor,
                       int* __restrict__ colidx){
  int e = blockIdx.x*blockDim.x + threadIdx.x;
  if (e >= NE) return;
  int d = dst[e];
  int pos = atomicAdd(&cursor[d], 1);
  colidx[rowptr[d] + pos] = src[e];
}

// ================= conversions =================
// x0 [NN,36] fp32 -> hi/lo bf16 [NN,64] zero-padded
__global__ void k_convx0(const float* __restrict__ x0, unsigned short* __restrict__ xh,
                         unsigned short* __restrict__ xl){
  int idx = blockIdx.x*blockDim.x + threadIdx.x;
  if (idx >= NN*64) return;
  int n = idx >> 6, c = idx & 63;
  float v = (c < 36) ? x0[n*36 + c] : 0.f;
  unsigned short h, l; split2(v, h, l);
  xh[idx] = h; xl[idx] = l;
}
// W [K,M] fp32 -> transposed hi/lo bf16 [M,Kp] zero-padded
__global__ void k_wconv(const float* __restrict__ src, unsigned short* __restrict__ dh,
                        unsigned short* __restrict__ dl, int K, int M, int Kp){
  int idx = blockIdx.x*blockDim.x + threadIdx.x;
  if (idx >= Kp*M) return;
  int kk = idx % Kp, m = idx / Kp;
  float v = (kk < K) ? src[(size_t)kk*M + m] : 0.f;
  unsigned short h, l; split2(v, h, l);
  dh[idx] = h; dl[idx] = l;
}

// ================= GEMM: C[N,M] = (Ah+Al)[N,Kp] @ (Bh+Bl)^T  =================
// bf16x3 split MFMA. Bt is [M][Kp]. BM=128, BN=64, BK=32, 256 threads (4 waves).
#define GBM 128
#define GBN 64
#define GBK 32
#define LDK 40    // padded LDS k-stride (bf16 units, 80 B, 16B-aligned rows)
__global__ __launch_bounds__(256) void k_gemm_bf3(
    const unsigned short* __restrict__ Ah, const unsigned short* __restrict__ Al,
    const unsigned short* __restrict__ Bh, const unsigned short* __restrict__ Bl,
    float* __restrict__ C, int N, int Kp, int M){
  __shared__ unsigned short As[2][GBM][LDK];
  __shared__ unsigned short Bs[2][GBN][LDK];
  // L2-friendly swizzle: groups of 8 row-blocks iterate all col-blocks
  int gx = M / GBN;
  int gy = (N + GBM - 1) / GBM;
  const int G = 8;
  int bid = blockIdx.x;
  int full = gy / G;
  int bid_full = full * G * gx;
  int by, bx;
  if (bid < bid_full){
    int g = bid / (G*gx); int rem = bid % (G*gx);
    by = g*G + rem % G; bx = rem / G;
  } else {
    int rem = bid - bid_full; int rows = gy - full*G;
    by = full*G + rem % rows; bx = rem / rows;
  }
  int row0 = by * GBM, col0 = bx * GBN;
  int t = threadIdx.x;
  int w = t >> 6, L = t & 63;
  int lm = L & 15, lq = L >> 4;

  f32x4 acc[2][4];
#pragma unroll
  for (int i = 0; i < 2; i++)
#pragma unroll
    for (int j = 0; j < 4; j++) acc[i][j] = (f32x4){0.f,0.f,0.f,0.f};

  const short8 z8 = {0,0,0,0,0,0,0,0};
  int ar0 = t >> 2, ao0 = (t & 3) * 8;          // A unit 0: rows 0..63
  int ar1 = (t + 256) >> 2, ao1 = ao0;          // A unit 1: rows 64..127
  int br  = t >> 2, bo = (t & 3) * 8;           // B unit: rows 0..63 (only t<256 all used)

  int nk = Kp / GBK;
  for (int kt = 0; kt < nk; kt++){
    int k0 = kt * GBK;
    __syncthreads();
    // stage A hi/lo
    short8 vh0 = (row0 + ar0 < N) ? *(const short8*)&Ah[(size_t)(row0+ar0)*Kp + k0 + ao0] : z8;
    short8 vl0 = (row0 + ar0 < N) ? *(const short8*)&Al[(size_t)(row0+ar0)*Kp + k0 + ao0] : z8;
    short8 vh1 = (row0 + ar1 < N) ? *(const short8*)&Ah[(size_t)(row0+ar1)*Kp + k0 + ao1] : z8;
    short8 vl1 = (row0 + ar1 < N) ? *(const short8*)&Al[(size_t)(row0+ar1)*Kp + k0 + ao1] : z8;
    *(short8*)&As[0][ar0][ao0] = vh0;
    *(short8*)&As[1][ar0][ao0] = vl0;
    *(short8*)&As[0][ar1][ao1] = vh1;
    *(short8*)&As[1][ar1][ao1] = vl1;
    // stage B hi/lo (transposed source: [M][Kp])
    short8 wh = *(const short8*)&Bh[(size_t)(col0+br)*Kp + k0 + bo];
    short8 wl = *(const short8*)&Bl[(size_t)(col0+br)*Kp + k0 + bo];
    *(short8*)&Bs[0][br][bo] = wh;
    *(short8*)&Bs[1][br][bo] = wl;
    __syncthreads();

    short8 afh[2], afl[2], bfh[4], bfl[4];
#pragma unroll
    for (int mi = 0; mi < 2; mi++){
      int r = w*32 + mi*16 + lm;
      afh[mi] = *(const short8*)&As[0][r][lq*8];
      afl[mi] = *(const short8*)&As[1][r][lq*8];
    }
#pragma unroll
    for (int ni = 0; ni < 4; ni++){
      int r = ni*16 + lm;
      bfh[ni] = *(const short8*)&Bs[0][r][lq*8];
      bfl[ni] = *(const short8*)&Bs[1][r][lq*8];
    }
#pragma unroll
    for (int mi = 0; mi < 2; mi++)
#pragma unroll
      for (int ni = 0; ni < 4; ni++){
        acc[mi][ni] = __builtin_amdgcn_mfma_f32_16x16x32_bf16(afh[mi], bfh[ni], acc[mi][ni], 0, 0, 0);
        acc[mi][ni] = __builtin_amdgcn_mfma_f32_16x16x32_bf16(afh[mi], bfl[ni], acc[mi][ni], 0, 0, 0);
        acc[mi][ni] = __builtin_amdgcn_mfma_f32_16x16x32_bf16(afl[mi], bfh[ni], acc[mi][ni], 0, 0, 0);
      }
  }
  // epilogue: C/D layout col=lane&15, row=(lane>>4)*4+reg
#pragma unroll
  for (int mi = 0; mi < 2; mi++)
#pragma unroll
    for (int ni = 0; ni < 4; ni++){
#pragma unroll
      for (int r = 0; r < 4; r++){
        int row = row0 + w*32 + mi*16 + lq*4 + r;
        int col = col0 + ni*16 + lm;
        if (row < N) C[(size_t)row*M + col] = acc[mi][ni][r];
      }
    }
}

// ================= GCN gather: wave per node, float4 in, bf16 hi/lo out =================
__global__ void k_gcn_gather(const float* __restrict__ hw, const float* __restrict__ dinv,
                             const int* __restrict__ rowptr, const int* __restrict__ colidx,
                             const float* __restrict__ gb,
                             unsigned short* __restrict__ outH, unsigned short* __restrict__ outL,
                             int M){
  int n = blockIdx.x, t = threadIdx.x;      // 64 threads
  int b = rowptr[n], e = rowptr[n+1];
  float dn = dinv[n];
  int FV = M >> 2;
  bool a0 = t < FV, a1 = (t + 64) < FV;
  float4 acc0 = make_float4(0,0,0,0), acc1 = make_float4(0,0,0,0);
  for (int j = b; j < e; j++){
    int s = colidx[j];
    float ww = dinv[s]*dn;
    const float4* row = (const float4*)(hw + (size_t)s*M);
    if (a0) fma4(acc0, row[t], ww);
    if (a1) fma4(acc1, row[t+64], ww);
  }
  const float4* self = (const float4*)(hw + (size_t)n*M);
  const float4* gb4  = (const float4*)gb;
  float dn2 = dn*dn;
  if (a0){
    float4 v = self[t], bb = gb4[t];
    float4 r = make_float4(fmaxf(acc0.x + v.x*dn2 + bb.x, 0.f),
                           fmaxf(acc0.y + v.y*dn2 + bb.y, 0.f),
                           fmaxf(acc0.z + v.z*dn2 + bb.z, 0.f),
                           fmaxf(acc0.w + v.w*dn2 + bb.w, 0.f));
    store_hl(outH, outL, (size_t)n*M + t*4, r);
  }
  if (a1){
    float4 v = self[t+64], bb = gb4[t+64];
    float4 r = make_float4(fmaxf(acc1.x + v.x*dn2 + bb.x, 0.f),
                           fmaxf(acc1.y + v.y*dn2 + bb.y, 0.f),
                           fmaxf(acc1.z + v.z*dn2 + bb.z, 0.f),
                           fmaxf(acc1.w + v.w*dn2 + bb.w, 0.f));
    store_hl(outH, outL, (size_t)n*M + (t+64)*4, r);
  }
}

// ================= GAT =================
__global__ void k_gat_alpha(const float* __restrict__ hg, const float* __restrict__ a_s,
                            const float* __restrict__ a_d, float* __restrict__ as_,
                            float* __restrict__ ad_, int M, int C){
  int idx = blockIdx.x*blockDim.x + threadIdx.x;
  if (idx >= NN*NH) return;
  int n = idx >> 2, hd = idx & 3;
  float ss = 0.f, dd = 0.f;
  const float* row = hg + (size_t)n*M + hd*C;
  const float* ws = a_s + hd*C;
  const float* wd = a_d + hd*C;
  for (int c = 0; c < C; c++){ float v = row[c]; ss += v*ws[c]; dd += v*wd[c]; }
  as_[idx] = ss; ad_[idx] = dd;
}
__global__ void k_gat_maxden(const int* __restrict__ rowptr, const int* __restrict__ colidx,
                             const float* __restrict__ as_, const float* __restrict__ ad_,
                             float* __restrict__ eself, float* __restrict__ den,
                             float* __restrict__ ealpha){
  int idx = blockIdx.x*blockDim.x + threadIdx.x;
  if (idx >= NN*NH) return;
  int n = idx >> 2, hd = idx & 3;
  float adn = ad_[idx];
  float selflog = leakyf(as_[idx] + adn);
  float m = selflog;
  int b = rowptr[n], e = rowptr[n+1];
  for (int j = b; j < e; j++){
    int s = colidx[j];
    m = fmaxf(m, leakyf(as_[s*NH + hd] + adn));
  }
  float es = expf(selflog - m);
  float dsum = es;
  for (int j = b; j < e; j++){
    int s = colidx[j];
    float v = expf(leakyf(as_[s*NH + hd] + adn) - m);
    ealpha[(size_t)j*NH + hd] = v;
    dsum += v;
  }
  eself[idx] = es;
  den[idx] = dsum;
}
// x = h + bias + (hg_self*eself + sum_edges hg_src*ealpha)/den ; h from bf16 hi/lo
__global__ void k_gat_gather(const float* __restrict__ hg,
                             const unsigned short* __restrict__ inH, const unsigned short* __restrict__ inL,
                             const int* __restrict__ rowptr, const int* __restrict__ colidx,
                             const float* __restrict__ ealpha, const float* __restrict__ eself,
                             const float* __restrict__ den, const float* __restrict__ ab,
                             unsigned short* __restrict__ outH, unsigned short* __restrict__ outL,
                             int M, int C){
  int n = blockIdx.x, t = threadIdx.x;      // 64 threads
  int b = rowptr[n], e = rowptr[n+1];
  int FV = M >> 2, C4 = C >> 2;
  bool a0 = t < FV, a1 = (t + 64) < FV;
  int hd0 = a0 ? t / C4 : 0;
  int hd1 = a1 ? (t + 64) / C4 : 0;
  float4 acc0 = make_float4(0,0,0,0), acc1 = make_float4(0,0,0,0);
  for (int j = b; j < e; j++){
    int s = colidx[j];
    const float4* row = (const float4*)(hg + (size_t)s*M);
    const float* ea = ealpha + (size_t)j*NH;
    if (a0) fma4(acc0, row[t], ea[hd0]);
    if (a1) fma4(acc1, row[t+64], ea[hd1]);
  }
  const float4* self = (const float4*)(hg + (size_t)n*M);
  const us4* ih = (const us4*)(inH + (size_t)n*M);
  const us4* il = (const us4*)(inL + (size_t)n*M);
  const float4* ab4 = (const float4*)ab;
  if (a0){
    int ai = n*NH + hd0;
    float es = eself[ai], inv = 1.f/den[ai];
    float4 sv = self[t], bb = ab4[t];
    us4 hh = ih[t], hl = il[t];
    float4 r = make_float4(
      bf2f(hh[0])+bf2f(hl[0]) + bb.x + (sv.x*es + acc0.x)*inv,
      bf2f(hh[1])+bf2f(hl[1]) + bb.y + (sv.y*es + acc0.y)*inv,
      bf2f(hh[2])+bf2f(hl[2]) + bb.z + (sv.z*es + acc0.z)*inv,
      bf2f(hh[3])+bf2f(hl[3]) + bb.w + (sv.w*es + acc0.w)*inv);
    store_hl(outH, outL, (size_t)n*M + t*4, r);
  }
  if (a1){
    int ai = n*NH + hd1;
    float es = eself[ai], inv = 1.f/den[ai];
    float4 sv = self[t+64], bb = ab4[t+64];
    us4 hh = ih[t+64], hl = il[t+64];
    float4 r = make_float4(
      bf2f(hh[0])+bf2f(hl[0]) + bb.x + (sv.x*es + acc1.x)*inv,
      bf2f(hh[1])+bf2f(hl[1]) + bb.y + (sv.y*es + acc1.y)*inv,
      bf2f(hh[2])+bf2f(hl[2]) + bb.z + (sv.z*es + acc1.z)*inv,
      bf2f(hh[3])+bf2f(hl[3]) + bb.w + (sv.w*es + acc1.w)*inv);
    store_hl(outH, outL, (size_t)n*M + (t+64)*4, r);
  }
}

// ================= attention pooling =================
__global__ void k_tanh_dot(const float* __restrict__ t1, const float* __restrict__ b1,
                           const float* __restrict__ w2, const float* __restrict__ b2,
                           float* __restrict__ apre){
  int n = blockIdx.x, t = threadIdx.x;   // 64 threads, 256 cols
  float4 v  = ((const float4*)(t1 + (size_t)n*256))[t];
  float4 bb = ((const float4*)b1)[t];
  float4 ww = ((const float4*)w2)[t];
  float s = tanhf(v.x+bb.x)*ww.x + tanhf(v.y+bb.y)*ww.y
          + tanhf(v.z+bb.z)*ww.z + tanhf(v.w+bb.w)*ww.w;
  for (int o = 32; o > 0; o >>= 1) s += __shfl_xor(s, o);
  if (t == 0) apre[n] = s + b2[0];
}
__global__ void k_starts(const int* __restrict__ batch, int* __restrict__ starts){
  int g = threadIdx.x;
  if (g > NB) return;
  int lo = 0, hi = NN;
  while (lo < hi){ int mid = (lo + hi) >> 1; if (batch[mid] < g) lo = mid + 1; else hi = mid; }
  starts[g] = lo;
}
__global__ void k_pool_prep(const float* __restrict__ apre, const int* __restrict__ starts,
                            float* __restrict__ pw){
  int g = blockIdx.x, t = threadIdx.x;
  int b = starts[g], e = starts[g+1];
  float m = -INFINITY;
  for (int n = b + t; n < e; n += 64) m = fmaxf(m, apre[n]);
  for (int o = 32; o > 0; o >>= 1) m = fmaxf(m, __shfl_xor(m, o));
  float s = 0.f;
  for (int n = b + t; n < e; n += 64) s += expf(apre[n] - m);
  for (int o = 32; o > 0; o >>= 1) s += __shfl_xor(s, o);
  float inv = 1.f / (s + 1e-8f);
  for (int n = b + t; n < e; n += 64) pw[n] = expf(apre[n] - m) * inv;
}
__global__ void k_pool(const unsigned short* __restrict__ xH, const unsigned short* __restrict__ xL,
                       const float* __restrict__ pw, const int* __restrict__ starts,
                       float* __restrict__ out){
  int g = blockIdx.x, t = threadIdx.x;   // 128 threads
  int b = starts[g], e = starts[g+1];
  float4 sum = make_float4(0,0,0,0), wacc = make_float4(0,0,0,0);
  float4 mx = make_float4(-INFINITY,-INFINITY,-INFINITY,-INFINITY);
  for (int n = b; n < e; n++){
    us4 xh = ((const us4*)(xH + (size_t)n*DOUT))[t];
    us4 xl = ((const us4*)(xL + (size_t)n*DOUT))[t];
    float4 xv = make_float4(bf2f(xh[0])+bf2f(xl[0]), bf2f(xh[1])+bf2f(xl[1]),
                            bf2f(xh[2])+bf2f(xl[2]), bf2f(xh[3])+bf2f(xl[3]));
    float p = pw[n];
    sum.x += xv.x; sum.y += xv.y; sum.z += xv.z; sum.w += xv.w;
    mx.x = fmaxf(mx.x, xv.x); mx.y = fmaxf(mx.y, xv.y);
    mx.z = fmaxf(mx.z, xv.z); mx.w = fmaxf(mx.w, xv.w);
    fma4(wacc, xv, p);
  }
  float ic = 1.f / fmaxf((float)(e - b), 1.f);
  float4* o = (float4*)(out + (size_t)g*4*DOUT);
  o[t]       = wacc;
  o[128 + t] = make_float4(sum.x*ic, sum.y*ic, sum.z*ic, sum.w*ic);
  o[256 + t] = mx;
  o[384 + t] = sum;
}

extern "C" void kernel_launch(void* const* d_in, const int* in_sizes, int n_in,
                              void* d_out, int out_size, void* d_ws, size_t ws_size,
                              hipStream_t stream) {
  const float* x0   = (const float*)d_in[0];
  const int*   ei   = (const int*)d_in[1];
  const int*   src  = ei;
  const int*   dst  = ei + NE;
  const int*   batch= (const int*)d_in[2];
  const float* gw[3]  = {(const float*)d_in[3],  (const float*)d_in[9],  (const float*)d_in[15]};
  const float* gb[3]  = {(const float*)d_in[4],  (const float*)d_in[10], (const float*)d_in[16]};
  const float* aw[3]  = {(const float*)d_in[5],  (const float*)d_in[11], (const float*)d_in[17]};
  const float* asw[3] = {(const float*)d_in[6],  (const float*)d_in[12], (const float*)d_in[18]};
  const float* adw[3] = {(const float*)d_in[7],  (const float*)d_in[13], (const float*)d_in[19]};
  const float* ab[3]  = {(const float*)d_in[8],  (const float*)d_in[14], (const float*)d_in[20]};
  const float* apw1 = (const float*)d_in[21];
  const float* apb1 = (const float*)d_in[22];
  const float* apw2 = (const float*)d_in[23];
  const float* apb2 = (const float*)d_in[24];
  float* out = (float*)d_out;

  // ---- workspace carve ----
  char* p = (char*)d_ws;
  auto alloc = [&](size_t bytes) -> void* {
    void* r = (void*)p; p += (bytes + 255) & ~(size_t)255; return r;
  };
  float* f1 = (float*)alloc((size_t)NN*512*4);
  unsigned short* actH0 = (unsigned short*)alloc((size_t)NN*512*2);
  unsigned short* actL0 = (unsigned short*)alloc((size_t)NN*512*2);
  unsigned short* actH1 = (unsigned short*)alloc((size_t)NN*512*2);
  unsigned short* actL1 = (unsigned short*)alloc((size_t)NN*512*2);
  unsigned short* x0h = (unsigned short*)alloc((size_t)NN*64*2);
  unsigned short* x0l = (unsigned short*)alloc((size_t)NN*64*2);
  const int wK[7]  = {36, 128, 128, 256, 256, 512, 512};
  const int wM[7]  = {128, 128, 256, 256, 512, 512, 256};
  const int wKp[7] = {64, 128, 128, 256, 256, 512, 512};
  const float* wsrc[7] = {gw[0], aw[0], gw[1], aw[1], gw[2], aw[2], apw1};
  unsigned short* wTh[7]; unsigned short* wTl[7];
  for (int i = 0; i < 7; i++){
    size_t sz = (size_t)wM[i]*wKp[i]*2;
    wTh[i] = (unsigned short*)alloc(sz);
    wTl[i] = (unsigned short*)alloc(sz);
  }
  float* ealpha = (float*)alloc((size_t)NE*NH*4);
  float* dinv = (float*)alloc(NN*4);
  float* as_  = (float*)alloc(NN*NH*4);
  float* ad_  = (float*)alloc(NN*NH*4);
  float* eself= (float*)alloc(NN*NH*4);
  float* den  = (float*)alloc(NN*NH*4);
  float* apre = (float*)alloc(NN*4);
  float* pw   = (float*)alloc(NN*4);
  int* rowptr = (int*)alloc((NN+1)*4);
  int* colidx = (int*)alloc((size_t)NE*4);
  int* cnt    = (int*)alloc(NN*4);
  int* cursor = (int*)alloc(NN*4);
  int* starts = (int*)alloc((NB+1)*4);

  // ---- CSR build + degrees + starts ----
  hipMemsetAsync(cnt, 0, NN*sizeof(int), stream);
  k_count<<<(NE+255)/256, 256, 0, stream>>>(dst, cnt);
  k_dinv<<<(NN+255)/256, 256, 0, stream>>>(cnt, dinv);
  k_scan<<<1, 256, 0, stream>>>(cnt, rowptr);
  hipMemsetAsync(cursor, 0, NN*sizeof(int), stream);
  k_fill<<<(NE+255)/256, 256, 0, stream>>>(src, dst, rowptr, cursor, colidx);
  k_starts<<<1, 256, 0, stream>>>(batch, starts);

  // ---- conversions ----
  k_convx0<<<(NN*64+255)/256, 256, 0, stream>>>(x0, x0h, x0l);
  for (int i = 0; i < 7; i++){
    int tot = wKp[i]*wM[i];
    k_wconv<<<(tot+255)/256, 256, 0, stream>>>(wsrc[i], wTh[i], wTl[i], wK[i], wM[i], wKp[i]);
  }

  auto gemm = [&](const unsigned short* Ahp, const unsigned short* Alp, int wi, int M){
    int nblk = (M/GBN) * ((NN+GBM-1)/GBM);
    k_gemm_bf3<<<nblk, 256, 0, stream>>>(Ahp, Alp, wTh[wi], wTl[wi], f1, NN, wKp[wi], M);
  };

  const int dims[4] = {36, 128, 256, 512};
  const unsigned short* curH = x0h; const unsigned short* curL = x0l;
  int wi = 0;
  for (int i = 0; i < 3; i++){
    int M = dims[i+1], C = M/NH;
    // GCN
    gemm(curH, curL, wi++, M);
    k_gcn_gather<<<NN, 64, 0, stream>>>(f1, dinv, rowptr, colidx, gb[i], actH0, actL0, M);
    // GAT
    gemm(actH0, actL0, wi++, M);
    k_gat_alpha<<<(NN*NH+255)/256, 256, 0, stream>>>(f1, asw[i], adw[i], as_, ad_, M, C);
    k_gat_maxden<<<(NN*NH+255)/256, 256, 0, stream>>>(rowptr, colidx, as_, ad_, eself, den, ealpha);
    k_gat_gather<<<NN, 64, 0, stream>>>(f1, actH0, actL0, rowptr, colidx, ealpha, eself, den,
                                        ab[i], actH1, actL1, M, C);
    curH = actH1; curL = actL1;
  }

  // ---- pooling ----
  gemm(actH1, actL1, 6, 256);
  k_tanh_dot<<<NN, 64, 0, stream>>>(f1, apb1, apw2, apb2, apre);
  k_pool_prep<<<NB, 64, 0, stream>>>(apre, starts, pw);
  k_pool<<<NB, 128, 0, stream>>>(actH1, actL1, pw, starts, out);
}

// Round 6
// 583.596 us; speedup vs baseline: 3.9567x; 1.0769x over previous
//
#include <hip/hip_runtime.h>
#include <math.h>

#define NN 10000
#define NE 160000
#define NB 128
#define NH 4
#define DOUT 512
#define NEG 0.2f

typedef __attribute__((ext_vector_type(8))) short short8;
typedef __attribute__((ext_vector_type(4))) float f32x4;
typedef __attribute__((ext_vector_type(4))) unsigned short us4;

__device__ __forceinline__ float leakyf(float v){ return v > 0.f ? v : NEG*v; }
__device__ __forceinline__ void fma4(float4& a, const float4 v, float w){
  a.x += v.x*w; a.y += v.y*w; a.z += v.z*w; a.w += v.w*w;
}
__device__ __forceinline__ unsigned short f2bf(float f){
  unsigned int u = __float_as_uint(f);
  u += 0x7FFFu + ((u >> 16) & 1u);
  return (unsigned short)(u >> 16);
}
__device__ __forceinline__ float bf2f(unsigned short h){
  return __uint_as_float(((unsigned int)h) << 16);
}
__device__ __forceinline__ void split2(float v, unsigned short& h, unsigned short& l){
  h = f2bf(v);
  l = f2bf(v - bf2f(h));
}
__device__ __forceinline__ void store_hl(unsigned short* H, unsigned short* L,
                                         size_t base, float4 v){
  us4 h, l; unsigned short hh, ll;
  split2(v.x, hh, ll); h[0]=hh; l[0]=ll;
  split2(v.y, hh, ll); h[1]=hh; l[1]=ll;
  split2(v.z, hh, ll); h[2]=hh; l[2]=ll;
  split2(v.w, hh, ll); h[3]=hh; l[3]=ll;
  *(us4*)&H[base] = h;
  *(us4*)&L[base] = l;
}

// ================= CSR build =================
__global__ void k_count(const int* __restrict__ dst, int* __restrict__ cnt){
  int e = blockIdx.x*blockDim.x + threadIdx.x;
  if (e < NE) atomicAdd(&cnt[dst[e]], 1);
}
__global__ void k_dinv(const int* __restrict__ cnt, float* __restrict__ dinv){
  int n = blockIdx.x*blockDim.x + threadIdx.x;
  if (n < NN) dinv[n] = rsqrtf((float)cnt[n] + 1.f);
}
__global__ void k_scan(const int* __restrict__ cnt, int* __restrict__ rowptr){
  __shared__ int part[256];
  const int CH = (NN + 255) / 256;
  int t = threadIdx.x;
  int base = t * CH;
  int s = 0;
  for (int i = 0; i < CH; i++){ int idx = base + i; if (idx < NN) s += cnt[idx]; }
  part[t] = s; __syncthreads();
  for (int o = 1; o < 256; o <<= 1){
    int v = 0;
    if (t >= o) v = part[t - o];
    __syncthreads();
    if (t >= o) part[t] += v;
    __syncthreads();
  }
  int pre = (t == 0) ? 0 : part[t - 1];
  for (int i = 0; i < CH; i++){
    int idx = base + i;
    if (idx < NN){ rowptr[idx] = pre; pre += cnt[idx]; }
  }
  if (t == 255) rowptr[NN] = part[255];
}
__global__ void k_fill(const int* __restrict__ src, const int* __restrict__ dst,
                       const int* __restrict__ rowptr, int* __restrict__ cursor,
                       int* __restrict__ colidx){
  int e = blockIdx.x*blockDim.x + threadIdx.x;
  if (e >= NE) return;
  int d = dst[e];
  int pos = atomicAdd(&cursor[d], 1);
  colidx[rowptr[d] + pos] = src[e];
}

// ================= conversions =================
__global__ void k_convx0(const float* __restrict__ x0, unsigned short* __restrict__ xh,
                         unsigned short* __restrict__ xl){
  int idx = blockIdx.x*blockDim.x + threadIdx.x;
  if (idx >= NN*64) return;
  int n = idx >> 6, c = idx & 63;
  float v = (c < 36) ? x0[n*36 + c] : 0.f;
  unsigned short h, l; split2(v, h, l);
  xh[idx] = h; xl[idx] = l;
}
__global__ void k_wconv(const float* __restrict__ src, unsigned short* __restrict__ dh,
                        unsigned short* __restrict__ dl, int K, int M, int Kp){
  int idx = blockIdx.x*blockDim.x + threadIdx.x;
  if (idx >= Kp*M) return;
  int kk = idx % Kp, m = idx / Kp;
  float v = (kk < K) ? src[(size_t)kk*M + m] : 0.f;
  unsigned short h, l; split2(v, h, l);
  dh[idx] = h; dl[idx] = l;
}

// ================= GEMM: bf16x3 split MFMA =================
#define GBM 128
#define GBN 64
#define GBK 32
#define LDK 40
__global__ __launch_bounds__(256) void k_gemm_bf3(
    const unsigned short* __restrict__ Ah, const unsigned short* __restrict__ Al,
    const unsigned short* __restrict__ Bh, const unsigned short* __restrict__ Bl,
    float* __restrict__ C, int N, int Kp, int M){
  __shared__ unsigned short As[2][GBM][LDK];
  __shared__ unsigned short Bs[2][GBN][LDK];
  int gx = M / GBN;
  int gy = (N + GBM - 1) / GBM;
  const int G = 8;
  int bid = blockIdx.x;
  int full = gy / G;
  int bid_full = full * G * gx;
  int by, bx;
  if (bid < bid_full){
    int g = bid / (G*gx); int rem = bid % (G*gx);
    by = g*G + rem % G; bx = rem / G;
  } else {
    int rem = bid - bid_full; int rows = gy - full*G;
    by = full*G + rem % rows; bx = rem / rows;
  }
  int row0 = by * GBM, col0 = bx * GBN;
  int t = threadIdx.x;
  int w = t >> 6, L = t & 63;
  int lm = L & 15, lq = L >> 4;

  f32x4 acc[2][4];
#pragma unroll
  for (int i = 0; i < 2; i++)
#pragma unroll
    for (int j = 0; j < 4; j++) acc[i][j] = (f32x4){0.f,0.f,0.f,0.f};

  const short8 z8 = {0,0,0,0,0,0,0,0};
  int ar0 = t >> 2, ao0 = (t & 3) * 8;
  int ar1 = (t + 256) >> 2, ao1 = ao0;
  int br  = t >> 2, bo = (t & 3) * 8;

  int nk = Kp / GBK;
  for (int kt = 0; kt < nk; kt++){
    int k0 = kt * GBK;
    __syncthreads();
    short8 vh0 = (row0 + ar0 < N) ? *(const short8*)&Ah[(size_t)(row0+ar0)*Kp + k0 + ao0] : z8;
    short8 vl0 = (row0 + ar0 < N) ? *(const short8*)&Al[(size_t)(row0+ar0)*Kp + k0 + ao0] : z8;
    short8 vh1 = (row0 + ar1 < N) ? *(const short8*)&Ah[(size_t)(row0+ar1)*Kp + k0 + ao1] : z8;
    short8 vl1 = (row0 + ar1 < N) ? *(const short8*)&Al[(size_t)(row0+ar1)*Kp + k0 + ao1] : z8;
    *(short8*)&As[0][ar0][ao0] = vh0;
    *(short8*)&As[1][ar0][ao0] = vl0;
    *(short8*)&As[0][ar1][ao1] = vh1;
    *(short8*)&As[1][ar1][ao1] = vl1;
    short8 wh = *(const short8*)&Bh[(size_t)(col0+br)*Kp + k0 + bo];
    short8 wl = *(const short8*)&Bl[(size_t)(col0+br)*Kp + k0 + bo];
    *(short8*)&Bs[0][br][bo] = wh;
    *(short8*)&Bs[1][br][bo] = wl;
    __syncthreads();

    short8 afh[2], afl[2], bfh[4], bfl[4];
#pragma unroll
    for (int mi = 0; mi < 2; mi++){
      int r = w*32 + mi*16 + lm;
      afh[mi] = *(const short8*)&As[0][r][lq*8];
      afl[mi] = *(const short8*)&As[1][r][lq*8];
    }
#pragma unroll
    for (int ni = 0; ni < 4; ni++){
      int r = ni*16 + lm;
      bfh[ni] = *(const short8*)&Bs[0][r][lq*8];
      bfl[ni] = *(const short8*)&Bs[1][r][lq*8];
    }
#pragma unroll
    for (int mi = 0; mi < 2; mi++)
#pragma unroll
      for (int ni = 0; ni < 4; ni++){
        acc[mi][ni] = __builtin_amdgcn_mfma_f32_16x16x32_bf16(afh[mi], bfh[ni], acc[mi][ni], 0, 0, 0);
        acc[mi][ni] = __builtin_amdgcn_mfma_f32_16x16x32_bf16(afh[mi], bfl[ni], acc[mi][ni], 0, 0, 0);
        acc[mi][ni] = __builtin_amdgcn_mfma_f32_16x16x32_bf16(afl[mi], bfh[ni], acc[mi][ni], 0, 0, 0);
      }
  }
#pragma unroll
  for (int mi = 0; mi < 2; mi++)
#pragma unroll
    for (int ni = 0; ni < 4; ni++){
#pragma unroll
      for (int r = 0; r < 4; r++){
        int row = row0 + w*32 + mi*16 + lq*4 + r;
        int col = col0 + ni*16 + lm;
        if (row < N) C[(size_t)row*M + col] = acc[mi][ni][r];
      }
    }
}

// ===== GCN gather: feature-chunked (64 feats), XCD-aligned; 16 nodes/block =====
// chunk = blockIdx.x % nchunk -> on round-robin XCD dispatch each XCD's L2 holds
// only its 64-col slice of hw (2.56 MB), killing the 8x cross-XCD refetch.
__global__ __launch_bounds__(256) void k_gcn_gather(
    const float* __restrict__ hw, const float* __restrict__ dinv,
    const int* __restrict__ rowptr, const int* __restrict__ colidx,
    const float* __restrict__ gb,
    unsigned short* __restrict__ outH, unsigned short* __restrict__ outL,
    int M, int nchunk){
  int bid = blockIdx.x;
  int chunk = bid % nchunk, grp = bid / nchunk;
  int t = threadIdx.x;
  int sub = t & 15;
  int n = grp*16 + (t >> 4);
  if (n >= NN) return;
  int f0 = chunk*64 + sub*4;
  int b = rowptr[n], e = rowptr[n+1];
  float dn = dinv[n];
  float4 acc = make_float4(0,0,0,0);
  for (int j = b; j < e; j++){
    int s = colidx[j];
    float4 v = *(const float4*)&hw[(size_t)s*M + f0];
    fma4(acc, v, dinv[s]*dn);
  }
  float4 sv = *(const float4*)&hw[(size_t)n*M + f0];
  float4 bb = *(const float4*)&gb[f0];
  float dn2 = dn*dn;
  float4 r = make_float4(fmaxf(acc.x + sv.x*dn2 + bb.x, 0.f),
                         fmaxf(acc.y + sv.y*dn2 + bb.y, 0.f),
                         fmaxf(acc.z + sv.z*dn2 + bb.z, 0.f),
                         fmaxf(acc.w + sv.w*dn2 + bb.w, 0.f));
  store_hl(outH, outL, (size_t)n*M + f0, r);
}

// ================= GAT =================
__global__ void k_gat_alpha(const float* __restrict__ hg, const float* __restrict__ a_s,
                            const float* __restrict__ a_d, float* __restrict__ as_,
                            float* __restrict__ ad_, int M, int C){
  int idx = blockIdx.x*blockDim.x + threadIdx.x;
  if (idx >= NN*NH) return;
  int n = idx >> 2, hd = idx & 3;
  float ss = 0.f, dd = 0.f;
  const float* row = hg + (size_t)n*M + hd*C;
  const float* ws = a_s + hd*C;
  const float* wd = a_d + hd*C;
  for (int c = 0; c < C; c++){ float v = row[c]; ss += v*ws[c]; dd += v*wd[c]; }
  as_[idx] = ss; ad_[idx] = dd;
}
__global__ void k_gat_maxden(const int* __restrict__ rowptr, const int* __restrict__ colidx,
                             const float* __restrict__ as_, const float* __restrict__ ad_,
                             float* __restrict__ eself, float* __restrict__ den,
                             float* __restrict__ ealpha){
  int idx = blockIdx.x*blockDim.x + threadIdx.x;
  if (idx >= NN*NH) return;
  int n = idx >> 2, hd = idx & 3;
  float adn = ad_[idx];
  float selflog = leakyf(as_[idx] + adn);
  float m = selflog;
  int b = rowptr[n], e = rowptr[n+1];
  for (int j = b; j < e; j++){
    int s = colidx[j];
    m = fmaxf(m, leakyf(as_[s*NH + hd] + adn));
  }
  float es = expf(selflog - m);
  float dsum = es;
  for (int j = b; j < e; j++){
    int s = colidx[j];
    float v = expf(leakyf(as_[s*NH + hd] + adn) - m);
    ealpha[(size_t)j*NH + hd] = v;
    dsum += v;
  }
  eself[idx] = es;
  den[idx] = dsum;
}
// ===== GAT gather: feature-chunked, XCD-aligned; 16 nodes/block =====
__global__ __launch_bounds__(256) void k_gat_gather(
    const float* __restrict__ hg,
    const unsigned short* __restrict__ inH, const unsigned short* __restrict__ inL,
    const int* __restrict__ rowptr, const int* __restrict__ colidx,
    const float* __restrict__ ealpha, const float* __restrict__ eself,
    const float* __restrict__ den, const float* __restrict__ ab,
    unsigned short* __restrict__ outH, unsigned short* __restrict__ outL,
    int M, int C, int nchunk){
  int bid = blockIdx.x;
  int chunk = bid % nchunk, grp = bid / nchunk;
  int t = threadIdx.x;
  int sub = t & 15;
  int n = grp*16 + (t >> 4);
  if (n >= NN) return;
  int f0 = chunk*64 + sub*4;
  int hd = f0 / C;
  int b = rowptr[n], e = rowptr[n+1];
  float4 acc = make_float4(0,0,0,0);
  for (int j = b; j < e; j++){
    int s = colidx[j];
    float4 v = *(const float4*)&hg[(size_t)s*M + f0];
    fma4(acc, v, ealpha[(size_t)j*NH + hd]);
  }
  int ai = n*NH + hd;
  float es = eself[ai], inv = 1.f/den[ai];
  float4 sv = *(const float4*)&hg[(size_t)n*M + f0];
  us4 hh = *(const us4*)&inH[(size_t)n*M + f0];
  us4 hl = *(const us4*)&inL[(size_t)n*M + f0];
  float4 bb = *(const float4*)&ab[f0];
  float4 r = make_float4(
    bf2f(hh[0])+bf2f(hl[0]) + bb.x + (sv.x*es + acc.x)*inv,
    bf2f(hh[1])+bf2f(hl[1]) + bb.y + (sv.y*es + acc.y)*inv,
    bf2f(hh[2])+bf2f(hl[2]) + bb.z + (sv.z*es + acc.z)*inv,
    bf2f(hh[3])+bf2f(hl[3]) + bb.w + (sv.w*es + acc.w)*inv);
  store_hl(outH, outL, (size_t)n*M + f0, r);
}

// ================= attention pooling =================
__global__ void k_tanh_dot(const float* __restrict__ t1, const float* __restrict__ b1,
                           const float* __restrict__ w2, const float* __restrict__ b2,
                           float* __restrict__ apre){
  int n = blockIdx.x, t = threadIdx.x;
  float4 v  = ((const float4*)(t1 + (size_t)n*256))[t];
  float4 bb = ((const float4*)b1)[t];
  float4 ww = ((const float4*)w2)[t];
  float s = tanhf(v.x+bb.x)*ww.x + tanhf(v.y+bb.y)*ww.y
          + tanhf(v.z+bb.z)*ww.z + tanhf(v.w+bb.w)*ww.w;
  for (int o = 32; o > 0; o >>= 1) s += __shfl_xor(s, o);
  if (t == 0) apre[n] = s + b2[0];
}
__global__ void k_starts(const int* __restrict__ batch, int* __restrict__ starts){
  int g = threadIdx.x;
  if (g > NB) return;
  int lo = 0, hi = NN;
  while (lo < hi){ int mid = (lo + hi) >> 1; if (batch[mid] < g) lo = mid + 1; else hi = mid; }
  starts[g] = lo;
}
__global__ void k_pool_prep(const float* __restrict__ apre, const int* __restrict__ starts,
                            float* __restrict__ pw){
  int g = blockIdx.x, t = threadIdx.x;
  int b = starts[g], e = starts[g+1];
  float m = -INFINITY;
  for (int n = b + t; n < e; n += 64) m = fmaxf(m, apre[n]);
  for (int o = 32; o > 0; o >>= 1) m = fmaxf(m, __shfl_xor(m, o));
  float s = 0.f;
  for (int n = b + t; n < e; n += 64) s += expf(apre[n] - m);
  for (int o = 32; o > 0; o >>= 1) s += __shfl_xor(s, o);
  float inv = 1.f / (s + 1e-8f);
  for (int n = b + t; n < e; n += 64) pw[n] = expf(apre[n] - m) * inv;
}
__global__ void k_pool(const unsigned short* __restrict__ xH, const unsigned short* __restrict__ xL,
                       const float* __restrict__ pw, const int* __restrict__ starts,
                       float* __restrict__ out){
  int g = blockIdx.x, t = threadIdx.x;
  int b = starts[g], e = starts[g+1];
  float4 sum = make_float4(0,0,0,0), wacc = make_float4(0,0,0,0);
  float4 mx = make_float4(-INFINITY,-INFINITY,-INFINITY,-INFINITY);
  for (int n = b; n < e; n++){
    us4 xh = ((const us4*)(xH + (size_t)n*DOUT))[t];
    us4 xl = ((const us4*)(xL + (size_t)n*DOUT))[t];
    float4 xv = make_float4(bf2f(xh[0])+bf2f(xl[0]), bf2f(xh[1])+bf2f(xl[1]),
                            bf2f(xh[2])+bf2f(xl[2]), bf2f(xh[3])+bf2f(xl[3]));
    float p = pw[n];
    sum.x += xv.x; sum.y += xv.y; sum.z += xv.z; sum.w += xv.w;
    mx.x = fmaxf(mx.x, xv.x); mx.y = fmaxf(mx.y, xv.y);
    mx.z = fmaxf(mx.z, xv.z); mx.w = fmaxf(mx.w, xv.w);
    fma4(wacc, xv, p);
  }
  float ic = 1.f / fmaxf((float)(e - b), 1.f);
  float4* o = (float4*)(out + (size_t)g*4*DOUT);
  o[t]       = wacc;
  o[128 + t] = make_float4(sum.x*ic, sum.y*ic, sum.z*ic, sum.w*ic);
  o[256 + t] = mx;
  o[384 + t] = sum;
}

extern "C" void kernel_launch(void* const* d_in, const int* in_sizes, int n_in,
                              void* d_out, int out_size, void* d_ws, size_t ws_size,
                              hipStream_t stream) {
  const float* x0   = (const float*)d_in[0];
  const int*   ei   = (const int*)d_in[1];
  const int*   src  = ei;
  const int*   dst  = ei + NE;
  const int*   batch= (const int*)d_in[2];
  const float* gw[3]  = {(const float*)d_in[3],  (const float*)d_in[9],  (const float*)d_in[15]};
  const float* gb[3]  = {(const float*)d_in[4],  (const float*)d_in[10], (const float*)d_in[16]};
  const float* aw[3]  = {(const float*)d_in[5],  (const float*)d_in[11], (const float*)d_in[17]};
  const float* asw[3] = {(const float*)d_in[6],  (const float*)d_in[12], (const float*)d_in[18]};
  const float* adw[3] = {(const float*)d_in[7],  (const float*)d_in[13], (const float*)d_in[19]};
  const float* ab[3]  = {(const float*)d_in[8],  (const float*)d_in[14], (const float*)d_in[20]};
  const float* apw1 = (const float*)d_in[21];
  const float* apb1 = (const float*)d_in[22];
  const float* apw2 = (const float*)d_in[23];
  const float* apb2 = (const float*)d_in[24];
  float* out = (float*)d_out;

  // ---- workspace carve ----
  char* p = (char*)d_ws;
  auto alloc = [&](size_t bytes) -> void* {
    void* r = (void*)p; p += (bytes + 255) & ~(size_t)255; return r;
  };
  float* f1 = (float*)alloc((size_t)NN*512*4);
  unsigned short* actH0 = (unsigned short*)alloc((size_t)NN*512*2);
  unsigned short* actL0 = (unsigned short*)alloc((size_t)NN*512*2);
  unsigned short* actH1 = (unsigned short*)alloc((size_t)NN*512*2);
  unsigned short* actL1 = (unsigned short*)alloc((size_t)NN*512*2);
  unsigned short* x0h = (unsigned short*)alloc((size_t)NN*64*2);
  unsigned short* x0l = (unsigned short*)alloc((size_t)NN*64*2);
  const int wK[7]  = {36, 128, 128, 256, 256, 512, 512};
  const int wM[7]  = {128, 128, 256, 256, 512, 512, 256};
  const int wKp[7] = {64, 128, 128, 256, 256, 512, 512};
  const float* wsrc[7] = {gw[0], aw[0], gw[1], aw[1], gw[2], aw[2], apw1};
  unsigned short* wTh[7]; unsigned short* wTl[7];
  for (int i = 0; i < 7; i++){
    size_t sz = (size_t)wM[i]*wKp[i]*2;
    wTh[i] = (unsigned short*)alloc(sz);
    wTl[i] = (unsigned short*)alloc(sz);
  }
  float* ealpha = (float*)alloc((size_t)NE*NH*4);
  float* dinv = (float*)alloc(NN*4);
  float* as_  = (float*)alloc(NN*NH*4);
  float* ad_  = (float*)alloc(NN*NH*4);
  float* eself= (float*)alloc(NN*NH*4);
  float* den  = (float*)alloc(NN*NH*4);
  float* apre = (float*)alloc(NN*4);
  float* pw   = (float*)alloc(NN*4);
  int* rowptr = (int*)alloc((NN+1)*4);
  int* colidx = (int*)alloc((size_t)NE*4);
  int* cnt    = (int*)alloc(NN*4);
  int* cursor = (int*)alloc(NN*4);
  int* starts = (int*)alloc((NB+1)*4);

  // ---- CSR build + degrees + starts ----
  hipMemsetAsync(cnt, 0, NN*sizeof(int), stream);
  k_count<<<(NE+255)/256, 256, 0, stream>>>(dst, cnt);
  k_dinv<<<(NN+255)/256, 256, 0, stream>>>(cnt, dinv);
  k_scan<<<1, 256, 0, stream>>>(cnt, rowptr);
  hipMemsetAsync(cursor, 0, NN*sizeof(int), stream);
  k_fill<<<(NE+255)/256, 256, 0, stream>>>(src, dst, rowptr, cursor, colidx);
  k_starts<<<1, 256, 0, stream>>>(batch, starts);

  // ---- conversions ----
  k_convx0<<<(NN*64+255)/256, 256, 0, stream>>>(x0, x0h, x0l);
  for (int i = 0; i < 7; i++){
    int tot = wKp[i]*wM[i];
    k_wconv<<<(tot+255)/256, 256, 0, stream>>>(wsrc[i], wTh[i], wTl[i], wK[i], wM[i], wKp[i]);
  }

  auto gemm = [&](const unsigned short* Ahp, const unsigned short* Alp, int wi, int M){
    int nblk = (M/GBN) * ((NN+GBM-1)/GBM);
    k_gemm_bf3<<<nblk, 256, 0, stream>>>(Ahp, Alp, wTh[wi], wTl[wi], f1, NN, wKp[wi], M);
  };

  const int dims[4] = {36, 128, 256, 512};
  const int ngrp = (NN + 15) / 16;   // 625 node-groups of 16
  const unsigned short* curH = x0h; const unsigned short* curL = x0l;
  int wi = 0;
  for (int i = 0; i < 3; i++){
    int M = dims[i+1], C = M/NH;
    int nchunk = M / 64;
    // GCN
    gemm(curH, curL, wi++, M);
    k_gcn_gather<<<nchunk*ngrp, 256, 0, stream>>>(f1, dinv, rowptr, colidx, gb[i],
                                                  actH0, actL0, M, nchunk);
    // GAT
    gemm(actH0, actL0, wi++, M);
    k_gat_alpha<<<(NN*NH+255)/256, 256, 0, stream>>>(f1, asw[i], adw[i], as_, ad_, M, C);
    k_gat_maxden<<<(NN*NH+255)/256, 256, 0, stream>>>(rowptr, colidx, as_, ad_, eself, den, ealpha);
    k_gat_gather<<<nchunk*ngrp, 256, 0, stream>>>(f1, actH0, actL0, rowptr, colidx,
                                                  ealpha, eself, den, ab[i],
                                                  actH1, actL1, M, C, nchunk);
    curH = actH1; curL = actL1;
  }

  // ---- pooling ----
  gemm(actH1, actL1, 6, 256);
  k_tanh_dot<<<NN, 64, 0, stream>>>(f1, apb1, apw2, apb2, apre);
  k_pool_prep<<<NB, 64, 0, stream>>>(apre, starts, pw);
  k_pool<<<NB, 128, 0, stream>>>(actH1, actL1, pw, starts, out);
}

// Round 7
// 517.831 us; speedup vs baseline: 4.4592x; 1.1270x over previous
//
#include <hip/hip_runtime.h>
#include <math.h>

#define NN 10000
#define NE 160000
#define NB 128
#define NH 4
#define DOUT 512
#define NEG 0.2f

typedef __attribute__((ext_vector_type(8))) short short8;
typedef __attribute__((ext_vector_type(4))) float f32x4;
typedef __attribute__((ext_vector_type(4))) unsigned short us4;

__device__ __forceinline__ float leakyf(float v){ return v > 0.f ? v : NEG*v; }
__device__ __forceinline__ void fma4(float4& a, const float4 v, float w){
  a.x += v.x*w; a.y += v.y*w; a.z += v.z*w; a.w += v.w*w;
}
__device__ __forceinline__ unsigned short f2bf(float f){
  unsigned int u = __float_as_uint(f);
  u += 0x7FFFu + ((u >> 16) & 1u);
  return (unsigned short)(u >> 16);
}
__device__ __forceinline__ float bf2f(unsigned short h){
  return __uint_as_float(((unsigned int)h) << 16);
}
__device__ __forceinline__ void split2(float v, unsigned short& h, unsigned short& l){
  h = f2bf(v);
  l = f2bf(v - bf2f(h));
}
__device__ __forceinline__ void store_hl(unsigned short* H, unsigned short* L,
                                         size_t base, float4 v){
  us4 h, l; unsigned short hh, ll;
  split2(v.x, hh, ll); h[0]=hh; l[0]=ll;
  split2(v.y, hh, ll); h[1]=hh; l[1]=ll;
  split2(v.z, hh, ll); h[2]=hh; l[2]=ll;
  split2(v.w, hh, ll); h[3]=hh; l[3]=ll;
  *(us4*)&H[base] = h;
  *(us4*)&L[base] = l;
}

// ================= CSR build =================
__global__ void k_count(const int* __restrict__ dst, int* __restrict__ cnt){
  int e = blockIdx.x*blockDim.x + threadIdx.x;
  if (e < NE) atomicAdd(&cnt[dst[e]], 1);
}
__global__ void k_dinv(const int* __restrict__ cnt, float* __restrict__ dinv){
  int n = blockIdx.x*blockDim.x + threadIdx.x;
  if (n < NN) dinv[n] = rsqrtf((float)cnt[n] + 1.f);
}
__global__ void k_scan(const int* __restrict__ cnt, int* __restrict__ rowptr){
  __shared__ int part[256];
  const int CH = (NN + 255) / 256;
  int t = threadIdx.x;
  int base = t * CH;
  int s = 0;
  for (int i = 0; i < CH; i++){ int idx = base + i; if (idx < NN) s += cnt[idx]; }
  part[t] = s; __syncthreads();
  for (int o = 1; o < 256; o <<= 1){
    int v = 0;
    if (t >= o) v = part[t - o];
    __syncthreads();
    if (t >= o) part[t] += v;
    __syncthreads();
  }
  int pre = (t == 0) ? 0 : part[t - 1];
  for (int i = 0; i < CH; i++){
    int idx = base + i;
    if (idx < NN){ rowptr[idx] = pre; pre += cnt[idx]; }
  }
  if (t == 255) rowptr[NN] = part[255];
}
__global__ void k_fill(const int* __restrict__ src, const int* __restrict__ dst,
                       const int* __restrict__ rowptr, int* __restrict__ cursor,
                       int* __restrict__ colidx){
  int e = blockIdx.x*blockDim.x + threadIdx.x;
  if (e >= NE) return;
  int d = dst[e];
  int pos = atomicAdd(&cursor[d], 1);
  colidx[rowptr[d] + pos] = src[e];
}

// ================= conversions =================
__global__ void k_convx0(const float* __restrict__ x0, unsigned short* __restrict__ xh,
                         unsigned short* __restrict__ xl){
  int idx = blockIdx.x*blockDim.x + threadIdx.x;
  if (idx >= NN*64) return;
  int n = idx >> 6, c = idx & 63;
  float v = (c < 36) ? x0[n*36 + c] : 0.f;
  unsigned short h, l; split2(v, h, l);
  xh[idx] = h; xl[idx] = l;
}
__global__ void k_wconv(const float* __restrict__ src, unsigned short* __restrict__ dh,
                        unsigned short* __restrict__ dl, int K, int M, int Kp){
  int idx = blockIdx.x*blockDim.x + threadIdx.x;
  if (idx >= Kp*M) return;
  int kk = idx % Kp, m = idx / Kp;
  float v = (kk < K) ? src[(size_t)kk*M + m] : 0.f;
  unsigned short h, l; split2(v, h, l);
  dh[idx] = h; dl[idx] = l;
}

// ================= GEMM: bf16x3 split MFMA =================
#define GBM 128
#define GBN 64
#define GBK 32
#define LDK 40
__global__ __launch_bounds__(256) void k_gemm_bf3(
    const unsigned short* __restrict__ Ah, const unsigned short* __restrict__ Al,
    const unsigned short* __restrict__ Bh, const unsigned short* __restrict__ Bl,
    float* __restrict__ C, int N, int Kp, int M){
  __shared__ unsigned short As[2][GBM][LDK];
  __shared__ unsigned short Bs[2][GBN][LDK];
  int gx = M / GBN;
  int gy = (N + GBM - 1) / GBM;
  const int G = 8;
  int bid = blockIdx.x;
  int full = gy / G;
  int bid_full = full * G * gx;
  int by, bx;
  if (bid < bid_full){
    int g = bid / (G*gx); int rem = bid % (G*gx);
    by = g*G + rem % G; bx = rem / G;
  } else {
    int rem = bid - bid_full; int rows = gy - full*G;
    by = full*G + rem % rows; bx = rem / rows;
  }
  int row0 = by * GBM, col0 = bx * GBN;
  int t = threadIdx.x;
  int w = t >> 6, L = t & 63;
  int lm = L & 15, lq = L >> 4;

  f32x4 acc[2][4];
#pragma unroll
  for (int i = 0; i < 2; i++)
#pragma unroll
    for (int j = 0; j < 4; j++) acc[i][j] = (f32x4){0.f,0.f,0.f,0.f};

  const short8 z8 = {0,0,0,0,0,0,0,0};
  int ar0 = t >> 2, ao0 = (t & 3) * 8;
  int ar1 = (t + 256) >> 2, ao1 = ao0;
  int br  = t >> 2, bo = (t & 3) * 8;

  int nk = Kp / GBK;
  for (int kt = 0; kt < nk; kt++){
    int k0 = kt * GBK;
    __syncthreads();
    short8 vh0 = (row0 + ar0 < N) ? *(const short8*)&Ah[(size_t)(row0+ar0)*Kp + k0 + ao0] : z8;
    short8 vl0 = (row0 + ar0 < N) ? *(const short8*)&Al[(size_t)(row0+ar0)*Kp + k0 + ao0] : z8;
    short8 vh1 = (row0 + ar1 < N) ? *(const short8*)&Ah[(size_t)(row0+ar1)*Kp + k0 + ao1] : z8;
    short8 vl1 = (row0 + ar1 < N) ? *(const short8*)&Al[(size_t)(row0+ar1)*Kp + k0 + ao1] : z8;
    *(short8*)&As[0][ar0][ao0] = vh0;
    *(short8*)&As[1][ar0][ao0] = vl0;
    *(short8*)&As[0][ar1][ao1] = vh1;
    *(short8*)&As[1][ar1][ao1] = vl1;
    short8 wh = *(const short8*)&Bh[(size_t)(col0+br)*Kp + k0 + bo];
    short8 wl = *(const short8*)&Bl[(size_t)(col0+br)*Kp + k0 + bo];
    *(short8*)&Bs[0][br][bo] = wh;
    *(short8*)&Bs[1][br][bo] = wl;
    __syncthreads();

    short8 afh[2], afl[2], bfh[4], bfl[4];
#pragma unroll
    for (int mi = 0; mi < 2; mi++){
      int r = w*32 + mi*16 + lm;
      afh[mi] = *(const short8*)&As[0][r][lq*8];
      afl[mi] = *(const short8*)&As[1][r][lq*8];
    }
#pragma unroll
    for (int ni = 0; ni < 4; ni++){
      int r = ni*16 + lm;
      bfh[ni] = *(const short8*)&Bs[0][r][lq*8];
      bfl[ni] = *(const short8*)&Bs[1][r][lq*8];
    }
#pragma unroll
    for (int mi = 0; mi < 2; mi++)
#pragma unroll
      for (int ni = 0; ni < 4; ni++){
        acc[mi][ni] = __builtin_amdgcn_mfma_f32_16x16x32_bf16(afh[mi], bfh[ni], acc[mi][ni], 0, 0, 0);
        acc[mi][ni] = __builtin_amdgcn_mfma_f32_16x16x32_bf16(afh[mi], bfl[ni], acc[mi][ni], 0, 0, 0);
        acc[mi][ni] = __builtin_amdgcn_mfma_f32_16x16x32_bf16(afl[mi], bfh[ni], acc[mi][ni], 0, 0, 0);
      }
  }
#pragma unroll
  for (int mi = 0; mi < 2; mi++)
#pragma unroll
    for (int ni = 0; ni < 4; ni++){
#pragma unroll
      for (int r = 0; r < 4; r++){
        int row = row0 + w*32 + mi*16 + lq*4 + r;
        int col = col0 + ni*16 + lm;
        if (row < N) C[(size_t)row*M + col] = acc[mi][ni][r];
      }
    }
}

// ===== GCN gather: feature-chunked, XCD-aligned, 4-way edge-unrolled =====
__global__ __launch_bounds__(256) void k_gcn_gather(
    const float* __restrict__ hw, const float* __restrict__ dinv,
    const int* __restrict__ rowptr, const int* __restrict__ colidx,
    const float* __restrict__ gb,
    unsigned short* __restrict__ outH, unsigned short* __restrict__ outL,
    int M, int nchunk){
  int bid = blockIdx.x;
  int chunk = bid % nchunk, grp = bid / nchunk;
  int t = threadIdx.x;
  int sub = t & 15;
  int n = grp*16 + (t >> 4);
  if (n >= NN) return;
  int f0 = chunk*64 + sub*4;
  int b = rowptr[n], e = rowptr[n+1];
  float dn = dinv[n];
  float4 a0 = make_float4(0,0,0,0), a1 = make_float4(0,0,0,0);
  float4 a2 = make_float4(0,0,0,0), a3 = make_float4(0,0,0,0);
  int j = b;
  for (; j + 3 < e; j += 4){
    int s0 = colidx[j], s1 = colidx[j+1], s2 = colidx[j+2], s3 = colidx[j+3];
    float w0 = dinv[s0], w1 = dinv[s1], w2 = dinv[s2], w3 = dinv[s3];
    float4 v0 = *(const float4*)&hw[(size_t)s0*M + f0];
    float4 v1 = *(const float4*)&hw[(size_t)s1*M + f0];
    float4 v2 = *(const float4*)&hw[(size_t)s2*M + f0];
    float4 v3 = *(const float4*)&hw[(size_t)s3*M + f0];
    fma4(a0, v0, w0*dn); fma4(a1, v1, w1*dn);
    fma4(a2, v2, w2*dn); fma4(a3, v3, w3*dn);
  }
  for (; j < e; j++){
    int s = colidx[j];
    float4 v = *(const float4*)&hw[(size_t)s*M + f0];
    fma4(a0, v, dinv[s]*dn);
  }
  float4 acc = make_float4(a0.x+a1.x+a2.x+a3.x, a0.y+a1.y+a2.y+a3.y,
                           a0.z+a1.z+a2.z+a3.z, a0.w+a1.w+a2.w+a3.w);
  float4 sv = *(const float4*)&hw[(size_t)n*M + f0];
  float4 bb = *(const float4*)&gb[f0];
  float dn2 = dn*dn;
  float4 r = make_float4(fmaxf(acc.x + sv.x*dn2 + bb.x, 0.f),
                         fmaxf(acc.y + sv.y*dn2 + bb.y, 0.f),
                         fmaxf(acc.z + sv.z*dn2 + bb.z, 0.f),
                         fmaxf(acc.w + sv.w*dn2 + bb.w, 0.f));
  store_hl(outH, outL, (size_t)n*M + f0, r);
}

// ================= GAT =================
__global__ void k_gat_alpha(const float* __restrict__ hg, const float* __restrict__ a_s,
                            const float* __restrict__ a_d, float* __restrict__ as_,
                            float* __restrict__ ad_, int M, int C){
  int idx = blockIdx.x*blockDim.x + threadIdx.x;
  if (idx >= NN*NH) return;
  int n = idx >> 2, hd = idx & 3;
  float ss = 0.f, dd = 0.f;
  const float* row = hg + (size_t)n*M + hd*C;
  const float* ws = a_s + hd*C;
  const float* wd = a_d + hd*C;
  for (int c = 0; c < C; c++){ float v = row[c]; ss += v*ws[c]; dd += v*wd[c]; }
  as_[idx] = ss; ad_[idx] = dd;
}
// 4-way unrolled max + exp-sum passes
__global__ void k_gat_maxden(const int* __restrict__ rowptr, const int* __restrict__ colidx,
                             const float* __restrict__ as_, const float* __restrict__ ad_,
                             float* __restrict__ eself, float* __restrict__ den,
                             float* __restrict__ ealpha){
  int idx = blockIdx.x*blockDim.x + threadIdx.x;
  if (idx >= NN*NH) return;
  int n = idx >> 2, hd = idx & 3;
  float adn = ad_[idx];
  float selflog = leakyf(as_[idx] + adn);
  int b = rowptr[n], e = rowptr[n+1];
  float m0 = selflog, m1 = -INFINITY, m2 = -INFINITY, m3 = -INFINITY;
  int j = b;
  for (; j + 3 < e; j += 4){
    int s0 = colidx[j], s1 = colidx[j+1], s2 = colidx[j+2], s3 = colidx[j+3];
    float q0 = as_[s0*NH + hd], q1 = as_[s1*NH + hd];
    float q2 = as_[s2*NH + hd], q3 = as_[s3*NH + hd];
    m0 = fmaxf(m0, leakyf(q0 + adn)); m1 = fmaxf(m1, leakyf(q1 + adn));
    m2 = fmaxf(m2, leakyf(q2 + adn)); m3 = fmaxf(m3, leakyf(q3 + adn));
  }
  for (; j < e; j++) m0 = fmaxf(m0, leakyf(as_[colidx[j]*NH + hd] + adn));
  float m = fmaxf(fmaxf(m0, m1), fmaxf(m2, m3));
  float es = expf(selflog - m);
  float d0 = es, d1 = 0.f, d2 = 0.f, d3 = 0.f;
  j = b;
  for (; j + 3 < e; j += 4){
    int s0 = colidx[j], s1 = colidx[j+1], s2 = colidx[j+2], s3 = colidx[j+3];
    float q0 = as_[s0*NH + hd], q1 = as_[s1*NH + hd];
    float q2 = as_[s2*NH + hd], q3 = as_[s3*NH + hd];
    float v0 = expf(leakyf(q0 + adn) - m), v1 = expf(leakyf(q1 + adn) - m);
    float v2 = expf(leakyf(q2 + adn) - m), v3 = expf(leakyf(q3 + adn) - m);
    ealpha[(size_t)(j+0)*NH + hd] = v0; ealpha[(size_t)(j+1)*NH + hd] = v1;
    ealpha[(size_t)(j+2)*NH + hd] = v2; ealpha[(size_t)(j+3)*NH + hd] = v3;
    d0 += v0; d1 += v1; d2 += v2; d3 += v3;
  }
  for (; j < e; j++){
    float v = expf(leakyf(as_[colidx[j]*NH + hd] + adn) - m);
    ealpha[(size_t)j*NH + hd] = v;
    d0 += v;
  }
  eself[idx] = es;
  den[idx] = (d0 + d1) + (d2 + d3);
}
// ===== GAT gather: feature-chunked, XCD-aligned, 4-way edge-unrolled =====
__global__ __launch_bounds__(256) void k_gat_gather(
    const float* __restrict__ hg,
    const unsigned short* __restrict__ inH, const unsigned short* __restrict__ inL,
    const int* __restrict__ rowptr, const int* __restrict__ colidx,
    const float* __restrict__ ealpha, const float* __restrict__ eself,
    const float* __restrict__ den, const float* __restrict__ ab,
    unsigned short* __restrict__ outH, unsigned short* __restrict__ outL,
    int M, int C, int nchunk){
  int bid = blockIdx.x;
  int chunk = bid % nchunk, grp = bid / nchunk;
  int t = threadIdx.x;
  int sub = t & 15;
  int n = grp*16 + (t >> 4);
  if (n >= NN) return;
  int f0 = chunk*64 + sub*4;
  int hd = f0 / C;
  int b = rowptr[n], e = rowptr[n+1];
  float4 a0 = make_float4(0,0,0,0), a1 = make_float4(0,0,0,0);
  float4 a2 = make_float4(0,0,0,0), a3 = make_float4(0,0,0,0);
  int j = b;
  for (; j + 3 < e; j += 4){
    int s0 = colidx[j], s1 = colidx[j+1], s2 = colidx[j+2], s3 = colidx[j+3];
    float e0 = ealpha[(size_t)(j+0)*NH + hd], e1 = ealpha[(size_t)(j+1)*NH + hd];
    float e2 = ealpha[(size_t)(j+2)*NH + hd], e3 = ealpha[(size_t)(j+3)*NH + hd];
    float4 v0 = *(const float4*)&hg[(size_t)s0*M + f0];
    float4 v1 = *(const float4*)&hg[(size_t)s1*M + f0];
    float4 v2 = *(const float4*)&hg[(size_t)s2*M + f0];
    float4 v3 = *(const float4*)&hg[(size_t)s3*M + f0];
    fma4(a0, v0, e0); fma4(a1, v1, e1);
    fma4(a2, v2, e2); fma4(a3, v3, e3);
  }
  for (; j < e; j++){
    int s = colidx[j];
    float4 v = *(const float4*)&hg[(size_t)s*M + f0];
    fma4(a0, v, ealpha[(size_t)j*NH + hd]);
  }
  float4 acc = make_float4(a0.x+a1.x+a2.x+a3.x, a0.y+a1.y+a2.y+a3.y,
                           a0.z+a1.z+a2.z+a3.z, a0.w+a1.w+a2.w+a3.w);
  int ai = n*NH + hd;
  float es = eself[ai], inv = 1.f/den[ai];
  float4 sv = *(const float4*)&hg[(size_t)n*M + f0];
  us4 hh = *(const us4*)&inH[(size_t)n*M + f0];
  us4 hl = *(const us4*)&inL[(size_t)n*M + f0];
  float4 bb = *(const float4*)&ab[f0];
  float4 r = make_float4(
    bf2f(hh[0])+bf2f(hl[0]) + bb.x + (sv.x*es + acc.x)*inv,
    bf2f(hh[1])+bf2f(hl[1]) + bb.y + (sv.y*es + acc.y)*inv,
    bf2f(hh[2])+bf2f(hl[2]) + bb.z + (sv.z*es + acc.z)*inv,
    bf2f(hh[3])+bf2f(hl[3]) + bb.w + (sv.w*es + acc.w)*inv);
  store_hl(outH, outL, (size_t)n*M + f0, r);
}

// ================= attention pooling =================
__global__ void k_tanh_dot(const float* __restrict__ t1, const float* __restrict__ b1,
                           const float* __restrict__ w2, const float* __restrict__ b2,
                           float* __restrict__ apre){
  int n = blockIdx.x, t = threadIdx.x;
  float4 v  = ((const float4*)(t1 + (size_t)n*256))[t];
  float4 bb = ((const float4*)b1)[t];
  float4 ww = ((const float4*)w2)[t];
  float s = tanhf(v.x+bb.x)*ww.x + tanhf(v.y+bb.y)*ww.y
          + tanhf(v.z+bb.z)*ww.z + tanhf(v.w+bb.w)*ww.w;
  for (int o = 32; o > 0; o >>= 1) s += __shfl_xor(s, o);
  if (t == 0) apre[n] = s + b2[0];
}
__global__ void k_starts(const int* __restrict__ batch, int* __restrict__ starts){
  int g = threadIdx.x;
  if (g > NB) return;
  int lo = 0, hi = NN;
  while (lo < hi){ int mid = (lo + hi) >> 1; if (batch[mid] < g) lo = mid + 1; else hi = mid; }
  starts[g] = lo;
}
__global__ void k_pool_prep(const float* __restrict__ apre, const int* __restrict__ starts,
                            float* __restrict__ pw){
  int g = blockIdx.x, t = threadIdx.x;
  int b = starts[g], e = starts[g+1];
  float m = -INFINITY;
  for (int n = b + t; n < e; n += 64) m = fmaxf(m, apre[n]);
  for (int o = 32; o > 0; o >>= 1) m = fmaxf(m, __shfl_xor(m, o));
  float s = 0.f;
  for (int n = b + t; n < e; n += 64) s += expf(apre[n] - m);
  for (int o = 32; o > 0; o >>= 1) s += __shfl_xor(s, o);
  float inv = 1.f / (s + 1e-8f);
  for (int n = b + t; n < e; n += 64) pw[n] = expf(apre[n] - m) * inv;
}
__global__ void k_pool(const unsigned short* __restrict__ xH, const unsigned short* __restrict__ xL,
                       const float* __restrict__ pw, const int* __restrict__ starts,
                       float* __restrict__ out){
  int g = blockIdx.x, t = threadIdx.x;
  int b = starts[g], e = starts[g+1];
  float4 sum = make_float4(0,0,0,0), wacc = make_float4(0,0,0,0);
  float4 mx = make_float4(-INFINITY,-INFINITY,-INFINITY,-INFINITY);
  for (int n = b; n < e; n++){
    us4 xh = ((const us4*)(xH + (size_t)n*DOUT))[t];
    us4 xl = ((const us4*)(xL + (size_t)n*DOUT))[t];
    float4 xv = make_float4(bf2f(xh[0])+bf2f(xl[0]), bf2f(xh[1])+bf2f(xl[1]),
                            bf2f(xh[2])+bf2f(xl[2]), bf2f(xh[3])+bf2f(xl[3]));
    float p = pw[n];
    sum.x += xv.x; sum.y += xv.y; sum.z += xv.z; sum.w += xv.w;
    mx.x = fmaxf(mx.x, xv.x); mx.y = fmaxf(mx.y, xv.y);
    mx.z = fmaxf(mx.z, xv.z); mx.w = fmaxf(mx.w, xv.w);
    fma4(wacc, xv, p);
  }
  float ic = 1.f / fmaxf((float)(e - b), 1.f);
  float4* o = (float4*)(out + (size_t)g*4*DOUT);
  o[t]       = wacc;
  o[128 + t] = make_float4(sum.x*ic, sum.y*ic, sum.z*ic, sum.w*ic);
  o[256 + t] = mx;
  o[384 + t] = sum;
}

extern "C" void kernel_launch(void* const* d_in, const int* in_sizes, int n_in,
                              void* d_out, int out_size, void* d_ws, size_t ws_size,
                              hipStream_t stream) {
  const float* x0   = (const float*)d_in[0];
  const int*   ei   = (const int*)d_in[1];
  const int*   src  = ei;
  const int*   dst  = ei + NE;
  const int*   batch= (const int*)d_in[2];
  const float* gw[3]  = {(const float*)d_in[3],  (const float*)d_in[9],  (const float*)d_in[15]};
  const float* gb[3]  = {(const float*)d_in[4],  (const float*)d_in[10], (const float*)d_in[16]};
  const float* aw[3]  = {(const float*)d_in[5],  (const float*)d_in[11], (const float*)d_in[17]};
  const float* asw[3] = {(const float*)d_in[6],  (const float*)d_in[12], (const float*)d_in[18]};
  const float* adw[3] = {(const float*)d_in[7],  (const float*)d_in[13], (const float*)d_in[19]};
  const float* ab[3]  = {(const float*)d_in[8],  (const float*)d_in[14], (const float*)d_in[20]};
  const float* apw1 = (const float*)d_in[21];
  const float* apb1 = (const float*)d_in[22];
  const float* apw2 = (const float*)d_in[23];
  const float* apb2 = (const float*)d_in[24];
  float* out = (float*)d_out;

  // ---- workspace carve ----
  char* p = (char*)d_ws;
  auto alloc = [&](size_t bytes) -> void* {
    void* r = (void*)p; p += (bytes + 255) & ~(size_t)255; return r;
  };
  float* f1 = (float*)alloc((size_t)NN*512*4);
  unsigned short* actH0 = (unsigned short*)alloc((size_t)NN*512*2);
  unsigned short* actL0 = (unsigned short*)alloc((size_t)NN*512*2);
  unsigned short* actH1 = (unsigned short*)alloc((size_t)NN*512*2);
  unsigned short* actL1 = (unsigned short*)alloc((size_t)NN*512*2);
  unsigned short* x0h = (unsigned short*)alloc((size_t)NN*64*2);
  unsigned short* x0l = (unsigned short*)alloc((size_t)NN*64*2);
  const int wK[7]  = {36, 128, 128, 256, 256, 512, 512};
  const int wM[7]  = {128, 128, 256, 256, 512, 512, 256};
  const int wKp[7] = {64, 128, 128, 256, 256, 512, 512};
  const float* wsrc[7] = {gw[0], aw[0], gw[1], aw[1], gw[2], aw[2], apw1};
  unsigned short* wTh[7]; unsigned short* wTl[7];
  for (int i = 0; i < 7; i++){
    size_t sz = (size_t)wM[i]*wKp[i]*2;
    wTh[i] = (unsigned short*)alloc(sz);
    wTl[i] = (unsigned short*)alloc(sz);
  }
  float* ealpha = (float*)alloc((size_t)NE*NH*4);
  float* dinv = (float*)alloc(NN*4);
  float* as_  = (float*)alloc(NN*NH*4);
  float* ad_  = (float*)alloc(NN*NH*4);
  float* eself= (float*)alloc(NN*NH*4);
  float* den  = (float*)alloc(NN*NH*4);
  float* apre = (float*)alloc(NN*4);
  float* pw   = (float*)alloc(NN*4);
  int* rowptr = (int*)alloc((NN+1)*4);
  int* colidx = (int*)alloc((size_t)NE*4);
  int* cnt    = (int*)alloc(NN*4);
  int* cursor = (int*)alloc(NN*4);
  int* starts = (int*)alloc((NB+1)*4);

  // ---- CSR build + degrees + starts ----
  hipMemsetAsync(cnt, 0, NN*sizeof(int), stream);
  k_count<<<(NE+255)/256, 256, 0, stream>>>(dst, cnt);
  k_dinv<<<(NN+255)/256, 256, 0, stream>>>(cnt, dinv);
  k_scan<<<1, 256, 0, stream>>>(cnt, rowptr);
  hipMemsetAsync(cursor, 0, NN*sizeof(int), stream);
  k_fill<<<(NE+255)/256, 256, 0, stream>>>(src, dst, rowptr, cursor, colidx);
  k_starts<<<1, 256, 0, stream>>>(batch, starts);

  // ---- conversions ----
  k_convx0<<<(NN*64+255)/256, 256, 0, stream>>>(x0, x0h, x0l);
  for (int i = 0; i < 7; i++){
    int tot = wKp[i]*wM[i];
    k_wconv<<<(tot+255)/256, 256, 0, stream>>>(wsrc[i], wTh[i], wTl[i], wK[i], wM[i], wKp[i]);
  }

  auto gemm = [&](const unsigned short* Ahp, const unsigned short* Alp, int wi, int M){
    int nblk = (M/GBN) * ((NN+GBM-1)/GBM);
    k_gemm_bf3<<<nblk, 256, 0, stream>>>(Ahp, Alp, wTh[wi], wTl[wi], f1, NN, wKp[wi], M);
  };

  const int dims[4] = {36, 128, 256, 512};
  const int ngrp = (NN + 15) / 16;
  const unsigned short* curH = x0h; const unsigned short* curL = x0l;
  int wi = 0;
  for (int i = 0; i < 3; i++){
    int M = dims[i+1], C = M/NH;
    int nchunk = M / 64;
    // GCN
    gemm(curH, curL, wi++, M);
    k_gcn_gather<<<nchunk*ngrp, 256, 0, stream>>>(f1, dinv, rowptr, colidx, gb[i],
                                                  actH0, actL0, M, nchunk);
    // GAT
    gemm(actH0, actL0, wi++, M);
    k_gat_alpha<<<(NN*NH+255)/256, 256, 0, stream>>>(f1, asw[i], adw[i], as_, ad_, M, C);
    k_gat_maxden<<<(NN*NH+255)/256, 256, 0, stream>>>(rowptr, colidx, as_, ad_, eself, den, ealpha);
    k_gat_gather<<<nchunk*ngrp, 256, 0, stream>>>(f1, actH0, actL0, rowptr, colidx,
                                                  ealpha, eself, den, ab[i],
                                                  actH1, actL1, M, C, nchunk);
    curH = actH1; curL = actL1;
  }

  // ---- pooling ----
  gemm(actH1, actL1, 6, 256);
  k_tanh_dot<<<NN, 64, 0, stream>>>(f1, apb1, apw2, apb2, apre);
  k_pool_prep<<<NB, 64, 0, stream>>>(apre, starts, pw);
  k_pool<<<NB, 128, 0, stream>>>(actH1, actL1, pw, starts, out);
}

// Round 8
// 498.359 us; speedup vs baseline: 4.6334x; 1.0391x over previous
//
#include <hip/hip_runtime.h>
#include <math.h>

#define NN 10000
#define NE 160000
#define NB 128
#define NH 4
#define DOUT 512
#define NEG 0.2f

typedef __attribute__((ext_vector_type(8))) short short8;
typedef __attribute__((ext_vector_type(4))) float f32x4;
typedef __attribute__((ext_vector_type(4))) unsigned short us4;

__device__ __forceinline__ float leakyf(float v){ return v > 0.f ? v : NEG*v; }
__device__ __forceinline__ void fma4(float4& a, const float4 v, float w){
  a.x += v.x*w; a.y += v.y*w; a.z += v.z*w; a.w += v.w*w;
}
__device__ __forceinline__ unsigned short f2bf(float f){
  unsigned int u = __float_as_uint(f);
  u += 0x7FFFu + ((u >> 16) & 1u);
  return (unsigned short)(u >> 16);
}
__device__ __forceinline__ float bf2f(unsigned short h){
  return __uint_as_float(((unsigned int)h) << 16);
}
__device__ __forceinline__ void split2(float v, unsigned short& h, unsigned short& l){
  h = f2bf(v);
  l = f2bf(v - bf2f(h));
}
__device__ __forceinline__ void store_hl(unsigned short* H, unsigned short* L,
                                         size_t base, float4 v){
  us4 h, l; unsigned short hh, ll;
  split2(v.x, hh, ll); h[0]=hh; l[0]=ll;
  split2(v.y, hh, ll); h[1]=hh; l[1]=ll;
  split2(v.z, hh, ll); h[2]=hh; l[2]=ll;
  split2(v.w, hh, ll); h[3]=hh; l[3]=ll;
  *(us4*)&H[base] = h;
  *(us4*)&L[base] = l;
}
// async global->LDS, 16B per lane; LDS dest = uniform base + lane*16
__device__ __forceinline__ void gl_lds16(const unsigned short* g, unsigned short* l){
  __builtin_amdgcn_global_load_lds(
      (const __attribute__((address_space(1))) unsigned int*)g,
      (__attribute__((address_space(3))) unsigned int*)l, 16, 0, 0);
}

// ================= CSR build =================
__global__ void k_count(const int* __restrict__ dst, int* __restrict__ cnt){
  int e = blockIdx.x*blockDim.x + threadIdx.x;
  if (e < NE) atomicAdd(&cnt[dst[e]], 1);
}
__global__ void k_dinv(const int* __restrict__ cnt, float* __restrict__ dinv){
  int n = blockIdx.x*blockDim.x + threadIdx.x;
  if (n < NN) dinv[n] = rsqrtf((float)cnt[n] + 1.f);
}
__global__ void k_scan(const int* __restrict__ cnt, int* __restrict__ rowptr){
  __shared__ int part[256];
  const int CH = (NN + 255) / 256;
  int t = threadIdx.x;
  int base = t * CH;
  int s = 0;
  for (int i = 0; i < CH; i++){ int idx = base + i; if (idx < NN) s += cnt[idx]; }
  part[t] = s; __syncthreads();
  for (int o = 1; o < 256; o <<= 1){
    int v = 0;
    if (t >= o) v = part[t - o];
    __syncthreads();
    if (t >= o) part[t] += v;
    __syncthreads();
  }
  int pre = (t == 0) ? 0 : part[t - 1];
  for (int i = 0; i < CH; i++){
    int idx = base + i;
    if (idx < NN){ rowptr[idx] = pre; pre += cnt[idx]; }
  }
  if (t == 255) rowptr[NN] = part[255];
}
__global__ void k_fill(const int* __restrict__ src, const int* __restrict__ dst,
                       const int* __restrict__ rowptr, int* __restrict__ cursor,
                       int* __restrict__ colidx){
  int e = blockIdx.x*blockDim.x + threadIdx.x;
  if (e >= NE) return;
  int d = dst[e];
  int pos = atomicAdd(&cursor[d], 1);
  colidx[rowptr[d] + pos] = src[e];
}

// ================= conversions =================
__global__ void k_convx0(const float* __restrict__ x0, unsigned short* __restrict__ xh,
                         unsigned short* __restrict__ xl){
  int idx = blockIdx.x*blockDim.x + threadIdx.x;
  if (idx >= NN*64) return;
  int n = idx >> 6, c = idx & 63;
  float v = (c < 36) ? x0[n*36 + c] : 0.f;
  unsigned short h, l; split2(v, h, l);
  xh[idx] = h; xl[idx] = l;
}
__global__ void k_wconv(const float* __restrict__ src, unsigned short* __restrict__ dh,
                        unsigned short* __restrict__ dl, int K, int M, int Kp){
  int idx = blockIdx.x*blockDim.x + threadIdx.x;
  if (idx >= Kp*M) return;
  int kk = idx % Kp, m = idx / Kp;
  float v = (kk < K) ? src[(size_t)kk*M + m] : 0.f;
  unsigned short h, l; split2(v, h, l);
  dh[idx] = h; dl[idx] = l;
}

// ===== GEMM: C[N,M] = (Ah+Al)[N,Kp] @ (Bh+Bl)^T, bf16x3, m97-style =====
// 128x128 tile, 4 waves x (4x4 16x16 MFMA tiles), global_load_lds staging.
// LDS unpadded [row][32] bf16 with source-side chunk swizzle: position c of
// row r holds global chunk g=(c-(r>>1))&3 -> frag reads are 2-way/bank (free).
#define GBM 128
#define GBN 128
#define GBK 32
__global__ __launch_bounds__(256) void k_gemm_bf3(
    const unsigned short* __restrict__ Ah, const unsigned short* __restrict__ Al,
    const unsigned short* __restrict__ Bh, const unsigned short* __restrict__ Bl,
    float* __restrict__ C, int N, int Kp, int M){
  __shared__ unsigned short AsH[GBM*GBK], AsL[GBM*GBK];
  __shared__ unsigned short BsH[GBN*GBK], BsL[GBN*GBK];
  int gx = M / GBN;
  int gy = (N + GBM - 1) / GBM;
  const int G = 8;
  int bid = blockIdx.x;
  int full = gy / G;
  int bid_full = full * G * gx;
  int by, bx;
  if (bid < bid_full){
    int g = bid / (G*gx); int rem = bid % (G*gx);
    by = g*G + rem % G; bx = rem / G;
  } else {
    int rem = bid - bid_full; int rows = gy - full*G;
    by = full*G + rem % rows; bx = rem / rows;
  }
  int row0 = by * GBM, col0 = bx * GBN;
  int t = threadIdx.x;
  int w = t >> 6, L = t & 63;
  int lm = L & 15, lq = L >> 4;
  int wr = (w >> 1) * 64, wc = (w & 1) * 64;

  // staging: wave w stages 16-row slabs {2w, 2w+1} of each 128-row tile.
  // lane L -> sub-row L>>2, slot c=L&3, fetches global chunk g=(c-(row>>1))&3
  int sr0 = (2*w)*16 + (L >> 2);
  int sr1 = (2*w+1)*16 + (L >> 2);
  int sc  = L & 3;
  int g0 = (sc - ((sr0 >> 1) & 3)) & 3;
  int g1 = (sc - ((sr1 >> 1) & 3)) & 3;
  int a0r = min(row0 + sr0, N-1);       // clamp tail (outputs guarded)
  int a1r = min(row0 + sr1, N-1);
  int b0r = col0 + sr0, b1r = col0 + sr1;
  unsigned short* dst0 = (unsigned short*)0; // silence unused warn pattern

  // frag read offsets (swizzled): c = (lq + (lm>>1)) & 3
  int rc = (lq + (lm >> 1)) & 3;
  int aoff[4], boff[4];
#pragma unroll
  for (int mi = 0; mi < 4; mi++) aoff[mi] = (wr + mi*16 + lm)*32 + rc*8;
#pragma unroll
  for (int ni = 0; ni < 4; ni++) boff[ni] = (wc + ni*16 + lm)*32 + rc*8;

  f32x4 acc[4][4];
#pragma unroll
  for (int i = 0; i < 4; i++)
#pragma unroll
    for (int j = 0; j < 4; j++) acc[i][j] = (f32x4){0.f,0.f,0.f,0.f};

  int nk = Kp / GBK;
  for (int kt = 0; kt < nk; kt++){
    int k0 = kt * GBK;
    if (kt) __syncthreads();       // previous reads complete before overwrite
    gl_lds16(&Ah[(size_t)a0r*Kp + k0 + g0*8], &AsH[(2*w)*512]);
    gl_lds16(&Ah[(size_t)a1r*Kp + k0 + g1*8], &AsH[(2*w+1)*512]);
    gl_lds16(&Al[(size_t)a0r*Kp + k0 + g0*8], &AsL[(2*w)*512]);
    gl_lds16(&Al[(size_t)a1r*Kp + k0 + g1*8], &AsL[(2*w+1)*512]);
    gl_lds16(&Bh[(size_t)b0r*Kp + k0 + g0*8], &BsH[(2*w)*512]);
    gl_lds16(&Bh[(size_t)b1r*Kp + k0 + g1*8], &BsH[(2*w+1)*512]);
    gl_lds16(&Bl[(size_t)b0r*Kp + k0 + g0*8], &BsL[(2*w)*512]);
    gl_lds16(&Bl[(size_t)b1r*Kp + k0 + g1*8], &BsL[(2*w+1)*512]);
    __syncthreads();               // drains vmcnt before barrier

    short8 ah[4], al[4], bh[4], bl[4];
#pragma unroll
    for (int mi = 0; mi < 4; mi++){
      ah[mi] = *(const short8*)&AsH[aoff[mi]];
      al[mi] = *(const short8*)&AsL[aoff[mi]];
    }
#pragma unroll
    for (int ni = 0; ni < 4; ni++){
      bh[ni] = *(const short8*)&BsH[boff[ni]];
      bl[ni] = *(const short8*)&BsL[boff[ni]];
    }
#pragma unroll
    for (int mi = 0; mi < 4; mi++)
#pragma unroll
      for (int ni = 0; ni < 4; ni++){
        acc[mi][ni] = __builtin_amdgcn_mfma_f32_16x16x32_bf16(ah[mi], bh[ni], acc[mi][ni], 0, 0, 0);
        acc[mi][ni] = __builtin_amdgcn_mfma_f32_16x16x32_bf16(ah[mi], bl[ni], acc[mi][ni], 0, 0, 0);
        acc[mi][ni] = __builtin_amdgcn_mfma_f32_16x16x32_bf16(al[mi], bh[ni], acc[mi][ni], 0, 0, 0);
      }
  }
  // epilogue: C/D layout col=lane&15, row=(lane>>4)*4+reg
#pragma unroll
  for (int mi = 0; mi < 4; mi++)
#pragma unroll
    for (int ni = 0; ni < 4; ni++){
#pragma unroll
      for (int r = 0; r < 4; r++){
        int row = row0 + wr + mi*16 + lq*4 + r;
        int col = col0 + wc + ni*16 + lm;
        if (row < N) C[(size_t)row*M + col] = acc[mi][ni][r];
      }
    }
  (void)dst0;
}

// ===== GCN gather: feature-chunked, XCD-aligned, 4-way edge-unrolled =====
__global__ __launch_bounds__(256) void k_gcn_gather(
    const float* __restrict__ hw, const float* __restrict__ dinv,
    const int* __restrict__ rowptr, const int* __restrict__ colidx,
    const float* __restrict__ gb,
    unsigned short* __restrict__ outH, unsigned short* __restrict__ outL,
    int M, int nchunk){
  int bid = blockIdx.x;
  int chunk = bid % nchunk, grp = bid / nchunk;
  int t = threadIdx.x;
  int sub = t & 15;
  int n = grp*16 + (t >> 4);
  if (n >= NN) return;
  int f0 = chunk*64 + sub*4;
  int b = rowptr[n], e = rowptr[n+1];
  float dn = dinv[n];
  float4 a0 = make_float4(0,0,0,0), a1 = make_float4(0,0,0,0);
  float4 a2 = make_float4(0,0,0,0), a3 = make_float4(0,0,0,0);
  int j = b;
  for (; j + 3 < e; j += 4){
    int s0 = colidx[j], s1 = colidx[j+1], s2 = colidx[j+2], s3 = colidx[j+3];
    float w0 = dinv[s0], w1 = dinv[s1], w2 = dinv[s2], w3 = dinv[s3];
    float4 v0 = *(const float4*)&hw[(size_t)s0*M + f0];
    float4 v1 = *(const float4*)&hw[(size_t)s1*M + f0];
    float4 v2 = *(const float4*)&hw[(size_t)s2*M + f0];
    float4 v3 = *(const float4*)&hw[(size_t)s3*M + f0];
    fma4(a0, v0, w0*dn); fma4(a1, v1, w1*dn);
    fma4(a2, v2, w2*dn); fma4(a3, v3, w3*dn);
  }
  for (; j < e; j++){
    int s = colidx[j];
    float4 v = *(const float4*)&hw[(size_t)s*M + f0];
    fma4(a0, v, dinv[s]*dn);
  }
  float4 acc = make_float4(a0.x+a1.x+a2.x+a3.x, a0.y+a1.y+a2.y+a3.y,
                           a0.z+a1.z+a2.z+a3.z, a0.w+a1.w+a2.w+a3.w);
  float4 sv = *(const float4*)&hw[(size_t)n*M + f0];
  float4 bb = *(const float4*)&gb[f0];
  float dn2 = dn*dn;
  float4 r = make_float4(fmaxf(acc.x + sv.x*dn2 + bb.x, 0.f),
                         fmaxf(acc.y + sv.y*dn2 + bb.y, 0.f),
                         fmaxf(acc.z + sv.z*dn2 + bb.z, 0.f),
                         fmaxf(acc.w + sv.w*dn2 + bb.w, 0.f));
  store_hl(outH, outL, (size_t)n*M + f0, r);
}

// ================= GAT =================
__global__ void k_gat_alpha(const float* __restrict__ hg, const float* __restrict__ a_s,
                            const float* __restrict__ a_d, float* __restrict__ as_,
                            float* __restrict__ ad_, int M, int C){
  int idx = blockIdx.x*blockDim.x + threadIdx.x;
  if (idx >= NN*NH) return;
  int n = idx >> 2, hd = idx & 3;
  const float4* row = (const float4*)(hg + (size_t)n*M + hd*C);
  const float4* w1 = (const float4*)(a_s + hd*C);
  const float4* w2 = (const float4*)(a_d + hd*C);
  float ss = 0.f, dd = 0.f;
  int c4 = C >> 2;
  for (int c = 0; c < c4; c++){
    float4 v = row[c], p = w1[c], q = w2[c];
    ss += v.x*p.x + v.y*p.y + v.z*p.z + v.w*p.w;
    dd += v.x*q.x + v.y*q.y + v.z*q.z + v.w*q.w;
  }
  as_[idx] = ss; ad_[idx] = dd;
}
__global__ void k_gat_maxden(const int* __restrict__ rowptr, const int* __restrict__ colidx,
                             const float* __restrict__ as_, const float* __restrict__ ad_,
                             float* __restrict__ eself, float* __restrict__ den,
                             float* __restrict__ ealpha){
  int idx = blockIdx.x*blockDim.x + threadIdx.x;
  if (idx >= NN*NH) return;
  int n = idx >> 2, hd = idx & 3;
  float adn = ad_[idx];
  float selflog = leakyf(as_[idx] + adn);
  int b = rowptr[n], e = rowptr[n+1];
  float m0 = selflog, m1 = -INFINITY, m2 = -INFINITY, m3 = -INFINITY;
  int j = b;
  for (; j + 3 < e; j += 4){
    int s0 = colidx[j], s1 = colidx[j+1], s2 = colidx[j+2], s3 = colidx[j+3];
    float q0 = as_[s0*NH + hd], q1 = as_[s1*NH + hd];
    float q2 = as_[s2*NH + hd], q3 = as_[s3*NH + hd];
    m0 = fmaxf(m0, leakyf(q0 + adn)); m1 = fmaxf(m1, leakyf(q1 + adn));
    m2 = fmaxf(m2, leakyf(q2 + adn)); m3 = fmaxf(m3, leakyf(q3 + adn));
  }
  for (; j < e; j++) m0 = fmaxf(m0, leakyf(as_[colidx[j]*NH + hd] + adn));
  float m = fmaxf(fmaxf(m0, m1), fmaxf(m2, m3));
  float es = expf(selflog - m);
  float d0 = es, d1 = 0.f, d2 = 0.f, d3 = 0.f;
  j = b;
  for (; j + 3 < e; j += 4){
    int s0 = colidx[j], s1 = colidx[j+1], s2 = colidx[j+2], s3 = colidx[j+3];
    float q0 = as_[s0*NH + hd], q1 = as_[s1*NH + hd];
    float q2 = as_[s2*NH + hd], q3 = as_[s3*NH + hd];
    float v0 = expf(leakyf(q0 + adn) - m), v1 = expf(leakyf(q1 + adn) - m);
    float v2 = expf(leakyf(q2 + adn) - m), v3 = expf(leakyf(q3 + adn) - m);
    ealpha[(size_t)(j+0)*NH + hd] = v0; ealpha[(size_t)(j+1)*NH + hd] = v1;
    ealpha[(size_t)(j+2)*NH + hd] = v2; ealpha[(size_t)(j+3)*NH + hd] = v3;
    d0 += v0; d1 += v1; d2 += v2; d3 += v3;
  }
  for (; j < e; j++){
    float v = expf(leakyf(as_[colidx[j]*NH + hd] + adn) - m);
    ealpha[(size_t)j*NH + hd] = v;
    d0 += v;
  }
  eself[idx] = es;
  den[idx] = (d0 + d1) + (d2 + d3);
}
// ===== GAT gather: feature-chunked, XCD-aligned, 4-way edge-unrolled =====
__global__ __launch_bounds__(256) void k_gat_gather(
    const float* __restrict__ hg,
    const unsigned short* __restrict__ inH, const unsigned short* __restrict__ inL,
    const int* __restrict__ rowptr, const int* __restrict__ colidx,
    const float* __restrict__ ealpha, const float* __restrict__ eself,
    const float* __restrict__ den, const float* __restrict__ ab,
    unsigned short* __restrict__ outH, unsigned short* __restrict__ outL,
    int M, int C, int nchunk){
  int bid = blockIdx.x;
  int chunk = bid % nchunk, grp = bid / nchunk;
  int t = threadIdx.x;
  int sub = t & 15;
  int n = grp*16 + (t >> 4);
  if (n >= NN) return;
  int f0 = chunk*64 + sub*4;
  int hd = f0 / C;
  int b = rowptr[n], e = rowptr[n+1];
  float4 a0 = make_float4(0,0,0,0), a1 = make_float4(0,0,0,0);
  float4 a2 = make_float4(0,0,0,0), a3 = make_float4(0,0,0,0);
  int j = b;
  for (; j + 3 < e; j += 4){
    int s0 = colidx[j], s1 = colidx[j+1], s2 = colidx[j+2], s3 = colidx[j+3];
    float e0 = ealpha[(size_t)(j+0)*NH + hd], e1 = ealpha[(size_t)(j+1)*NH + hd];
    float e2 = ealpha[(size_t)(j+2)*NH + hd], e3 = ealpha[(size_t)(j+3)*NH + hd];
    float4 v0 = *(const float4*)&hg[(size_t)s0*M + f0];
    float4 v1 = *(const float4*)&hg[(size_t)s1*M + f0];
    float4 v2 = *(const float4*)&hg[(size_t)s2*M + f0];
    float4 v3 = *(const float4*)&hg[(size_t)s3*M + f0];
    fma4(a0, v0, e0); fma4(a1, v1, e1);
    fma4(a2, v2, e2); fma4(a3, v3, e3);
  }
  for (; j < e; j++){
    int s = colidx[j];
    float4 v = *(const float4*)&hg[(size_t)s*M + f0];
    fma4(a0, v, ealpha[(size_t)j*NH + hd]);
  }
  float4 acc = make_float4(a0.x+a1.x+a2.x+a3.x, a0.y+a1.y+a2.y+a3.y,
                           a0.z+a1.z+a2.z+a3.z, a0.w+a1.w+a2.w+a3.w);
  int ai = n*NH + hd;
  float es = eself[ai], inv = 1.f/den[ai];
  float4 sv = *(const float4*)&hg[(size_t)n*M + f0];
  us4 hh = *(const us4*)&inH[(size_t)n*M + f0];
  us4 hl = *(const us4*)&inL[(size_t)n*M + f0];
  float4 bb = *(const float4*)&ab[f0];
  float4 r = make_float4(
    bf2f(hh[0])+bf2f(hl[0]) + bb.x + (sv.x*es + acc.x)*inv,
    bf2f(hh[1])+bf2f(hl[1]) + bb.y + (sv.y*es + acc.y)*inv,
    bf2f(hh[2])+bf2f(hl[2]) + bb.z + (sv.z*es + acc.z)*inv,
    bf2f(hh[3])+bf2f(hl[3]) + bb.w + (sv.w*es + acc.w)*inv);
  store_hl(outH, outL, (size_t)n*M + f0, r);
}

// ================= attention pooling =================
__global__ void k_tanh_dot(const float* __restrict__ t1, const float* __restrict__ b1,
                           const float* __restrict__ w2, const float* __restrict__ b2,
                           float* __restrict__ apre){
  int n = blockIdx.x, t = threadIdx.x;
  float4 v  = ((const float4*)(t1 + (size_t)n*256))[t];
  float4 bb = ((const float4*)b1)[t];
  float4 ww = ((const float4*)w2)[t];
  float s = tanhf(v.x+bb.x)*ww.x + tanhf(v.y+bb.y)*ww.y
          + tanhf(v.z+bb.z)*ww.z + tanhf(v.w+bb.w)*ww.w;
  for (int o = 32; o > 0; o >>= 1) s += __shfl_xor(s, o);
  if (t == 0) apre[n] = s + b2[0];
}
__global__ void k_starts(const int* __restrict__ batch, int* __restrict__ starts){
  int g = threadIdx.x;
  if (g > NB) return;
  int lo = 0, hi = NN;
  while (lo < hi){ int mid = (lo + hi) >> 1; if (batch[mid] < g) lo = mid + 1; else hi = mid; }
  starts[g] = lo;
}
__global__ void k_pool_prep(const float* __restrict__ apre, const int* __restrict__ starts,
                            float* __restrict__ pw){
  int g = blockIdx.x, t = threadIdx.x;
  int b = starts[g], e = starts[g+1];
  float m = -INFINITY;
  for (int n = b + t; n < e; n += 64) m = fmaxf(m, apre[n]);
  for (int o = 32; o > 0; o >>= 1) m = fmaxf(m, __shfl_xor(m, o));
  float s = 0.f;
  for (int n = b + t; n < e; n += 64) s += expf(apre[n] - m);
  for (int o = 32; o > 0; o >>= 1) s += __shfl_xor(s, o);
  float inv = 1.f / (s + 1e-8f);
  for (int n = b + t; n < e; n += 64) pw[n] = expf(apre[n] - m) * inv;
}
__global__ void k_pool(const unsigned short* __restrict__ xH, const unsigned short* __restrict__ xL,
                       const float* __restrict__ pw, const int* __restrict__ starts,
                       float* __restrict__ out){
  int g = blockIdx.x, t = threadIdx.x;
  int b = starts[g], e = starts[g+1];
  float4 sum = make_float4(0,0,0,0), wacc = make_float4(0,0,0,0);
  float4 mx = make_float4(-INFINITY,-INFINITY,-INFINITY,-INFINITY);
  for (int n = b; n < e; n++){
    us4 xh = ((const us4*)(xH + (size_t)n*DOUT))[t];
    us4 xl = ((const us4*)(xL + (size_t)n*DOUT))[t];
    float4 xv = make_float4(bf2f(xh[0])+bf2f(xl[0]), bf2f(xh[1])+bf2f(xl[1]),
                            bf2f(xh[2])+bf2f(xl[2]), bf2f(xh[3])+bf2f(xl[3]));
    float p = pw[n];
    sum.x += xv.x; sum.y += xv.y; sum.z += xv.z; sum.w += xv.w;
    mx.x = fmaxf(mx.x, xv.x); mx.y = fmaxf(mx.y, xv.y);
    mx.z = fmaxf(mx.z, xv.z); mx.w = fmaxf(mx.w, xv.w);
    fma4(wacc, xv, p);
  }
  float ic = 1.f / fmaxf((float)(e - b), 1.f);
  float4* o = (float4*)(out + (size_t)g*4*DOUT);
  o[t]       = wacc;
  o[128 + t] = make_float4(sum.x*ic, sum.y*ic, sum.z*ic, sum.w*ic);
  o[256 + t] = mx;
  o[384 + t] = sum;
}

extern "C" void kernel_launch(void* const* d_in, const int* in_sizes, int n_in,
                              void* d_out, int out_size, void* d_ws, size_t ws_size,
                              hipStream_t stream) {
  const float* x0   = (const float*)d_in[0];
  const int*   ei   = (const int*)d_in[1];
  const int*   src  = ei;
  const int*   dst  = ei + NE;
  const int*   batch= (const int*)d_in[2];
  const float* gw[3]  = {(const float*)d_in[3],  (const float*)d_in[9],  (const float*)d_in[15]};
  const float* gb[3]  = {(const float*)d_in[4],  (const float*)d_in[10], (const float*)d_in[16]};
  const float* aw[3]  = {(const float*)d_in[5],  (const float*)d_in[11], (const float*)d_in[17]};
  const float* asw[3] = {(const float*)d_in[6],  (const float*)d_in[12], (const float*)d_in[18]};
  const float* adw[3] = {(const float*)d_in[7],  (const float*)d_in[13], (const float*)d_in[19]};
  const float* ab[3]  = {(const float*)d_in[8],  (const float*)d_in[14], (const float*)d_in[20]};
  const float* apw1 = (const float*)d_in[21];
  const float* apb1 = (const float*)d_in[22];
  const float* apw2 = (const float*)d_in[23];
  const float* apb2 = (const float*)d_in[24];
  float* out = (float*)d_out;

  // ---- workspace carve ----
  char* p = (char*)d_ws;
  auto alloc = [&](size_t bytes) -> void* {
    void* r = (void*)p; p += (bytes + 255) & ~(size_t)255; return r;
  };
  float* f1 = (float*)alloc((size_t)NN*512*4);
  unsigned short* actH0 = (unsigned short*)alloc((size_t)NN*512*2);
  unsigned short* actL0 = (unsigned short*)alloc((size_t)NN*512*2);
  unsigned short* actH1 = (unsigned short*)alloc((size_t)NN*512*2);
  unsigned short* actL1 = (unsigned short*)alloc((size_t)NN*512*2);
  unsigned short* x0h = (unsigned short*)alloc((size_t)NN*64*2);
  unsigned short* x0l = (unsigned short*)alloc((size_t)NN*64*2);
  const int wK[7]  = {36, 128, 128, 256, 256, 512, 512};
  const int wM[7]  = {128, 128, 256, 256, 512, 512, 256};
  const int wKp[7] = {64, 128, 128, 256, 256, 512, 512};
  const float* wsrc[7] = {gw[0], aw[0], gw[1], aw[1], gw[2], aw[2], apw1};
  unsigned short* wTh[7]; unsigned short* wTl[7];
  for (int i = 0; i < 7; i++){
    size_t sz = (size_t)wM[i]*wKp[i]*2;
    wTh[i] = (unsigned short*)alloc(sz);
    wTl[i] = (unsigned short*)alloc(sz);
  }
  float* ealpha = (float*)alloc((size_t)NE*NH*4);
  float* dinv = (float*)alloc(NN*4);
  float* as_  = (float*)alloc(NN*NH*4);
  float* ad_  = (float*)alloc(NN*NH*4);
  float* eself= (float*)alloc(NN*NH*4);
  float* den  = (float*)alloc(NN*NH*4);
  float* apre = (float*)alloc(NN*4);
  float* pw   = (float*)alloc(NN*4);
  int* rowptr = (int*)alloc((NN+1)*4);
  int* colidx = (int*)alloc((size_t)NE*4);
  int* cnt    = (int*)alloc(NN*4);
  int* cursor = (int*)alloc(NN*4);
  int* starts = (int*)alloc((NB+1)*4);

  // ---- CSR build + degrees + starts ----
  hipMemsetAsync(cnt, 0, NN*sizeof(int), stream);
  k_count<<<(NE+255)/256, 256, 0, stream>>>(dst, cnt);
  k_dinv<<<(NN+255)/256, 256, 0, stream>>>(cnt, dinv);
  k_scan<<<1, 256, 0, stream>>>(cnt, rowptr);
  hipMemsetAsync(cursor, 0, NN*sizeof(int), stream);
  k_fill<<<(NE+255)/256, 256, 0, stream>>>(src, dst, rowptr, cursor, colidx);
  k_starts<<<1, 256, 0, stream>>>(batch, starts);

  // ---- conversions ----
  k_convx0<<<(NN*64+255)/256, 256, 0, stream>>>(x0, x0h, x0l);
  for (int i = 0; i < 7; i++){
    int tot = wKp[i]*wM[i];
    k_wconv<<<(tot+255)/256, 256, 0, stream>>>(wsrc[i], wTh[i], wTl[i], wK[i], wM[i], wKp[i]);
  }

  auto gemm = [&](const unsigned short* Ahp, const unsigned short* Alp, int wi, int M){
    int nblk = (M/GBN) * ((NN+GBM-1)/GBM);
    k_gemm_bf3<<<nblk, 256, 0, stream>>>(Ahp, Alp, wTh[wi], wTl[wi], f1, NN, wKp[wi], M);
  };

  const int dims[4] = {36, 128, 256, 512};
  const int ngrp = (NN + 15) / 16;
  const unsigned short* curH = x0h; const unsigned short* curL = x0l;
  int wi = 0;
  for (int i = 0; i < 3; i++){
    int M = dims[i+1], C = M/NH;
    int nchunk = M / 64;
    // GCN
    gemm(curH, curL, wi++, M);
    k_gcn_gather<<<nchunk*ngrp, 256, 0, stream>>>(f1, dinv, rowptr, colidx, gb[i],
                                                  actH0, actL0, M, nchunk);
    // GAT
    gemm(actH0, actL0, wi++, M);
    k_gat_alpha<<<(NN*NH+255)/256, 256, 0, stream>>>(f1, asw[i], adw[i], as_, ad_, M, C);
    k_gat_maxden<<<(NN*NH+255)/256, 256, 0, stream>>>(rowptr, colidx, as_, ad_, eself, den, ealpha);
    k_gat_gather<<<nchunk*ngrp, 256, 0, stream>>>(f1, actH0, actL0, rowptr, colidx,
                                                  ealpha, eself, den, ab[i],
                                                  actH1, actL1, M, C, nchunk);
    curH = actH1; curL = actL1;
  }

  // ---- pooling ----
  gemm(actH1, actL1, 6, 256);
  k_tanh_dot<<<NN, 64, 0, stream>>>(f1, apb1, apw2, apb2, apre);
  k_pool_prep<<<NB, 64, 0, stream>>>(apre, starts, pw);
  k_pool<<<NB, 128, 0, stream>>>(actH1, actL1, pw, starts, out);
}

// Round 9
// 482.753 us; speedup vs baseline: 4.7832x; 1.0323x over previous
//
#include <hip/hip_runtime.h>
#include <math.h>

#define NN 10000
#define NE 160000
#define NB 128
#define NH 4
#define DOUT 512
#define NEG 0.2f

typedef __attribute__((ext_vector_type(8))) short short8;
typedef __attribute__((ext_vector_type(4))) float f32x4;
typedef __attribute__((ext_vector_type(4))) unsigned short us4;

__device__ __forceinline__ float leakyf(float v){ return v > 0.f ? v : NEG*v; }
__device__ __forceinline__ void fma4(float4& a, const float4 v, float w){
  a.x += v.x*w; a.y += v.y*w; a.z += v.z*w; a.w += v.w*w;
}
__device__ __forceinline__ unsigned short f2bf(float f){
  unsigned int u = __float_as_uint(f);
  u += 0x7FFFu + ((u >> 16) & 1u);
  return (unsigned short)(u >> 16);
}
__device__ __forceinline__ float bf2f(unsigned short h){
  return __uint_as_float(((unsigned int)h) << 16);
}
__device__ __forceinline__ void split2(float v, unsigned short& h, unsigned short& l){
  h = f2bf(v);
  l = f2bf(v - bf2f(h));
}
__device__ __forceinline__ void store_hl(unsigned short* H, unsigned short* L,
                                         size_t base, float4 v){
  us4 h, l; unsigned short hh, ll;
  split2(v.x, hh, ll); h[0]=hh; l[0]=ll;
  split2(v.y, hh, ll); h[1]=hh; l[1]=ll;
  split2(v.z, hh, ll); h[2]=hh; l[2]=ll;
  split2(v.w, hh, ll); h[3]=hh; l[3]=ll;
  *(us4*)&H[base] = h;
  *(us4*)&L[base] = l;
}
__device__ __forceinline__ void gl_lds16(const unsigned short* g, unsigned short* l){
  __builtin_amdgcn_global_load_lds(
      (const __attribute__((address_space(1))) unsigned int*)g,
      (__attribute__((address_space(3))) unsigned int*)l, 16, 0, 0);
}

// ================= CSR build =================
__global__ void k_count(const int* __restrict__ dst, int* __restrict__ cnt){
  int e = blockIdx.x*blockDim.x + threadIdx.x;
  if (e < NE) atomicAdd(&cnt[dst[e]], 1);
}
// scan + dinv + cursor-zero + segment starts, single block of 256
__global__ void k_scan(const int* __restrict__ cnt, int* __restrict__ rowptr,
                       float* __restrict__ dinv, int* __restrict__ cursor,
                       const int* __restrict__ batch, int* __restrict__ starts){
  __shared__ int part[256];
  const int CH = (NN + 255) / 256;
  int t = threadIdx.x;
  int base = t * CH;
  int s = 0;
  for (int i = 0; i < CH; i++){ int idx = base + i; if (idx < NN) s += cnt[idx]; }
  part[t] = s; __syncthreads();
  for (int o = 1; o < 256; o <<= 1){
    int v = 0;
    if (t >= o) v = part[t - o];
    __syncthreads();
    if (t >= o) part[t] += v;
    __syncthreads();
  }
  int pre = (t == 0) ? 0 : part[t - 1];
  for (int i = 0; i < CH; i++){
    int idx = base + i;
    if (idx < NN){
      int c = cnt[idx];
      rowptr[idx] = pre; pre += c;
      dinv[idx] = rsqrtf((float)c + 1.f);
      cursor[idx] = 0;
    }
  }
  if (t == 255) rowptr[NN] = part[255];
  if (t <= NB){
    int lo = 0, hi = NN;
    while (lo < hi){ int mid = (lo + hi) >> 1; if (batch[mid] < t) lo = mid + 1; else hi = mid; }
    starts[t] = lo;
  }
}
__global__ void k_fill(const int* __restrict__ src, const int* __restrict__ dst,
                       const int* __restrict__ rowptr, int* __restrict__ cursor,
                       int* __restrict__ colidx){
  int e = blockIdx.x*blockDim.x + threadIdx.x;
  if (e >= NE) return;
  int d = dst[e];
  int pos = atomicAdd(&cursor[d], 1);
  colidx[rowptr[d] + pos] = src[e];
}

// ============ fused conversions: job 0 = x0 pad-convert, jobs 1..7 = W^T ============
struct AllConv {
  const float* src[8];
  unsigned short* dh[8];
  unsigned short* dl[8];
  int K[8], Mm[8], Kp[8], tot[8];
};
__global__ void k_convall(AllConv a){
  int j = blockIdx.y;
  int idx = blockIdx.x*blockDim.x + threadIdx.x;
  if (idx >= a.tot[j]) return;
  float v;
  if (j == 0){
    int n = idx >> 6, c = idx & 63;
    v = (c < 36) ? a.src[0][n*36 + c] : 0.f;
  } else {
    int Kp = a.Kp[j], K = a.K[j], M = a.Mm[j];
    int kk = idx % Kp, m = idx / Kp;
    v = (kk < K) ? a.src[j][(size_t)kk*M + m] : 0.f;
  }
  unsigned short h, l; split2(v, h, l);
  a.dh[j][idx] = h; a.dl[j][idx] = l;
}

// ===== GEMM: C[N,M] = (Ah+Al)[N,Kp] @ (Bh+Bl)^T, bf16x3, m97-style =====
// 64x128 tile (better CU utilization at small M), 4 waves x (4m x 2n) 16x16 tiles,
// global_load_lds staging, source-side chunk swizzle (2-way/bank frag reads).
#define GBM 64
#define GBN 128
#define GBK 32
__global__ __launch_bounds__(256) void k_gemm_bf3(
    const unsigned short* __restrict__ Ah, const unsigned short* __restrict__ Al,
    const unsigned short* __restrict__ Bh, const unsigned short* __restrict__ Bl,
    float* __restrict__ C, int N, int Kp, int M){
  __shared__ unsigned short AsH[GBM*GBK], AsL[GBM*GBK];
  __shared__ unsigned short BsH[GBN*GBK], BsL[GBN*GBK];
  int gx = M / GBN;
  int gy = (N + GBM - 1) / GBM;
  const int G = 8;
  int bid = blockIdx.x;
  int full = gy / G;
  int bid_full = full * G * gx;
  int by, bx;
  if (bid < bid_full){
    int g = bid / (G*gx); int rem = bid % (G*gx);
    by = g*G + rem % G; bx = rem / G;
  } else {
    int rem = bid - bid_full; int rows = gy - full*G;
    by = full*G + rem % rows; bx = rem / rows;
  }
  int row0 = by * GBM, col0 = bx * GBN;
  int t = threadIdx.x;
  int w = t >> 6, L = t & 63;
  int lm = L & 15, lq = L >> 4;
  int wc = w * 32;

  // staging: lane L -> sub-row L>>2 of a 16-row segment, slot c=L&3,
  // fetches global chunk g=(c-(row>>1))&3 (LDS slot c of row r holds chunk (c-(r>>1))&3)
  int sr = L >> 2, sc = L & 3;
  int art = w*16 + sr;                       // A tile row (wave w: rows 16w..16w+15)
  int ga  = (sc - ((art >> 1) & 3)) & 3;
  int agrow = min(row0 + art, N-1);          // clamp tail; outputs guarded
  int brt0 = w*16 + sr;                      // B segments w and w+4
  int brt1 = (w+4)*16 + sr;
  int gb0 = (sc - ((brt0 >> 1) & 3)) & 3;
  int gb1 = (sc - ((brt1 >> 1) & 3)) & 3;
  int bgrow0 = col0 + brt0, bgrow1 = col0 + brt1;

  // frag read slot: c = (lq + (lm>>1)) & 3  (tile-row bases are multiples of 16)
  int rc = (lq + (lm >> 1)) & 3;
  int aoff[4], boff[2];
#pragma unroll
  for (int mi = 0; mi < 4; mi++) aoff[mi] = (mi*16 + lm)*32 + rc*8;
#pragma unroll
  for (int ni = 0; ni < 2; ni++) boff[ni] = (wc + ni*16 + lm)*32 + rc*8;

  f32x4 acc[4][2];
#pragma unroll
  for (int i = 0; i < 4; i++)
#pragma unroll
    for (int j = 0; j < 2; j++) acc[i][j] = (f32x4){0.f,0.f,0.f,0.f};

  int nk = Kp / GBK;
  for (int kt = 0; kt < nk; kt++){
    int k0 = kt * GBK;
    if (kt) __syncthreads();
    gl_lds16(&Ah[(size_t)agrow*Kp + k0 + ga*8],  &AsH[w*512]);
    gl_lds16(&Al[(size_t)agrow*Kp + k0 + ga*8],  &AsL[w*512]);
    gl_lds16(&Bh[(size_t)bgrow0*Kp + k0 + gb0*8], &BsH[w*512]);
    gl_lds16(&Bh[(size_t)bgrow1*Kp + k0 + gb1*8], &BsH[(w+4)*512]);
    gl_lds16(&Bl[(size_t)bgrow0*Kp + k0 + gb0*8], &BsL[w*512]);
    gl_lds16(&Bl[(size_t)bgrow1*Kp + k0 + gb1*8], &BsL[(w+4)*512]);
    __syncthreads();

    short8 ah[4], al[4], bh[2], bl[2];
#pragma unroll
    for (int mi = 0; mi < 4; mi++){
      ah[mi] = *(const short8*)&AsH[aoff[mi]];
      al[mi] = *(const short8*)&AsL[aoff[mi]];
    }
#pragma unroll
    for (int ni = 0; ni < 2; ni++){
      bh[ni] = *(const short8*)&BsH[boff[ni]];
      bl[ni] = *(const short8*)&BsL[boff[ni]];
    }
#pragma unroll
    for (int mi = 0; mi < 4; mi++)
#pragma unroll
      for (int ni = 0; ni < 2; ni++){
        acc[mi][ni] = __builtin_amdgcn_mfma_f32_16x16x32_bf16(ah[mi], bh[ni], acc[mi][ni], 0, 0, 0);
        acc[mi][ni] = __builtin_amdgcn_mfma_f32_16x16x32_bf16(ah[mi], bl[ni], acc[mi][ni], 0, 0, 0);
        acc[mi][ni] = __builtin_amdgcn_mfma_f32_16x16x32_bf16(al[mi], bh[ni], acc[mi][ni], 0, 0, 0);
      }
  }
  // epilogue: C/D layout col=lane&15, row=(lane>>4)*4+reg
#pragma unroll
  for (int mi = 0; mi < 4; mi++)
#pragma unroll
    for (int ni = 0; ni < 2; ni++){
#pragma unroll
      for (int r = 0; r < 4; r++){
        int row = row0 + mi*16 + lq*4 + r;
        int col = col0 + wc + ni*16 + lm;
        if (row < N) C[(size_t)row*M + col] = acc[mi][ni][r];
      }
    }
}

// ===== GCN gather: feature-chunked, XCD-aligned, 4-way edge-unrolled =====
__global__ __launch_bounds__(256) void k_gcn_gather(
    const float* __restrict__ hw, const float* __restrict__ dinv,
    const int* __restrict__ rowptr, const int* __restrict__ colidx,
    const float* __restrict__ gb,
    unsigned short* __restrict__ outH, unsigned short* __restrict__ outL,
    int M, int nchunk){
  int bid = blockIdx.x;
  int chunk = bid % nchunk, grp = bid / nchunk;
  int t = threadIdx.x;
  int sub = t & 15;
  int n = grp*16 + (t >> 4);
  if (n >= NN) return;
  int f0 = chunk*64 + sub*4;
  int b = rowptr[n], e = rowptr[n+1];
  float dn = dinv[n];
  float4 a0 = make_float4(0,0,0,0), a1 = make_float4(0,0,0,0);
  float4 a2 = make_float4(0,0,0,0), a3 = make_float4(0,0,0,0);
  int j = b;
  for (; j + 3 < e; j += 4){
    int s0 = colidx[j], s1 = colidx[j+1], s2 = colidx[j+2], s3 = colidx[j+3];
    float w0 = dinv[s0], w1 = dinv[s1], w2 = dinv[s2], w3 = dinv[s3];
    float4 v0 = *(const float4*)&hw[(size_t)s0*M + f0];
    float4 v1 = *(const float4*)&hw[(size_t)s1*M + f0];
    float4 v2 = *(const float4*)&hw[(size_t)s2*M + f0];
    float4 v3 = *(const float4*)&hw[(size_t)s3*M + f0];
    fma4(a0, v0, w0*dn); fma4(a1, v1, w1*dn);
    fma4(a2, v2, w2*dn); fma4(a3, v3, w3*dn);
  }
  for (; j < e; j++){
    int s = colidx[j];
    float4 v = *(const float4*)&hw[(size_t)s*M + f0];
    fma4(a0, v, dinv[s]*dn);
  }
  float4 acc = make_float4(a0.x+a1.x+a2.x+a3.x, a0.y+a1.y+a2.y+a3.y,
                           a0.z+a1.z+a2.z+a3.z, a0.w+a1.w+a2.w+a3.w);
  float4 sv = *(const float4*)&hw[(size_t)n*M + f0];
  float4 bb = *(const float4*)&gb[f0];
  float dn2 = dn*dn;
  float4 r = make_float4(fmaxf(acc.x + sv.x*dn2 + bb.x, 0.f),
                         fmaxf(acc.y + sv.y*dn2 + bb.y, 0.f),
                         fmaxf(acc.z + sv.z*dn2 + bb.z, 0.f),
                         fmaxf(acc.w + sv.w*dn2 + bb.w, 0.f));
  store_hl(outH, outL, (size_t)n*M + f0, r);
}

// ================= GAT =================
__global__ void k_gat_alpha(const float* __restrict__ hg, const float* __restrict__ a_s,
                            const float* __restrict__ a_d, float* __restrict__ as_,
                            float* __restrict__ ad_, int M, int C){
  int idx = blockIdx.x*blockDim.x + threadIdx.x;
  if (idx >= NN*NH) return;
  int n = idx >> 2, hd = idx & 3;
  const float4* row = (const float4*)(hg + (size_t)n*M + hd*C);
  const float4* w1 = (const float4*)(a_s + hd*C);
  const float4* w2 = (const float4*)(a_d + hd*C);
  float ss = 0.f, dd = 0.f;
  int c4 = C >> 2;
  for (int c = 0; c < c4; c++){
    float4 v = row[c], p = w1[c], q = w2[c];
    ss += v.x*p.x + v.y*p.y + v.z*p.z + v.w*p.w;
    dd += v.x*q.x + v.y*q.y + v.z*q.z + v.w*q.w;
  }
  as_[idx] = ss; ad_[idx] = dd;
}
// pass1: scattered as_ gather -> logits cached in ealpha + max; pass2: sequential exp
__global__ void k_gat_maxden(const int* __restrict__ rowptr, const int* __restrict__ colidx,
                             const float* __restrict__ as_, const float* __restrict__ ad_,
                             float* __restrict__ eself, float* __restrict__ den,
                             float* __restrict__ ealpha){
  int idx = blockIdx.x*blockDim.x + threadIdx.x;
  if (idx >= NN*NH) return;
  int n = idx >> 2, hd = idx & 3;
  float adn = ad_[idx];
  float selflog = leakyf(as_[idx] + adn);
  int b = rowptr[n], e = rowptr[n+1];
  float m0 = selflog, m1 = -INFINITY, m2 = -INFINITY, m3 = -INFINITY;
  int j = b;
  for (; j + 3 < e; j += 4){
    int s0 = colidx[j], s1 = colidx[j+1], s2 = colidx[j+2], s3 = colidx[j+3];
    float l0 = leakyf(as_[s0*NH + hd] + adn), l1 = leakyf(as_[s1*NH + hd] + adn);
    float l2 = leakyf(as_[s2*NH + hd] + adn), l3 = leakyf(as_[s3*NH + hd] + adn);
    ealpha[(size_t)(j+0)*NH + hd] = l0; ealpha[(size_t)(j+1)*NH + hd] = l1;
    ealpha[(size_t)(j+2)*NH + hd] = l2; ealpha[(size_t)(j+3)*NH + hd] = l3;
    m0 = fmaxf(m0, l0); m1 = fmaxf(m1, l1);
    m2 = fmaxf(m2, l2); m3 = fmaxf(m3, l3);
  }
  for (; j < e; j++){
    float l = leakyf(as_[colidx[j]*NH + hd] + adn);
    ealpha[(size_t)j*NH + hd] = l;
    m0 = fmaxf(m0, l);
  }
  float m = fmaxf(fmaxf(m0, m1), fmaxf(m2, m3));
  float es = expf(selflog - m);
  float d0 = es, d1 = 0.f, d2 = 0.f, d3 = 0.f;
  j = b;
  for (; j + 3 < e; j += 4){
    float v0 = expf(ealpha[(size_t)(j+0)*NH + hd] - m);
    float v1 = expf(ealpha[(size_t)(j+1)*NH + hd] - m);
    float v2 = expf(ealpha[(size_t)(j+2)*NH + hd] - m);
    float v3 = expf(ealpha[(size_t)(j+3)*NH + hd] - m);
    ealpha[(size_t)(j+0)*NH + hd] = v0; ealpha[(size_t)(j+1)*NH + hd] = v1;
    ealpha[(size_t)(j+2)*NH + hd] = v2; ealpha[(size_t)(j+3)*NH + hd] = v3;
    d0 += v0; d1 += v1; d2 += v2; d3 += v3;
  }
  for (; j < e; j++){
    float v = expf(ealpha[(size_t)j*NH + hd] - m);
    ealpha[(size_t)j*NH + hd] = v;
    d0 += v;
  }
  eself[idx] = es;
  den[idx] = (d0 + d1) + (d2 + d3);
}
// ===== GAT gather: feature-chunked, XCD-aligned, 4-way edge-unrolled =====
__global__ __launch_bounds__(256) void k_gat_gather(
    const float* __restrict__ hg,
    const unsigned short* __restrict__ inH, const unsigned short* __restrict__ inL,
    const int* __restrict__ rowptr, const int* __restrict__ colidx,
    const float* __restrict__ ealpha, const float* __restrict__ eself,
    const float* __restrict__ den, const float* __restrict__ ab,
    unsigned short* __restrict__ outH, unsigned short* __restrict__ outL,
    int M, int C, int nchunk){
  int bid = blockIdx.x;
  int chunk = bid % nchunk, grp = bid / nchunk;
  int t = threadIdx.x;
  int sub = t & 15;
  int n = grp*16 + (t >> 4);
  if (n >= NN) return;
  int f0 = chunk*64 + sub*4;
  int hd = f0 / C;
  int b = rowptr[n], e = rowptr[n+1];
  float4 a0 = make_float4(0,0,0,0), a1 = make_float4(0,0,0,0);
  float4 a2 = make_float4(0,0,0,0), a3 = make_float4(0,0,0,0);
  int j = b;
  for (; j + 3 < e; j += 4){
    int s0 = colidx[j], s1 = colidx[j+1], s2 = colidx[j+2], s3 = colidx[j+3];
    float e0 = ealpha[(size_t)(j+0)*NH + hd], e1 = ealpha[(size_t)(j+1)*NH + hd];
    float e2 = ealpha[(size_t)(j+2)*NH + hd], e3 = ealpha[(size_t)(j+3)*NH + hd];
    float4 v0 = *(const float4*)&hg[(size_t)s0*M + f0];
    float4 v1 = *(const float4*)&hg[(size_t)s1*M + f0];
    float4 v2 = *(const float4*)&hg[(size_t)s2*M + f0];
    float4 v3 = *(const float4*)&hg[(size_t)s3*M + f0];
    fma4(a0, v0, e0); fma4(a1, v1, e1);
    fma4(a2, v2, e2); fma4(a3, v3, e3);
  }
  for (; j < e; j++){
    int s = colidx[j];
    float4 v = *(const float4*)&hg[(size_t)s*M + f0];
    fma4(a0, v, ealpha[(size_t)j*NH + hd]);
  }
  float4 acc = make_float4(a0.x+a1.x+a2.x+a3.x, a0.y+a1.y+a2.y+a3.y,
                           a0.z+a1.z+a2.z+a3.z, a0.w+a1.w+a2.w+a3.w);
  int ai = n*NH + hd;
  float es = eself[ai], inv = 1.f/den[ai];
  float4 sv = *(const float4*)&hg[(size_t)n*M + f0];
  us4 hh = *(const us4*)&inH[(size_t)n*M + f0];
  us4 hl = *(const us4*)&inL[(size_t)n*M + f0];
  float4 bb = *(const float4*)&ab[f0];
  float4 r = make_float4(
    bf2f(hh[0])+bf2f(hl[0]) + bb.x + (sv.x*es + acc.x)*inv,
    bf2f(hh[1])+bf2f(hl[1]) + bb.y + (sv.y*es + acc.y)*inv,
    bf2f(hh[2])+bf2f(hl[2]) + bb.z + (sv.z*es + acc.z)*inv,
    bf2f(hh[3])+bf2f(hl[3]) + bb.w + (sv.w*es + acc.w)*inv);
  store_hl(outH, outL, (size_t)n*M + f0, r);
}

// ================= attention pooling =================
__global__ void k_tanh_dot(const float* __restrict__ t1, const float* __restrict__ b1,
                           const float* __restrict__ w2, const float* __restrict__ b2,
                           float* __restrict__ apre){
  int n = blockIdx.x, t = threadIdx.x;
  float4 v  = ((const float4*)(t1 + (size_t)n*256))[t];
  float4 bb = ((const float4*)b1)[t];
  float4 ww = ((const float4*)w2)[t];
  float s = tanhf(v.x+bb.x)*ww.x + tanhf(v.y+bb.y)*ww.y
          + tanhf(v.z+bb.z)*ww.z + tanhf(v.w+bb.w)*ww.w;
  for (int o = 32; o > 0; o >>= 1) s += __shfl_xor(s, o);
  if (t == 0) apre[n] = s + b2[0];
}
__global__ void k_pool_prep(const float* __restrict__ apre, const int* __restrict__ starts,
                            float* __restrict__ pw){
  int g = blockIdx.x, t = threadIdx.x;
  int b = starts[g], e = starts[g+1];
  float m = -INFINITY;
  for (int n = b + t; n < e; n += 64) m = fmaxf(m, apre[n]);
  for (int o = 32; o > 0; o >>= 1) m = fmaxf(m, __shfl_xor(m, o));
  float s = 0.f;
  for (int n = b + t; n < e; n += 64) s += expf(apre[n] - m);
  for (int o = 32; o > 0; o >>= 1) s += __shfl_xor(s, o);
  float inv = 1.f / (s + 1e-8f);
  for (int n = b + t; n < e; n += 64) pw[n] = expf(apre[n] - m) * inv;
}
__global__ void k_pool(const unsigned short* __restrict__ xH, const unsigned short* __restrict__ xL,
                       const float* __restrict__ pw, const int* __restrict__ starts,
                       float* __restrict__ out){
  int g = blockIdx.x, t = threadIdx.x;
  int b = starts[g], e = starts[g+1];
  float4 sum = make_float4(0,0,0,0), wacc = make_float4(0,0,0,0);
  float4 mx = make_float4(-INFINITY,-INFINITY,-INFINITY,-INFINITY);
  for (int n = b; n < e; n++){
    us4 xh = ((const us4*)(xH + (size_t)n*DOUT))[t];
    us4 xl = ((const us4*)(xL + (size_t)n*DOUT))[t];
    float4 xv = make_float4(bf2f(xh[0])+bf2f(xl[0]), bf2f(xh[1])+bf2f(xl[1]),
                            bf2f(xh[2])+bf2f(xl[2]), bf2f(xh[3])+bf2f(xl[3]));
    float p = pw[n];
    sum.x += xv.x; sum.y += xv.y; sum.z += xv.z; sum.w += xv.w;
    mx.x = fmaxf(mx.x, xv.x); mx.y = fmaxf(mx.y, xv.y);
    mx.z = fmaxf(mx.z, xv.z); mx.w = fmaxf(mx.w, xv.w);
    fma4(wacc, xv, p);
  }
  float ic = 1.f / fmaxf((float)(e - b), 1.f);
  float4* o = (float4*)(out + (size_t)g*4*DOUT);
  o[t]       = wacc;
  o[128 + t] = make_float4(sum.x*ic, sum.y*ic, sum.z*ic, sum.w*ic);
  o[256 + t] = mx;
  o[384 + t] = sum;
}

extern "C" void kernel_launch(void* const* d_in, const int* in_sizes, int n_in,
                              void* d_out, int out_size, void* d_ws, size_t ws_size,
                              hipStream_t stream) {
  const float* x0   = (const float*)d_in[0];
  const int*   ei   = (const int*)d_in[1];
  const int*   src  = ei;
  const int*   dst  = ei + NE;
  const int*   batch= (const int*)d_in[2];
  const float* gw[3]  = {(const float*)d_in[3],  (const float*)d_in[9],  (const float*)d_in[15]};
  const float* gb[3]  = {(const float*)d_in[4],  (const float*)d_in[10], (const float*)d_in[16]};
  const float* aw[3]  = {(const float*)d_in[5],  (const float*)d_in[11], (const float*)d_in[17]};
  const float* asw[3] = {(const float*)d_in[6],  (const float*)d_in[12], (const float*)d_in[18]};
  const float* adw[3] = {(const float*)d_in[7],  (const float*)d_in[13], (const float*)d_in[19]};
  const float* ab[3]  = {(const float*)d_in[8],  (const float*)d_in[14], (const float*)d_in[20]};
  const float* apw1 = (const float*)d_in[21];
  const float* apb1 = (const float*)d_in[22];
  const float* apw2 = (const float*)d_in[23];
  const float* apb2 = (const float*)d_in[24];
  float* out = (float*)d_out;

  // ---- workspace carve ----
  char* p = (char*)d_ws;
  auto alloc = [&](size_t bytes) -> void* {
    void* r = (void*)p; p += (bytes + 255) & ~(size_t)255; return r;
  };
  float* f1 = (float*)alloc((size_t)NN*512*4);
  unsigned short* actH0 = (unsigned short*)alloc((size_t)NN*512*2);
  unsigned short* actL0 = (unsigned short*)alloc((size_t)NN*512*2);
  unsigned short* actH1 = (unsigned short*)alloc((size_t)NN*512*2);
  unsigned short* actL1 = (unsigned short*)alloc((size_t)NN*512*2);
  unsigned short* x0h = (unsigned short*)alloc((size_t)NN*64*2);
  unsigned short* x0l = (unsigned short*)alloc((size_t)NN*64*2);
  const int wK[7]  = {36, 128, 128, 256, 256, 512, 512};
  const int wM[7]  = {128, 128, 256, 256, 512, 512, 256};
  const int wKp[7] = {64, 128, 128, 256, 256, 512, 512};
  const float* wsrc[7] = {gw[0], aw[0], gw[1], aw[1], gw[2], aw[2], apw1};
  unsigned short* wTh[7]; unsigned short* wTl[7];
  for (int i = 0; i < 7; i++){
    size_t sz = (size_t)wM[i]*wKp[i]*2;
    wTh[i] = (unsigned short*)alloc(sz);
    wTl[i] = (unsigned short*)alloc(sz);
  }
  float* ealpha = (float*)alloc((size_t)NE*NH*4);
  float* dinv = (float*)alloc(NN*4);
  float* as_  = (float*)alloc(NN*NH*4);
  float* ad_  = (float*)alloc(NN*NH*4);
  float* eself= (float*)alloc(NN*NH*4);
  float* den  = (float*)alloc(NN*NH*4);
  float* apre = (float*)alloc(NN*4);
  float* pw   = (float*)alloc(NN*4);
  int* rowptr = (int*)alloc((NN+1)*4);
  int* colidx = (int*)alloc((size_t)NE*4);
  int* cnt    = (int*)alloc(NN*4);
  int* cursor = (int*)alloc(NN*4);
  int* starts = (int*)alloc((NB+1)*4);

  // ---- CSR build + degrees + starts (fused) ----
  hipMemsetAsync(cnt, 0, NN*sizeof(int), stream);
  k_count<<<(NE+255)/256, 256, 0, stream>>>(dst, cnt);
  k_scan<<<1, 256, 0, stream>>>(cnt, rowptr, dinv, cursor, batch, starts);
  k_fill<<<(NE+255)/256, 256, 0, stream>>>(src, dst, rowptr, cursor, colidx);

  // ---- fused conversions (1 launch) ----
  AllConv ac;
  ac.src[0] = x0; ac.dh[0] = x0h; ac.dl[0] = x0l;
  ac.K[0] = 36; ac.Mm[0] = NN; ac.Kp[0] = 64; ac.tot[0] = NN*64;
  int maxtot = NN*64;
  for (int i = 0; i < 7; i++){
    ac.src[i+1] = wsrc[i]; ac.dh[i+1] = wTh[i]; ac.dl[i+1] = wTl[i];
    ac.K[i+1] = wK[i]; ac.Mm[i+1] = wM[i]; ac.Kp[i+1] = wKp[i];
    ac.tot[i+1] = wKp[i]*wM[i];
    if (ac.tot[i+1] > maxtot) maxtot = ac.tot[i+1];
  }
  k_convall<<<dim3((maxtot+255)/256, 8), 256, 0, stream>>>(ac);

  auto gemm = [&](const unsigned short* Ahp, const unsigned short* Alp, int wi, int M){
    int nblk = (M/GBN) * ((NN+GBM-1)/GBM);
    k_gemm_bf3<<<nblk, 256, 0, stream>>>(Ahp, Alp, wTh[wi], wTl[wi], f1, NN, wKp[wi], M);
  };

  const int dims[4] = {36, 128, 256, 512};
  const int ngrp = (NN + 15) / 16;
  const unsigned short* curH = x0h; const unsigned short* curL = x0l;
  int wi = 0;
  for (int i = 0; i < 3; i++){
    int M = dims[i+1], C = M/NH;
    int nchunk = M / 64;
    // GCN
    gemm(curH, curL, wi++, M);
    k_gcn_gather<<<nchunk*ngrp, 256, 0, stream>>>(f1, dinv, rowptr, colidx, gb[i],
                                                  actH0, actL0, M, nchunk);
    // GAT
    gemm(actH0, actL0, wi++, M);
    k_gat_alpha<<<(NN*NH+255)/256, 256, 0, stream>>>(f1, asw[i], adw[i], as_, ad_, M, C);
    k_gat_maxden<<<(NN*NH+255)/256, 256, 0, stream>>>(rowptr, colidx, as_, ad_, eself, den, ealpha);
    k_gat_gather<<<nchunk*ngrp, 256, 0, stream>>>(f1, actH0, actL0, rowptr, colidx,
                                                  ealpha, eself, den, ab[i],
                                                  actH1, actL1, M, C, nchunk);
    curH = actH1; curL = actL1;
  }

  // ---- pooling ----
  gemm(actH1, actL1, 6, 256);
  k_tanh_dot<<<NN, 64, 0, stream>>>(f1, apb1, apw2, apb2, apre);
  k_pool_prep<<<NB, 64, 0, stream>>>(apre, starts, pw);
  k_pool<<<NB, 128, 0, stream>>>(actH1, actL1, pw, starts, out);
}

// Round 10
// 465.095 us; speedup vs baseline: 4.9648x; 1.0380x over previous
//
#include <hip/hip_runtime.h>
#include <math.h>

#define NN 10000
#define NE 160000
#define NB 128
#define NH 4
#define DOUT 512
#define NEG 0.2f

typedef __attribute__((ext_vector_type(8))) short short8;
typedef __attribute__((ext_vector_type(4))) float f32x4;
typedef __attribute__((ext_vector_type(4))) unsigned short us4;

__device__ __forceinline__ float leakyf(float v){ return v > 0.f ? v : NEG*v; }
__device__ __forceinline__ void fma4(float4& a, const float4 v, float w){
  a.x += v.x*w; a.y += v.y*w; a.z += v.z*w; a.w += v.w*w;
}
__device__ __forceinline__ unsigned short f2bf(float f){
  unsigned int u = __float_as_uint(f);
  u += 0x7FFFu + ((u >> 16) & 1u);
  return (unsigned short)(u >> 16);
}
__device__ __forceinline__ float bf2f(unsigned short h){
  return __uint_as_float(((unsigned int)h) << 16);
}
__device__ __forceinline__ void split2(float v, unsigned short& h, unsigned short& l){
  h = f2bf(v);
  l = f2bf(v - bf2f(h));
}
__device__ __forceinline__ void store_hl(unsigned short* H, unsigned short* L,
                                         size_t base, float4 v){
  us4 h, l; unsigned short hh, ll;
  split2(v.x, hh, ll); h[0]=hh; l[0]=ll;
  split2(v.y, hh, ll); h[1]=hh; l[1]=ll;
  split2(v.z, hh, ll); h[2]=hh; l[2]=ll;
  split2(v.w, hh, ll); h[3]=hh; l[3]=ll;
  *(us4*)&H[base] = h;
  *(us4*)&L[base] = l;
}
__device__ __forceinline__ float4 load_hl(const unsigned short* __restrict__ H,
                                          const unsigned short* __restrict__ L, size_t base){
  us4 h = *(const us4*)&H[base];
  us4 l = *(const us4*)&L[base];
  return make_float4(bf2f(h[0])+bf2f(l[0]), bf2f(h[1])+bf2f(l[1]),
                     bf2f(h[2])+bf2f(l[2]), bf2f(h[3])+bf2f(l[3]));
}
__device__ __forceinline__ void gl_lds16(const unsigned short* g, unsigned short* l){
  __builtin_amdgcn_global_load_lds(
      (const __attribute__((address_space(1))) unsigned int*)g,
      (__attribute__((address_space(3))) unsigned int*)l, 16, 0, 0);
}

// ================= CSR build =================
__global__ void k_count(const int* __restrict__ dst, int* __restrict__ cnt){
  int e = blockIdx.x*blockDim.x + threadIdx.x;
  if (e < NE) atomicAdd(&cnt[dst[e]], 1);
}
__global__ void k_scan(const int* __restrict__ cnt, int* __restrict__ rowptr,
                       float* __restrict__ dinv, int* __restrict__ cursor,
                       const int* __restrict__ batch, int* __restrict__ starts){
  __shared__ int part[256];
  const int CH = (NN + 255) / 256;
  int t = threadIdx.x;
  int base = t * CH;
  int s = 0;
  for (int i = 0; i < CH; i++){ int idx = base + i; if (idx < NN) s += cnt[idx]; }
  part[t] = s; __syncthreads();
  for (int o = 1; o < 256; o <<= 1){
    int v = 0;
    if (t >= o) v = part[t - o];
    __syncthreads();
    if (t >= o) part[t] += v;
    __syncthreads();
  }
  int pre = (t == 0) ? 0 : part[t - 1];
  for (int i = 0; i < CH; i++){
    int idx = base + i;
    if (idx < NN){
      int c = cnt[idx];
      rowptr[idx] = pre; pre += c;
      dinv[idx] = rsqrtf((float)c + 1.f);
      cursor[idx] = 0;
    }
  }
  if (t == 255) rowptr[NN] = part[255];
  if (t <= NB){
    int lo = 0, hi = NN;
    while (lo < hi){ int mid = (lo + hi) >> 1; if (batch[mid] < t) lo = mid + 1; else hi = mid; }
    starts[t] = lo;
  }
}
__global__ void k_fill(const int* __restrict__ src, const int* __restrict__ dst,
                       const int* __restrict__ rowptr, int* __restrict__ cursor,
                       int* __restrict__ colidx){
  int e = blockIdx.x*blockDim.x + threadIdx.x;
  if (e >= NE) return;
  int d = dst[e];
  int pos = atomicAdd(&cursor[d], 1);
  colidx[rowptr[d] + pos] = src[e];
}

// ============ fused conversions: job 0 = x0 pad-convert, jobs 1..7 = W^T ============
struct AllConv {
  const float* src[8];
  unsigned short* dh[8];
  unsigned short* dl[8];
  int K[8], Mm[8], Kp[8], tot[8];
};
__global__ void k_convall(AllConv a){
  int j = blockIdx.y;
  int idx = blockIdx.x*blockDim.x + threadIdx.x;
  if (idx >= a.tot[j]) return;
  float v;
  if (j == 0){
    int n = idx >> 6, c = idx & 63;
    v = (c < 36) ? a.src[0][n*36 + c] : 0.f;
  } else {
    int Kp = a.Kp[j], K = a.K[j], M = a.Mm[j];
    int kk = idx % Kp, m = idx / Kp;
    v = (kk < K) ? a.src[j][(size_t)kk*M + m] : 0.f;
  }
  unsigned short h, l; split2(v, h, l);
  a.dh[j][idx] = h; a.dl[j][idx] = l;
}

// ===== GEMM: C[N,M] = (Ah+Al)[N,Kp] @ (Bh+Bl)^T, bf16x3, m97-style =====
// 64x128 tile, 4 waves x (4m x 2n), global_load_lds staging, chunk swizzle.
// mode 0: plain fp32 -> C
// mode 1: GCN epilogue: relu(acc + bias) -> hi/lo bf16
// mode 2: GAT epilogue: fp32 -> C, plus fused per-head alpha dots -> as_o/ad_o
#define GBM 64
#define GBN 128
#define GBK 32
__global__ __launch_bounds__(256) void k_gemm_bf3(
    const unsigned short* __restrict__ Ah, const unsigned short* __restrict__ Al,
    const unsigned short* __restrict__ Bh, const unsigned short* __restrict__ Bl,
    float* __restrict__ C, int N, int Kp, int M, int mode,
    const float* __restrict__ bias, unsigned short* __restrict__ outH,
    unsigned short* __restrict__ outL,
    const float* __restrict__ a_s, const float* __restrict__ a_d,
    float* __restrict__ as_o, float* __restrict__ ad_o, int Cdim){
  __shared__ unsigned short AsH[GBM*GBK], AsL[GBM*GBK];
  __shared__ unsigned short BsH[GBN*GBK], BsL[GBN*GBK];
  __shared__ float sred[2][GBM][4];
  int gx = M / GBN;
  int gy = (N + GBM - 1) / GBM;
  const int G = 8;
  int bid = blockIdx.x;
  int full = gy / G;
  int bid_full = full * G * gx;
  int by, bx;
  if (bid < bid_full){
    int g = bid / (G*gx); int rem = bid % (G*gx);
    by = g*G + rem % G; bx = rem / G;
  } else {
    int rem = bid - bid_full; int rows = gy - full*G;
    by = full*G + rem % rows; bx = rem / rows;
  }
  int row0 = by * GBM, col0 = bx * GBN;
  int t = threadIdx.x;
  int w = t >> 6, L = t & 63;
  int lm = L & 15, lq = L >> 4;
  int wc = w * 32;

  int sr = L >> 2, sc = L & 3;
  int art = w*16 + sr;
  int ga  = (sc - ((art >> 1) & 3)) & 3;
  int agrow = min(row0 + art, N-1);
  int brt0 = w*16 + sr;
  int brt1 = (w+4)*16 + sr;
  int gb0 = (sc - ((brt0 >> 1) & 3)) & 3;
  int gb1 = (sc - ((brt1 >> 1) & 3)) & 3;
  int bgrow0 = col0 + brt0, bgrow1 = col0 + brt1;

  int rc = (lq + (lm >> 1)) & 3;
  int aoff[4], boff[2];
#pragma unroll
  for (int mi = 0; mi < 4; mi++) aoff[mi] = (mi*16 + lm)*32 + rc*8;
#pragma unroll
  for (int ni = 0; ni < 2; ni++) boff[ni] = (wc + ni*16 + lm)*32 + rc*8;

  f32x4 acc[4][2];
#pragma unroll
  for (int i = 0; i < 4; i++)
#pragma unroll
    for (int j = 0; j < 2; j++) acc[i][j] = (f32x4){0.f,0.f,0.f,0.f};

  int nk = Kp / GBK;
  for (int kt = 0; kt < nk; kt++){
    int k0 = kt * GBK;
    if (kt) __syncthreads();
    gl_lds16(&Ah[(size_t)agrow*Kp + k0 + ga*8],  &AsH[w*512]);
    gl_lds16(&Al[(size_t)agrow*Kp + k0 + ga*8],  &AsL[w*512]);
    gl_lds16(&Bh[(size_t)bgrow0*Kp + k0 + gb0*8], &BsH[w*512]);
    gl_lds16(&Bh[(size_t)bgrow1*Kp + k0 + gb1*8], &BsH[(w+4)*512]);
    gl_lds16(&Bl[(size_t)bgrow0*Kp + k0 + gb0*8], &BsL[w*512]);
    gl_lds16(&Bl[(size_t)bgrow1*Kp + k0 + gb1*8], &BsL[(w+4)*512]);
    __syncthreads();

    short8 ah[4], al[4], bh[2], bl[2];
#pragma unroll
    for (int mi = 0; mi < 4; mi++){
      ah[mi] = *(const short8*)&AsH[aoff[mi]];
      al[mi] = *(const short8*)&AsL[aoff[mi]];
    }
#pragma unroll
    for (int ni = 0; ni < 2; ni++){
      bh[ni] = *(const short8*)&BsH[boff[ni]];
      bl[ni] = *(const short8*)&BsL[boff[ni]];
    }
#pragma unroll
    for (int mi = 0; mi < 4; mi++)
#pragma unroll
      for (int ni = 0; ni < 2; ni++){
        acc[mi][ni] = __builtin_amdgcn_mfma_f32_16x16x32_bf16(ah[mi], bh[ni], acc[mi][ni], 0, 0, 0);
        acc[mi][ni] = __builtin_amdgcn_mfma_f32_16x16x32_bf16(ah[mi], bl[ni], acc[mi][ni], 0, 0, 0);
        acc[mi][ni] = __builtin_amdgcn_mfma_f32_16x16x32_bf16(al[mi], bh[ni], acc[mi][ni], 0, 0, 0);
      }
  }
  // ---- epilogue; C/D layout col=lane&15, row=(lane>>4)*4+reg ----
  if (mode == 1){
#pragma unroll
    for (int mi = 0; mi < 4; mi++)
#pragma unroll
      for (int ni = 0; ni < 2; ni++){
#pragma unroll
        for (int r = 0; r < 4; r++){
          int row = row0 + mi*16 + lq*4 + r;
          int col = col0 + wc + ni*16 + lm;
          if (row < N){
            float v = fmaxf(acc[mi][ni][r] + bias[col], 0.f);
            unsigned short hh, ll; split2(v, hh, ll);
            outH[(size_t)row*M + col] = hh;
            outL[(size_t)row*M + col] = ll;
          }
        }
      }
  } else {
#pragma unroll
    for (int mi = 0; mi < 4; mi++)
#pragma unroll
      for (int ni = 0; ni < 2; ni++){
#pragma unroll
        for (int r = 0; r < 4; r++){
          int row = row0 + mi*16 + lq*4 + r;
          int col = col0 + wc + ni*16 + lm;
          if (row < N) C[(size_t)row*M + col] = acc[mi][ni][r];
        }
      }
  }
  if (mode == 2){
    // fused alpha dots: wave covers 32 cols, always within one head (Cdim>=32)
    float sA0 = a_s[col0 + wc + lm], sA1 = a_s[col0 + wc + 16 + lm];
    float dA0 = a_d[col0 + wc + lm], dA1 = a_d[col0 + wc + 16 + lm];
#pragma unroll
    for (int mi = 0; mi < 4; mi++)
#pragma unroll
      for (int r = 0; r < 4; r++){
        float vs = acc[mi][0][r]*sA0 + acc[mi][1][r]*sA1;
        float vd = acc[mi][0][r]*dA0 + acc[mi][1][r]*dA1;
#pragma unroll
        for (int o = 1; o <= 8; o <<= 1){
          vs += __shfl_xor(vs, o);
          vd += __shfl_xor(vd, o);
        }
        if (lm == 0){
          int row = mi*16 + lq*4 + r;
          sred[0][row][w] = vs;
          sred[1][row][w] = vd;
        }
      }
    __syncthreads();
    if (t < GBM){
      int n = row0 + t;
      if (n < N){
        int wph = Cdim >> 5;          // waves per head
        int nheads = 4 / wph;
        for (int g = 0; g < nheads; g++){
          float ss = 0.f, dd = 0.f;
          for (int q = 0; q < wph; q++){
            ss += sred[0][t][g*wph + q];
            dd += sred[1][t][g*wph + q];
          }
          int hd = (col0 + g*wph*32) / Cdim;
          as_o[n*NH + hd] = ss;
          ad_o[n*NH + hd] = dd;
        }
      }
    }
  }
}

// ===== GCN pre-aggregation: aggregate X at input dim (A(XW) = (AX)W) =====
__global__ __launch_bounds__(256) void k_gcn_pre(
    const unsigned short* __restrict__ inH, const unsigned short* __restrict__ inL,
    const float* __restrict__ dinv,
    const int* __restrict__ rowptr, const int* __restrict__ colidx,
    unsigned short* __restrict__ outH, unsigned short* __restrict__ outL,
    int Kp, int nchunk){
  int bid = blockIdx.x;
  int chunk = bid % nchunk, grp = bid / nchunk;
  int t = threadIdx.x;
  int sub = t & 15;
  int n = grp*16 + (t >> 4);
  if (n >= NN) return;
  int f0 = chunk*64 + sub*4;
  int b = rowptr[n], e = rowptr[n+1];
  float dn = dinv[n];
  float4 a0 = make_float4(0,0,0,0), a1 = make_float4(0,0,0,0);
  float4 a2 = make_float4(0,0,0,0), a3 = make_float4(0,0,0,0);
  int j = b;
  for (; j + 3 < e; j += 4){
    int s0 = colidx[j], s1 = colidx[j+1], s2 = colidx[j+2], s3 = colidx[j+3];
    float w0 = dinv[s0], w1 = dinv[s1], w2 = dinv[s2], w3 = dinv[s3];
    float4 v0 = load_hl(inH, inL, (size_t)s0*Kp + f0);
    float4 v1 = load_hl(inH, inL, (size_t)s1*Kp + f0);
    float4 v2 = load_hl(inH, inL, (size_t)s2*Kp + f0);
    float4 v3 = load_hl(inH, inL, (size_t)s3*Kp + f0);
    fma4(a0, v0, w0*dn); fma4(a1, v1, w1*dn);
    fma4(a2, v2, w2*dn); fma4(a3, v3, w3*dn);
  }
  for (; j < e; j++){
    int s = colidx[j];
    float4 v = load_hl(inH, inL, (size_t)s*Kp + f0);
    fma4(a0, v, dinv[s]*dn);
  }
  float4 acc = make_float4(a0.x+a1.x+a2.x+a3.x, a0.y+a1.y+a2.y+a3.y,
                           a0.z+a1.z+a2.z+a3.z, a0.w+a1.w+a2.w+a3.w);
  float4 sv = load_hl(inH, inL, (size_t)n*Kp + f0);
  float dn2 = dn*dn;
  acc.x += sv.x*dn2; acc.y += sv.y*dn2; acc.z += sv.z*dn2; acc.w += sv.w*dn2;
  store_hl(outH, outL, (size_t)n*Kp + f0, acc);
}

// ===== GAT maxden: pass1 scattered logits cached + max; pass2 sequential exp =====
__global__ void k_gat_maxden(const int* __restrict__ rowptr, const int* __restrict__ colidx,
                             const float* __restrict__ as_, const float* __restrict__ ad_,
                             float* __restrict__ eself, float* __restrict__ den,
                             float* __restrict__ ealpha){
  int idx = blockIdx.x*blockDim.x + threadIdx.x;
  if (idx >= NN*NH) return;
  int n = idx >> 2, hd = idx & 3;
  float adn = ad_[idx];
  float selflog = leakyf(as_[idx] + adn);
  int b = rowptr[n], e = rowptr[n+1];
  float m0 = selflog, m1 = -INFINITY, m2 = -INFINITY, m3 = -INFINITY;
  int j = b;
  for (; j + 3 < e; j += 4){
    int s0 = colidx[j], s1 = colidx[j+1], s2 = colidx[j+2], s3 = colidx[j+3];
    float l0 = leakyf(as_[s0*NH + hd] + adn), l1 = leakyf(as_[s1*NH + hd] + adn);
    float l2 = leakyf(as_[s2*NH + hd] + adn), l3 = leakyf(as_[s3*NH + hd] + adn);
    ealpha[(size_t)(j+0)*NH + hd] = l0; ealpha[(size_t)(j+1)*NH + hd] = l1;
    ealpha[(size_t)(j+2)*NH + hd] = l2; ealpha[(size_t)(j+3)*NH + hd] = l3;
    m0 = fmaxf(m0, l0); m1 = fmaxf(m1, l1);
    m2 = fmaxf(m2, l2); m3 = fmaxf(m3, l3);
  }
  for (; j < e; j++){
    float l = leakyf(as_[colidx[j]*NH + hd] + adn);
    ealpha[(size_t)j*NH + hd] = l;
    m0 = fmaxf(m0, l);
  }
  float m = fmaxf(fmaxf(m0, m1), fmaxf(m2, m3));
  float es = expf(selflog - m);
  float d0 = es, d1 = 0.f, d2 = 0.f, d3 = 0.f;
  j = b;
  for (; j + 3 < e; j += 4){
    float v0 = expf(ealpha[(size_t)(j+0)*NH + hd] - m);
    float v1 = expf(ealpha[(size_t)(j+1)*NH + hd] - m);
    float v2 = expf(ealpha[(size_t)(j+2)*NH + hd] - m);
    float v3 = expf(ealpha[(size_t)(j+3)*NH + hd] - m);
    ealpha[(size_t)(j+0)*NH + hd] = v0; ealpha[(size_t)(j+1)*NH + hd] = v1;
    ealpha[(size_t)(j+2)*NH + hd] = v2; ealpha[(size_t)(j+3)*NH + hd] = v3;
    d0 += v0; d1 += v1; d2 += v2; d3 += v3;
  }
  for (; j < e; j++){
    float v = expf(ealpha[(size_t)j*NH + hd] - m);
    ealpha[(size_t)j*NH + hd] = v;
    d0 += v;
  }
  eself[idx] = es;
  den[idx] = (d0 + d1) + (d2 + d3);
}
// ===== GAT gather: feature-chunked, XCD-aligned, 4-way edge-unrolled =====
__global__ __launch_bounds__(256) void k_gat_gather(
    const float* __restrict__ hg,
    const unsigned short* __restrict__ inH, const unsigned short* __restrict__ inL,
    const int* __restrict__ rowptr, const int* __restrict__ colidx,
    const float* __restrict__ ealpha, const float* __restrict__ eself,
    const float* __restrict__ den, const float* __restrict__ ab,
    unsigned short* __restrict__ outH, unsigned short* __restrict__ outL,
    int M, int C, int nchunk){
  int bid = blockIdx.x;
  int chunk = bid % nchunk, grp = bid / nchunk;
  int t = threadIdx.x;
  int sub = t & 15;
  int n = grp*16 + (t >> 4);
  if (n >= NN) return;
  int f0 = chunk*64 + sub*4;
  int hd = f0 / C;
  int b = rowptr[n], e = rowptr[n+1];
  float4 a0 = make_float4(0,0,0,0), a1 = make_float4(0,0,0,0);
  float4 a2 = make_float4(0,0,0,0), a3 = make_float4(0,0,0,0);
  int j = b;
  for (; j + 3 < e; j += 4){
    int s0 = colidx[j], s1 = colidx[j+1], s2 = colidx[j+2], s3 = colidx[j+3];
    float e0 = ealpha[(size_t)(j+0)*NH + hd], e1 = ealpha[(size_t)(j+1)*NH + hd];
    float e2 = ealpha[(size_t)(j+2)*NH + hd], e3 = ealpha[(size_t)(j+3)*NH + hd];
    float4 v0 = *(const float4*)&hg[(size_t)s0*M + f0];
    float4 v1 = *(const float4*)&hg[(size_t)s1*M + f0];
    float4 v2 = *(const float4*)&hg[(size_t)s2*M + f0];
    float4 v3 = *(const float4*)&hg[(size_t)s3*M + f0];
    fma4(a0, v0, e0); fma4(a1, v1, e1);
    fma4(a2, v2, e2); fma4(a3, v3, e3);
  }
  for (; j < e; j++){
    int s = colidx[j];
    float4 v = *(const float4*)&hg[(size_t)s*M + f0];
    fma4(a0, v, ealpha[(size_t)j*NH + hd]);
  }
  float4 acc = make_float4(a0.x+a1.x+a2.x+a3.x, a0.y+a1.y+a2.y+a3.y,
                           a0.z+a1.z+a2.z+a3.z, a0.w+a1.w+a2.w+a3.w);
  int ai = n*NH + hd;
  float es = eself[ai], inv = 1.f/den[ai];
  float4 sv = *(const float4*)&hg[(size_t)n*M + f0];
  float4 hv = load_hl(inH, inL, (size_t)n*M + f0);
  float4 bb = *(const float4*)&ab[f0];
  float4 r = make_float4(
    hv.x + bb.x + (sv.x*es + acc.x)*inv,
    hv.y + bb.y + (sv.y*es + acc.y)*inv,
    hv.z + bb.z + (sv.z*es + acc.z)*inv,
    hv.w + bb.w + (sv.w*es + acc.w)*inv);
  store_hl(outH, outL, (size_t)n*M + f0, r);
}

// ================= attention pooling =================
__global__ void k_tanh_dot(const float* __restrict__ t1, const float* __restrict__ b1,
                           const float* __restrict__ w2, const float* __restrict__ b2,
                           float* __restrict__ apre){
  int n = blockIdx.x, t = threadIdx.x;
  float4 v  = ((const float4*)(t1 + (size_t)n*256))[t];
  float4 bb = ((const float4*)b1)[t];
  float4 ww = ((const float4*)w2)[t];
  float s = tanhf(v.x+bb.x)*ww.x + tanhf(v.y+bb.y)*ww.y
          + tanhf(v.z+bb.z)*ww.z + tanhf(v.w+bb.w)*ww.w;
  for (int o = 32; o > 0; o >>= 1) s += __shfl_xor(s, o);
  if (t == 0) apre[n] = s + b2[0];
}
__global__ void k_pool_prep(const float* __restrict__ apre, const int* __restrict__ starts,
                            float* __restrict__ pw){
  int g = blockIdx.x, t = threadIdx.x;
  int b = starts[g], e = starts[g+1];
  float m = -INFINITY;
  for (int n = b + t; n < e; n += 64) m = fmaxf(m, apre[n]);
  for (int o = 32; o > 0; o >>= 1) m = fmaxf(m, __shfl_xor(m, o));
  float s = 0.f;
  for (int n = b + t; n < e; n += 64) s += expf(apre[n] - m);
  for (int o = 32; o > 0; o >>= 1) s += __shfl_xor(s, o);
  float inv = 1.f / (s + 1e-8f);
  for (int n = b + t; n < e; n += 64) pw[n] = expf(apre[n] - m) * inv;
}
__global__ void k_pool(const unsigned short* __restrict__ xH, const unsigned short* __restrict__ xL,
                       const float* __restrict__ pw, const int* __restrict__ starts,
                       float* __restrict__ out){
  int g = blockIdx.x, t = threadIdx.x;
  int b = starts[g], e = starts[g+1];
  float4 sum = make_float4(0,0,0,0), wacc = make_float4(0,0,0,0);
  float4 mx = make_float4(-INFINITY,-INFINITY,-INFINITY,-INFINITY);
  for (int n = b; n < e; n++){
    float4 xv = load_hl(xH, xL, (size_t)n*DOUT + t*4);
    float p = pw[n];
    sum.x += xv.x; sum.y += xv.y; sum.z += xv.z; sum.w += xv.w;
    mx.x = fmaxf(mx.x, xv.x); mx.y = fmaxf(mx.y, xv.y);
    mx.z = fmaxf(mx.z, xv.z); mx.w = fmaxf(mx.w, xv.w);
    fma4(wacc, xv, p);
  }
  float ic = 1.f / fmaxf((float)(e - b), 1.f);
  float4* o = (float4*)(out + (size_t)g*4*DOUT);
  o[t]       = wacc;
  o[128 + t] = make_float4(sum.x*ic, sum.y*ic, sum.z*ic, sum.w*ic);
  o[256 + t] = mx;
  o[384 + t] = sum;
}

extern "C" void kernel_launch(void* const* d_in, const int* in_sizes, int n_in,
                              void* d_out, int out_size, void* d_ws, size_t ws_size,
                              hipStream_t stream) {
  const float* x0   = (const float*)d_in[0];
  const int*   ei   = (const int*)d_in[1];
  const int*   src  = ei;
  const int*   dst  = ei + NE;
  const int*   batch= (const int*)d_in[2];
  const float* gw[3]  = {(const float*)d_in[3],  (const float*)d_in[9],  (const float*)d_in[15]};
  const float* gb[3]  = {(const float*)d_in[4],  (const float*)d_in[10], (const float*)d_in[16]};
  const float* aw[3]  = {(const float*)d_in[5],  (const float*)d_in[11], (const float*)d_in[17]};
  const float* asw[3] = {(const float*)d_in[6],  (const float*)d_in[12], (const float*)d_in[18]};
  const float* adw[3] = {(const float*)d_in[7],  (const float*)d_in[13], (const float*)d_in[19]};
  const float* ab[3]  = {(const float*)d_in[8],  (const float*)d_in[14], (const float*)d_in[20]};
  const float* apw1 = (const float*)d_in[21];
  const float* apb1 = (const float*)d_in[22];
  const float* apw2 = (const float*)d_in[23];
  const float* apb2 = (const float*)d_in[24];
  float* out = (float*)d_out;

  // ---- workspace carve ----
  char* p = (char*)d_ws;
  auto alloc = [&](size_t bytes) -> void* {
    void* r = (void*)p; p += (bytes + 255) & ~(size_t)255; return r;
  };
  float* f1 = (float*)alloc((size_t)NN*512*4);
  unsigned short* actH0 = (unsigned short*)alloc((size_t)NN*512*2);   // h (GCN out)
  unsigned short* actL0 = (unsigned short*)alloc((size_t)NN*512*2);
  unsigned short* actH1 = (unsigned short*)alloc((size_t)NN*512*2);   // x (layer out)
  unsigned short* actL1 = (unsigned short*)alloc((size_t)NN*512*2);
  unsigned short* preH  = (unsigned short*)alloc((size_t)NN*256*2);   // aggregated X
  unsigned short* preL  = (unsigned short*)alloc((size_t)NN*256*2);
  unsigned short* x0h = (unsigned short*)alloc((size_t)NN*64*2);
  unsigned short* x0l = (unsigned short*)alloc((size_t)NN*64*2);
  const int wK[7]  = {36, 128, 128, 256, 256, 512, 512};
  const int wM[7]  = {128, 128, 256, 256, 512, 512, 256};
  const int wKp[7] = {64, 128, 128, 256, 256, 512, 512};
  const float* wsrc[7] = {gw[0], aw[0], gw[1], aw[1], gw[2], aw[2], apw1};
  unsigned short* wTh[7]; unsigned short* wTl[7];
  for (int i = 0; i < 7; i++){
    size_t sz = (size_t)wM[i]*wKp[i]*2;
    wTh[i] = (unsigned short*)alloc(sz);
    wTl[i] = (unsigned short*)alloc(sz);
  }
  float* ealpha = (float*)alloc((size_t)NE*NH*4);
  float* dinv = (float*)alloc(NN*4);
  float* as_  = (float*)alloc(NN*NH*4);
  float* ad_  = (float*)alloc(NN*NH*4);
  float* eself= (float*)alloc(NN*NH*4);
  float* den  = (float*)alloc(NN*NH*4);
  float* apre = (float*)alloc(NN*4);
  float* pw   = (float*)alloc(NN*4);
  int* rowptr = (int*)alloc((NN+1)*4);
  int* colidx = (int*)alloc((size_t)NE*4);
  int* cnt    = (int*)alloc(NN*4);
  int* cursor = (int*)alloc(NN*4);
  int* starts = (int*)alloc((NB+1)*4);

  // ---- CSR build + degrees + starts (fused) ----
  hipMemsetAsync(cnt, 0, NN*sizeof(int), stream);
  k_count<<<(NE+255)/256, 256, 0, stream>>>(dst, cnt);
  k_scan<<<1, 256, 0, stream>>>(cnt, rowptr, dinv, cursor, batch, starts);
  k_fill<<<(NE+255)/256, 256, 0, stream>>>(src, dst, rowptr, cursor, colidx);

  // ---- fused conversions ----
  AllConv ac;
  ac.src[0] = x0; ac.dh[0] = x0h; ac.dl[0] = x0l;
  ac.K[0] = 36; ac.Mm[0] = NN; ac.Kp[0] = 64; ac.tot[0] = NN*64;
  int maxtot = NN*64;
  for (int i = 0; i < 7; i++){
    ac.src[i+1] = wsrc[i]; ac.dh[i+1] = wTh[i]; ac.dl[i+1] = wTl[i];
    ac.K[i+1] = wK[i]; ac.Mm[i+1] = wM[i]; ac.Kp[i+1] = wKp[i];
    ac.tot[i+1] = wKp[i]*wM[i];
    if (ac.tot[i+1] > maxtot) maxtot = ac.tot[i+1];
  }
  k_convall<<<dim3((maxtot+255)/256, 8), 256, 0, stream>>>(ac);

  const int dims[4] = {36, 128, 256, 512};
  const int ngrp = (NN + 15) / 16;
  const unsigned short* curH = x0h; const unsigned short* curL = x0l;
  int wi = 0;
  for (int i = 0; i < 3; i++){
    int Kin = (i == 0) ? 64 : dims[i];   // padded input dim
    int M = dims[i+1], C = M/NH;
    int nchunk_in = Kin / 64;
    int nchunk = M / 64;
    int nblk = (M/GBN) * ((NN+GBM-1)/GBM);
    // GCN: aggregate X at input dim, then GEMM with fused bias+relu+split epilogue
    k_gcn_pre<<<nchunk_in*ngrp, 256, 0, stream>>>(curH, curL, dinv, rowptr, colidx,
                                                  preH, preL, Kin, nchunk_in);
    k_gemm_bf3<<<nblk, 256, 0, stream>>>(preH, preL, wTh[wi], wTl[wi], f1, NN, wKp[wi], M,
                                         1, gb[i], actH0, actL0,
                                         nullptr, nullptr, nullptr, nullptr, C);
    wi++;
    // GAT: GEMM with fused alpha-dot epilogue
    k_gemm_bf3<<<nblk, 256, 0, stream>>>(actH0, actL0, wTh[wi], wTl[wi], f1, NN, wKp[wi], M,
                                         2, nullptr, nullptr, nullptr,
                                         asw[i], adw[i], as_, ad_, C);
    wi++;
    k_gat_maxden<<<(NN*NH+255)/256, 256, 0, stream>>>(rowptr, colidx, as_, ad_, eself, den, ealpha);
    k_gat_gather<<<nchunk*ngrp, 256, 0, stream>>>(f1, actH0, actL0, rowptr, colidx,
                                                  ealpha, eself, den, ab[i],
                                                  actH1, actL1, M, C, nchunk);
    curH = actH1; curL = actL1;
  }

  // ---- pooling ----
  {
    int nblk = (256/GBN) * ((NN+GBM-1)/GBM);
    k_gemm_bf3<<<nblk, 256, 0, stream>>>(actH1, actL1, wTh[6], wTl[6], f1, NN, wKp[6], 256,
                                         0, nullptr, nullptr, nullptr,
                                         nullptr, nullptr, nullptr, nullptr, 64);
  }
  k_tanh_dot<<<NN, 64, 0, stream>>>(f1, apb1, apw2, apb2, apre);
  k_pool_prep<<<NB, 64, 0, stream>>>(apre, starts, pw);
  k_pool<<<NB, 128, 0, stream>>>(actH1, actL1, pw, starts, out);
}

// Round 11
// 455.949 us; speedup vs baseline: 5.0644x; 1.0201x over previous
//
#include <hip/hip_runtime.h>
#include <math.h>

#define NN 10000
#define NE 160000
#define NB 128
#define NH 4
#define DOUT 512
#define NEG 0.2f

typedef __attribute__((ext_vector_type(8))) short short8;
typedef __attribute__((ext_vector_type(4))) float f32x4;
typedef __attribute__((ext_vector_type(4))) unsigned short us4;

__device__ __forceinline__ float leakyf(float v){ return v > 0.f ? v : NEG*v; }
__device__ __forceinline__ void fma4(float4& a, const float4 v, float w){
  a.x += v.x*w; a.y += v.y*w; a.z += v.z*w; a.w += v.w*w;
}
__device__ __forceinline__ unsigned short f2bf(float f){
  unsigned int u = __float_as_uint(f);
  u += 0x7FFFu + ((u >> 16) & 1u);
  return (unsigned short)(u >> 16);
}
__device__ __forceinline__ float bf2f(unsigned short h){
  return __uint_as_float(((unsigned int)h) << 16);
}
__device__ __forceinline__ void split2(float v, unsigned short& h, unsigned short& l){
  h = f2bf(v);
  l = f2bf(v - bf2f(h));
}
__device__ __forceinline__ void store_hl(unsigned short* H, unsigned short* L,
                                         size_t base, float4 v){
  us4 h, l; unsigned short hh, ll;
  split2(v.x, hh, ll); h[0]=hh; l[0]=ll;
  split2(v.y, hh, ll); h[1]=hh; l[1]=ll;
  split2(v.z, hh, ll); h[2]=hh; l[2]=ll;
  split2(v.w, hh, ll); h[3]=hh; l[3]=ll;
  *(us4*)&H[base] = h;
  *(us4*)&L[base] = l;
}
__device__ __forceinline__ float4 load_hl(const unsigned short* __restrict__ H,
                                          const unsigned short* __restrict__ L, size_t base){
  us4 h = *(const us4*)&H[base];
  us4 l = *(const us4*)&L[base];
  return make_float4(bf2f(h[0])+bf2f(l[0]), bf2f(h[1])+bf2f(l[1]),
                     bf2f(h[2])+bf2f(l[2]), bf2f(h[3])+bf2f(l[3]));
}
__device__ __forceinline__ void gl_lds16(const unsigned short* g, unsigned short* l){
  __builtin_amdgcn_global_load_lds(
      (const __attribute__((address_space(1))) unsigned int*)g,
      (__attribute__((address_space(3))) unsigned int*)l, 16, 0, 0);
}

// ================= CSR build =================
__global__ void k_count(const int* __restrict__ dst, int* __restrict__ cnt){
  int e = blockIdx.x*blockDim.x + threadIdx.x;
  if (e < NE) atomicAdd(&cnt[dst[e]], 1);
}
__global__ void k_scan(const int* __restrict__ cnt, int* __restrict__ rowptr,
                       float* __restrict__ dinv, int* __restrict__ cursor,
                       const int* __restrict__ batch, int* __restrict__ starts){
  __shared__ int part[256];
  const int CH = (NN + 255) / 256;
  int t = threadIdx.x;
  int base = t * CH;
  int s = 0;
  for (int i = 0; i < CH; i++){ int idx = base + i; if (idx < NN) s += cnt[idx]; }
  part[t] = s; __syncthreads();
  for (int o = 1; o < 256; o <<= 1){
    int v = 0;
    if (t >= o) v = part[t - o];
    __syncthreads();
    if (t >= o) part[t] += v;
    __syncthreads();
  }
  int pre = (t == 0) ? 0 : part[t - 1];
  for (int i = 0; i < CH; i++){
    int idx = base + i;
    if (idx < NN){
      int c = cnt[idx];
      rowptr[idx] = pre; pre += c;
      dinv[idx] = rsqrtf((float)c + 1.f);
      cursor[idx] = 0;
    }
  }
  if (t == 255) rowptr[NN] = part[255];
  if (t <= NB){
    int lo = 0, hi = NN;
    while (lo < hi){ int mid = (lo + hi) >> 1; if (batch[mid] < t) lo = mid + 1; else hi = mid; }
    starts[t] = lo;
  }
}
__global__ void k_fill(const int* __restrict__ src, const int* __restrict__ dst,
                       const int* __restrict__ rowptr, int* __restrict__ cursor,
                       int* __restrict__ colidx){
  int e = blockIdx.x*blockDim.x + threadIdx.x;
  if (e >= NE) return;
  int d = dst[e];
  int pos = atomicAdd(&cursor[d], 1);
  colidx[rowptr[d] + pos] = src[e];
}

// ============ fused conversions: job 0 = x0 pad-convert, jobs 1..7 = W^T ============
struct AllConv {
  const float* src[8];
  unsigned short* dh[8];
  unsigned short* dl[8];
  int K[8], Mm[8], Kp[8], tot[8];
};
__global__ void k_convall(AllConv a){
  int j = blockIdx.y;
  int idx = blockIdx.x*blockDim.x + threadIdx.x;
  if (idx >= a.tot[j]) return;
  float v;
  if (j == 0){
    int n = idx >> 6, c = idx & 63;
    v = (c < 36) ? a.src[0][n*36 + c] : 0.f;
  } else {
    int Kp = a.Kp[j], K = a.K[j], M = a.Mm[j];
    int kk = idx % Kp, m = idx / Kp;
    v = (kk < K) ? a.src[j][(size_t)kk*M + m] : 0.f;
  }
  unsigned short h, l; split2(v, h, l);
  a.dh[j][idx] = h; a.dl[j][idx] = l;
}

// ===== GEMM: C[N,M] = (Ah+Al)[N,Kp] @ (Bh+Bl)^T, bf16x3, m97-style =====
// 64x128 tile, 4 waves x (4m x 2n), global_load_lds staging, chunk swizzle.
// mode 0: plain fp32 -> C
// mode 1: GCN epilogue: relu(acc + bias) -> hi/lo bf16
// mode 2: fp32 -> C + fused per-head alpha dots -> as_o/ad_o
// mode 3: pooling head: atomicAdd(apre, tanh(acc+bias).w2) ; no C store (b2 dropped:
//         softmax is shift-invariant)
#define GBM 64
#define GBN 128
#define GBK 32
__global__ __launch_bounds__(256) void k_gemm_bf3(
    const unsigned short* __restrict__ Ah, const unsigned short* __restrict__ Al,
    const unsigned short* __restrict__ Bh, const unsigned short* __restrict__ Bl,
    float* __restrict__ C, int N, int Kp, int M, int mode,
    const float* __restrict__ bias, unsigned short* __restrict__ outH,
    unsigned short* __restrict__ outL,
    const float* __restrict__ a_s, const float* __restrict__ a_d,
    float* __restrict__ as_o, float* __restrict__ ad_o, int Cdim){
  __shared__ unsigned short AsH[GBM*GBK], AsL[GBM*GBK];
  __shared__ unsigned short BsH[GBN*GBK], BsL[GBN*GBK];
  __shared__ float sred[2][GBM][4];
  int gx = M / GBN;
  int gy = (N + GBM - 1) / GBM;
  const int G = 8;
  int bid = blockIdx.x;
  int full = gy / G;
  int bid_full = full * G * gx;
  int by, bx;
  if (bid < bid_full){
    int g = bid / (G*gx); int rem = bid % (G*gx);
    by = g*G + rem % G; bx = rem / G;
  } else {
    int rem = bid - bid_full; int rows = gy - full*G;
    by = full*G + rem % rows; bx = rem / rows;
  }
  int row0 = by * GBM, col0 = bx * GBN;
  int t = threadIdx.x;
  int w = t >> 6, L = t & 63;
  int lm = L & 15, lq = L >> 4;
  int wc = w * 32;

  int sr = L >> 2, sc = L & 3;
  int art = w*16 + sr;
  int ga  = (sc - ((art >> 1) & 3)) & 3;
  int agrow = min(row0 + art, N-1);
  int brt0 = w*16 + sr;
  int brt1 = (w+4)*16 + sr;
  int gb0 = (sc - ((brt0 >> 1) & 3)) & 3;
  int gb1 = (sc - ((brt1 >> 1) & 3)) & 3;
  int bgrow0 = col0 + brt0, bgrow1 = col0 + brt1;

  int rc = (lq + (lm >> 1)) & 3;
  int aoff[4], boff[2];
#pragma unroll
  for (int mi = 0; mi < 4; mi++) aoff[mi] = (mi*16 + lm)*32 + rc*8;
#pragma unroll
  for (int ni = 0; ni < 2; ni++) boff[ni] = (wc + ni*16 + lm)*32 + rc*8;

  f32x4 acc[4][2];
#pragma unroll
  for (int i = 0; i < 4; i++)
#pragma unroll
    for (int j = 0; j < 2; j++) acc[i][j] = (f32x4){0.f,0.f,0.f,0.f};

  int nk = Kp / GBK;
  for (int kt = 0; kt < nk; kt++){
    int k0 = kt * GBK;
    if (kt) __syncthreads();
    gl_lds16(&Ah[(size_t)agrow*Kp + k0 + ga*8],  &AsH[w*512]);
    gl_lds16(&Al[(size_t)agrow*Kp + k0 + ga*8],  &AsL[w*512]);
    gl_lds16(&Bh[(size_t)bgrow0*Kp + k0 + gb0*8], &BsH[w*512]);
    gl_lds16(&Bh[(size_t)bgrow1*Kp + k0 + gb1*8], &BsH[(w+4)*512]);
    gl_lds16(&Bl[(size_t)bgrow0*Kp + k0 + gb0*8], &BsL[w*512]);
    gl_lds16(&Bl[(size_t)bgrow1*Kp + k0 + gb1*8], &BsL[(w+4)*512]);
    __syncthreads();

    short8 ah[4], al[4], bh[2], bl[2];
#pragma unroll
    for (int mi = 0; mi < 4; mi++){
      ah[mi] = *(const short8*)&AsH[aoff[mi]];
      al[mi] = *(const short8*)&AsL[aoff[mi]];
    }
#pragma unroll
    for (int ni = 0; ni < 2; ni++){
      bh[ni] = *(const short8*)&BsH[boff[ni]];
      bl[ni] = *(const short8*)&BsL[boff[ni]];
    }
#pragma unroll
    for (int mi = 0; mi < 4; mi++)
#pragma unroll
      for (int ni = 0; ni < 2; ni++){
        acc[mi][ni] = __builtin_amdgcn_mfma_f32_16x16x32_bf16(ah[mi], bh[ni], acc[mi][ni], 0, 0, 0);
        acc[mi][ni] = __builtin_amdgcn_mfma_f32_16x16x32_bf16(ah[mi], bl[ni], acc[mi][ni], 0, 0, 0);
        acc[mi][ni] = __builtin_amdgcn_mfma_f32_16x16x32_bf16(al[mi], bh[ni], acc[mi][ni], 0, 0, 0);
      }
  }
  // ---- epilogue; C/D layout col=lane&15, row=(lane>>4)*4+reg ----
  if (mode == 1){
#pragma unroll
    for (int mi = 0; mi < 4; mi++)
#pragma unroll
      for (int ni = 0; ni < 2; ni++){
#pragma unroll
        for (int r = 0; r < 4; r++){
          int row = row0 + mi*16 + lq*4 + r;
          int col = col0 + wc + ni*16 + lm;
          if (row < N){
            float v = fmaxf(acc[mi][ni][r] + bias[col], 0.f);
            unsigned short hh, ll; split2(v, hh, ll);
            outH[(size_t)row*M + col] = hh;
            outL[(size_t)row*M + col] = ll;
          }
        }
      }
  } else if (mode != 3){
#pragma unroll
    for (int mi = 0; mi < 4; mi++)
#pragma unroll
      for (int ni = 0; ni < 2; ni++){
#pragma unroll
        for (int r = 0; r < 4; r++){
          int row = row0 + mi*16 + lq*4 + r;
          int col = col0 + wc + ni*16 + lm;
          if (row < N) C[(size_t)row*M + col] = acc[mi][ni][r];
        }
      }
  }
  if (mode == 2){
    // fused alpha dots: wave covers 32 cols, always within one head (Cdim>=32)
    float sA0 = a_s[col0 + wc + lm], sA1 = a_s[col0 + wc + 16 + lm];
    float dA0 = a_d[col0 + wc + lm], dA1 = a_d[col0 + wc + 16 + lm];
#pragma unroll
    for (int mi = 0; mi < 4; mi++)
#pragma unroll
      for (int r = 0; r < 4; r++){
        float vs = acc[mi][0][r]*sA0 + acc[mi][1][r]*sA1;
        float vd = acc[mi][0][r]*dA0 + acc[mi][1][r]*dA1;
#pragma unroll
        for (int o = 1; o <= 8; o <<= 1){
          vs += __shfl_xor(vs, o);
          vd += __shfl_xor(vd, o);
        }
        if (lm == 0){
          int row = mi*16 + lq*4 + r;
          sred[0][row][w] = vs;
          sred[1][row][w] = vd;
        }
      }
    __syncthreads();
    if (t < GBM){
      int n = row0 + t;
      if (n < N){
        int wph = Cdim >> 5;
        int nheads = 4 / wph;
        for (int g = 0; g < nheads; g++){
          float ss = 0.f, dd = 0.f;
          for (int q = 0; q < wph; q++){
            ss += sred[0][t][g*wph + q];
            dd += sred[1][t][g*wph + q];
          }
          int hd = (col0 + g*wph*32) / Cdim;
          as_o[n*NH + hd] = ss;
          ad_o[n*NH + hd] = dd;
        }
      }
    }
  } else if (mode == 3){
    // pooling head: apre[row] += sum_cols tanh(acc + b1[col]) * w2[col]
    float b0 = bias[col0 + wc + lm], b1v = bias[col0 + wc + 16 + lm];
    float w0v = a_s[col0 + wc + lm], w1v = a_s[col0 + wc + 16 + lm];
#pragma unroll
    for (int mi = 0; mi < 4; mi++)
#pragma unroll
      for (int r = 0; r < 4; r++){
        float v = tanhf(acc[mi][0][r] + b0)*w0v + tanhf(acc[mi][1][r] + b1v)*w1v;
#pragma unroll
        for (int o = 1; o <= 8; o <<= 1) v += __shfl_xor(v, o);
        if (lm == 0) sred[0][mi*16 + lq*4 + r][w] = v;
      }
    __syncthreads();
    if (t < GBM){
      int n = row0 + t;
      if (n < N){
        float s = sred[0][t][0] + sred[0][t][1] + sred[0][t][2] + sred[0][t][3];
        atomicAdd(&as_o[n], s);
      }
    }
  }
}

// ===== GCN pre-aggregation: aggregate X at input dim (A(XW) = (AX)W) =====
__global__ __launch_bounds__(256) void k_gcn_pre(
    const unsigned short* __restrict__ inH, const unsigned short* __restrict__ inL,
    const float* __restrict__ dinv,
    const int* __restrict__ rowptr, const int* __restrict__ colidx,
    unsigned short* __restrict__ outH, unsigned short* __restrict__ outL,
    int Kp, int nchunk){
  int bid = blockIdx.x;
  int chunk = bid % nchunk, grp = bid / nchunk;
  int t = threadIdx.x;
  int sub = t & 15;
  int n = grp*16 + (t >> 4);
  if (n >= NN) return;
  int f0 = chunk*64 + sub*4;
  int b = rowptr[n], e = rowptr[n+1];
  float dn = dinv[n];
  float4 a0 = make_float4(0,0,0,0), a1 = make_float4(0,0,0,0);
  float4 a2 = make_float4(0,0,0,0), a3 = make_float4(0,0,0,0);
  int j = b;
  for (; j + 3 < e; j += 4){
    int s0 = colidx[j], s1 = colidx[j+1], s2 = colidx[j+2], s3 = colidx[j+3];
    float w0 = dinv[s0], w1 = dinv[s1], w2 = dinv[s2], w3 = dinv[s3];
    float4 v0 = load_hl(inH, inL, (size_t)s0*Kp + f0);
    float4 v1 = load_hl(inH, inL, (size_t)s1*Kp + f0);
    float4 v2 = load_hl(inH, inL, (size_t)s2*Kp + f0);
    float4 v3 = load_hl(inH, inL, (size_t)s3*Kp + f0);
    fma4(a0, v0, w0*dn); fma4(a1, v1, w1*dn);
    fma4(a2, v2, w2*dn); fma4(a3, v3, w3*dn);
  }
  for (; j < e; j++){
    int s = colidx[j];
    float4 v = load_hl(inH, inL, (size_t)s*Kp + f0);
    fma4(a0, v, dinv[s]*dn);
  }
  float4 acc = make_float4(a0.x+a1.x+a2.x+a3.x, a0.y+a1.y+a2.y+a3.y,
                           a0.z+a1.z+a2.z+a3.z, a0.w+a1.w+a2.w+a3.w);
  float4 sv = load_hl(inH, inL, (size_t)n*Kp + f0);
  float dn2 = dn*dn;
  acc.x += sv.x*dn2; acc.y += sv.y*dn2; acc.z += sv.z*dn2; acc.w += sv.w*dn2;
  store_hl(outH, outL, (size_t)n*Kp + f0, acc);
}

// ===== GAT maxden: single pass, online softmax (logits cached in ealpha) =====
__global__ void k_gat_maxden(const int* __restrict__ rowptr, const int* __restrict__ colidx,
                             const float* __restrict__ as_, const float* __restrict__ ad_,
                             float* __restrict__ eself, float* __restrict__ den,
                             float* __restrict__ mmax, float* __restrict__ ealpha){
  int idx = blockIdx.x*blockDim.x + threadIdx.x;
  if (idx >= NN*NH) return;
  int n = idx >> 2, hd = idx & 3;
  float adn = ad_[idx];
  float selflog = leakyf(as_[idx] + adn);
  int b = rowptr[n], e = rowptr[n+1];
  float m = selflog, d = 1.f;          // self term: exp(selflog - m) = 1
  int j = b;
  for (; j + 3 < e; j += 4){
    int s0 = colidx[j], s1 = colidx[j+1], s2 = colidx[j+2], s3 = colidx[j+3];
    float l0 = leakyf(as_[s0*NH + hd] + adn), l1 = leakyf(as_[s1*NH + hd] + adn);
    float l2 = leakyf(as_[s2*NH + hd] + adn), l3 = leakyf(as_[s3*NH + hd] + adn);
    ealpha[(size_t)(j+0)*NH + hd] = l0; ealpha[(size_t)(j+1)*NH + hd] = l1;
    ealpha[(size_t)(j+2)*NH + hd] = l2; ealpha[(size_t)(j+3)*NH + hd] = l3;
    float m4 = fmaxf(fmaxf(l0, l1), fmaxf(l2, l3));
    if (m4 > m){ d *= expf(m - m4); m = m4; }
    d += expf(l0 - m) + expf(l1 - m) + expf(l2 - m) + expf(l3 - m);
  }
  for (; j < e; j++){
    float l = leakyf(as_[colidx[j]*NH + hd] + adn);
    ealpha[(size_t)j*NH + hd] = l;
    if (l > m){ d *= expf(m - l); m = l; }
    d += expf(l - m);
  }
  eself[idx] = expf(selflog - m);
  den[idx] = d;
  mmax[idx] = m;
}
// ===== GAT gather: feature-chunked, XCD-aligned, 4-way unrolled; exp inline =====
__global__ __launch_bounds__(256) void k_gat_gather(
    const float* __restrict__ hg,
    const unsigned short* __restrict__ inH, const unsigned short* __restrict__ inL,
    const int* __restrict__ rowptr, const int* __restrict__ colidx,
    const float* __restrict__ ealpha, const float* __restrict__ eself,
    const float* __restrict__ den, const float* __restrict__ mmax,
    const float* __restrict__ ab,
    unsigned short* __restrict__ outH, unsigned short* __restrict__ outL,
    int M, int C, int nchunk){
  int bid = blockIdx.x;
  int chunk = bid % nchunk, grp = bid / nchunk;
  int t = threadIdx.x;
  int sub = t & 15;
  int n = grp*16 + (t >> 4);
  if (n >= NN) return;
  int f0 = chunk*64 + sub*4;
  int hd = f0 / C;
  int b = rowptr[n], e = rowptr[n+1];
  int ai = n*NH + hd;
  float mm = mmax[ai];
  float4 a0 = make_float4(0,0,0,0), a1 = make_float4(0,0,0,0);
  float4 a2 = make_float4(0,0,0,0), a3 = make_float4(0,0,0,0);
  int j = b;
  for (; j + 3 < e; j += 4){
    int s0 = colidx[j], s1 = colidx[j+1], s2 = colidx[j+2], s3 = colidx[j+3];
    float e0 = expf(ealpha[(size_t)(j+0)*NH + hd] - mm);
    float e1 = expf(ealpha[(size_t)(j+1)*NH + hd] - mm);
    float e2 = expf(ealpha[(size_t)(j+2)*NH + hd] - mm);
    float e3 = expf(ealpha[(size_t)(j+3)*NH + hd] - mm);
    float4 v0 = *(const float4*)&hg[(size_t)s0*M + f0];
    float4 v1 = *(const float4*)&hg[(size_t)s1*M + f0];
    float4 v2 = *(const float4*)&hg[(size_t)s2*M + f0];
    float4 v3 = *(const float4*)&hg[(size_t)s3*M + f0];
    fma4(a0, v0, e0); fma4(a1, v1, e1);
    fma4(a2, v2, e2); fma4(a3, v3, e3);
  }
  for (; j < e; j++){
    int s = colidx[j];
    float4 v = *(const float4*)&hg[(size_t)s*M + f0];
    fma4(a0, v, expf(ealpha[(size_t)j*NH + hd] - mm));
  }
  float4 acc = make_float4(a0.x+a1.x+a2.x+a3.x, a0.y+a1.y+a2.y+a3.y,
                           a0.z+a1.z+a2.z+a3.z, a0.w+a1.w+a2.w+a3.w);
  float es = eself[ai], inv = 1.f/den[ai];
  float4 sv = *(const float4*)&hg[(size_t)n*M + f0];
  float4 hv = load_hl(inH, inL, (size_t)n*M + f0);
  float4 bb = *(const float4*)&ab[f0];
  float4 r = make_float4(
    hv.x + bb.x + (sv.x*es + acc.x)*inv,
    hv.y + bb.y + (sv.y*es + acc.y)*inv,
    hv.z + bb.z + (sv.z*es + acc.z)*inv,
    hv.w + bb.w + (sv.w*es + acc.w)*inv);
  store_hl(outH, outL, (size_t)n*M + f0, r);
}

// ================= attention pooling (fused prep + gather) =================
__global__ void k_pool(const unsigned short* __restrict__ xH, const unsigned short* __restrict__ xL,
                       const float* __restrict__ apre, const int* __restrict__ starts,
                       float* __restrict__ out){
  __shared__ float red[128];
  int g = blockIdx.x, t = threadIdx.x;   // 128 threads
  int b = starts[g], e = starts[g+1];
  // per-graph softmax stats (global softmax denominator cancels in renorm)
  float m = -INFINITY;
  for (int n = b + t; n < e; n += 128) m = fmaxf(m, apre[n]);
  red[t] = m; __syncthreads();
  for (int o = 64; o > 0; o >>= 1){
    if (t < o) red[t] = fmaxf(red[t], red[t + o]);
    __syncthreads();
  }
  m = red[0]; __syncthreads();
  float s = 0.f;
  for (int n = b + t; n < e; n += 128) s += expf(apre[n] - m);
  red[t] = s; __syncthreads();
  for (int o = 64; o > 0; o >>= 1){
    if (t < o) red[t] += red[t + o];
    __syncthreads();
  }
  float inv = 1.f / (red[0] + 1e-8f);
  float4 sum = make_float4(0,0,0,0), wacc = make_float4(0,0,0,0);
  float4 mx = make_float4(-INFINITY,-INFINITY,-INFINITY,-INFINITY);
  for (int n = b; n < e; n++){
    float4 xv = load_hl(xH, xL, (size_t)n*DOUT + t*4);
    float p = expf(apre[n] - m) * inv;
    sum.x += xv.x; sum.y += xv.y; sum.z += xv.z; sum.w += xv.w;
    mx.x = fmaxf(mx.x, xv.x); mx.y = fmaxf(mx.y, xv.y);
    mx.z = fmaxf(mx.z, xv.z); mx.w = fmaxf(mx.w, xv.w);
    fma4(wacc, xv, p);
  }
  float ic = 1.f / fmaxf((float)(e - b), 1.f);
  float4* o = (float4*)(out + (size_t)g*4*DOUT);
  o[t]       = wacc;
  o[128 + t] = make_float4(sum.x*ic, sum.y*ic, sum.z*ic, sum.w*ic);
  o[256 + t] = mx;
  o[384 + t] = sum;
}

extern "C" void kernel_launch(void* const* d_in, const int* in_sizes, int n_in,
                              void* d_out, int out_size, void* d_ws, size_t ws_size,
                              hipStream_t stream) {
  const float* x0   = (const float*)d_in[0];
  const int*   ei   = (const int*)d_in[1];
  const int*   src  = ei;
  const int*   dst  = ei + NE;
  const int*   batch= (const int*)d_in[2];
  const float* gw[3]  = {(const float*)d_in[3],  (const float*)d_in[9],  (const float*)d_in[15]};
  const float* gb[3]  = {(const float*)d_in[4],  (const float*)d_in[10], (const float*)d_in[16]};
  const float* aw[3]  = {(const float*)d_in[5],  (const float*)d_in[11], (const float*)d_in[17]};
  const float* asw[3] = {(const float*)d_in[6],  (const float*)d_in[12], (const float*)d_in[18]};
  const float* adw[3] = {(const float*)d_in[7],  (const float*)d_in[13], (const float*)d_in[19]};
  const float* ab[3]  = {(const float*)d_in[8],  (const float*)d_in[14], (const float*)d_in[20]};
  const float* apw1 = (const float*)d_in[21];
  const float* apb1 = (const float*)d_in[22];
  const float* apw2 = (const float*)d_in[23];
  float* out = (float*)d_out;

  // ---- workspace carve ----
  char* p = (char*)d_ws;
  auto alloc = [&](size_t bytes) -> void* {
    void* r = (void*)p; p += (bytes + 255) & ~(size_t)255; return r;
  };
  float* f1 = (float*)alloc((size_t)NN*512*4);
  unsigned short* actH0 = (unsigned short*)alloc((size_t)NN*512*2);   // h (GCN out)
  unsigned short* actL0 = (unsigned short*)alloc((size_t)NN*512*2);
  unsigned short* actH1 = (unsigned short*)alloc((size_t)NN*512*2);   // x (layer out)
  unsigned short* actL1 = (unsigned short*)alloc((size_t)NN*512*2);
  unsigned short* preH  = (unsigned short*)alloc((size_t)NN*256*2);   // aggregated X
  unsigned short* preL  = (unsigned short*)alloc((size_t)NN*256*2);
  unsigned short* x0h = (unsigned short*)alloc((size_t)NN*64*2);
  unsigned short* x0l = (unsigned short*)alloc((size_t)NN*64*2);
  const int wK[7]  = {36, 128, 128, 256, 256, 512, 512};
  const int wM[7]  = {128, 128, 256, 256, 512, 512, 256};
  const int wKp[7] = {64, 128, 128, 256, 256, 512, 512};
  const float* wsrc[7] = {gw[0], aw[0], gw[1], aw[1], gw[2], aw[2], apw1};
  unsigned short* wTh[7]; unsigned short* wTl[7];
  for (int i = 0; i < 7; i++){
    size_t sz = (size_t)wM[i]*wKp[i]*2;
    wTh[i] = (unsigned short*)alloc(sz);
    wTl[i] = (unsigned short*)alloc(sz);
  }
  float* ealpha = (float*)alloc((size_t)NE*NH*4);
  float* dinv = (float*)alloc(NN*4);
  float* as_  = (float*)alloc(NN*NH*4);
  float* ad_  = (float*)alloc(NN*NH*4);
  float* eself= (float*)alloc(NN*NH*4);
  float* den  = (float*)alloc(NN*NH*4);
  float* mmax = (float*)alloc(NN*NH*4);
  float* apre = (float*)alloc(NN*4);
  int* rowptr = (int*)alloc((NN+1)*4);
  int* colidx = (int*)alloc((size_t)NE*4);
  int* cnt    = (int*)alloc(NN*4);
  int* cursor = (int*)alloc(NN*4);
  int* starts = (int*)alloc((NB+1)*4);

  // ---- CSR build + degrees + starts (fused) ----
  hipMemsetAsync(cnt, 0, NN*sizeof(int), stream);
  k_count<<<(NE+255)/256, 256, 0, stream>>>(dst, cnt);
  k_scan<<<1, 256, 0, stream>>>(cnt, rowptr, dinv, cursor, batch, starts);
  k_fill<<<(NE+255)/256, 256, 0, stream>>>(src, dst, rowptr, cursor, colidx);

  // ---- fused conversions ----
  AllConv ac;
  ac.src[0] = x0; ac.dh[0] = x0h; ac.dl[0] = x0l;
  ac.K[0] = 36; ac.Mm[0] = NN; ac.Kp[0] = 64; ac.tot[0] = NN*64;
  int maxtot = NN*64;
  for (int i = 0; i < 7; i++){
    ac.src[i+1] = wsrc[i]; ac.dh[i+1] = wTh[i]; ac.dl[i+1] = wTl[i];
    ac.K[i+1] = wK[i]; ac.Mm[i+1] = wM[i]; ac.Kp[i+1] = wKp[i];
    ac.tot[i+1] = wKp[i]*wM[i];
    if (ac.tot[i+1] > maxtot) maxtot = ac.tot[i+1];
  }
  k_convall<<<dim3((maxtot+255)/256, 8), 256, 0, stream>>>(ac);

  const int dims[4] = {36, 128, 256, 512};
  const int ngrp = (NN + 15) / 16;
  const unsigned short* curH = x0h; const unsigned short* curL = x0l;
  int wi = 0;
  for (int i = 0; i < 3; i++){
    int Kin = (i == 0) ? 64 : dims[i];
    int M = dims[i+1], C = M/NH;
    int nchunk_in = Kin / 64;
    int nchunk = M / 64;
    int nblk = (M/GBN) * ((NN+GBM-1)/GBM);
    // GCN: aggregate X at input dim, then GEMM with fused bias+relu+split epilogue
    k_gcn_pre<<<nchunk_in*ngrp, 256, 0, stream>>>(curH, curL, dinv, rowptr, colidx,
                                                  preH, preL, Kin, nchunk_in);
    k_gemm_bf3<<<nblk, 256, 0, stream>>>(preH, preL, wTh[wi], wTl[wi], f1, NN, wKp[wi], M,
                                         1, gb[i], actH0, actL0,
                                         nullptr, nullptr, nullptr, nullptr, C);
    wi++;
    // GAT: GEMM with fused alpha-dot epilogue
    k_gemm_bf3<<<nblk, 256, 0, stream>>>(actH0, actL0, wTh[wi], wTl[wi], f1, NN, wKp[wi], M,
                                         2, nullptr, nullptr, nullptr,
                                         asw[i], adw[i], as_, ad_, C);
    wi++;
    k_gat_maxden<<<(NN*NH+255)/256, 256, 0, stream>>>(rowptr, colidx, as_, ad_,
                                                      eself, den, mmax, ealpha);
    k_gat_gather<<<nchunk*ngrp, 256, 0, stream>>>(f1, actH0, actL0, rowptr, colidx,
                                                  ealpha, eself, den, mmax, ab[i],
                                                  actH1, actL1, M, C, nchunk);
    curH = actH1; curL = actL1;
  }

  // ---- pooling: GEMM with fused tanh-dot epilogue -> apre, then fused pool ----
  hipMemsetAsync(apre, 0, NN*sizeof(float), stream);
  {
    int nblk = (256/GBN) * ((NN+GBM-1)/GBM);
    k_gemm_bf3<<<nblk, 256, 0, stream>>>(actH1, actL1, wTh[6], wTl[6], f1, NN, wKp[6], 256,
                                         3, apb1, nullptr, nullptr,
                                         apw2, nullptr, apre, nullptr, 64);
  }
  k_pool<<<NB, 128, 0, stream>>>(actH1, actL1, apre, starts, out);
}

// Round 12
// 441.501 us; speedup vs baseline: 5.2301x; 1.0327x over previous
//
#include <hip/hip_runtime.h>
#include <math.h>

#define NN 10000
#define NE 160000
#define NB 128
#define NH 4
#define DOUT 512
#define NEG 0.2f

typedef __attribute__((ext_vector_type(8))) short short8;
typedef __attribute__((ext_vector_type(4))) float f32x4;
typedef __attribute__((ext_vector_type(4))) unsigned short us4;

__device__ __forceinline__ float leakyf(float v){ return v > 0.f ? v : NEG*v; }
__device__ __forceinline__ void fma4(float4& a, const float4 v, float w){
  a.x += v.x*w; a.y += v.y*w; a.z += v.z*w; a.w += v.w*w;
}
__device__ __forceinline__ void mul4(float4& a, float s){
  a.x *= s; a.y *= s; a.z *= s; a.w *= s;
}
__device__ __forceinline__ unsigned short f2bf(float f){
  unsigned int u = __float_as_uint(f);
  u += 0x7FFFu + ((u >> 16) & 1u);
  return (unsigned short)(u >> 16);
}
__device__ __forceinline__ float bf2f(unsigned short h){
  return __uint_as_float(((unsigned int)h) << 16);
}
__device__ __forceinline__ void split2(float v, unsigned short& h, unsigned short& l){
  h = f2bf(v);
  l = f2bf(v - bf2f(h));
}
__device__ __forceinline__ void store_hl(unsigned short* H, unsigned short* L,
                                         size_t base, float4 v){
  us4 h, l; unsigned short hh, ll;
  split2(v.x, hh, ll); h[0]=hh; l[0]=ll;
  split2(v.y, hh, ll); h[1]=hh; l[1]=ll;
  split2(v.z, hh, ll); h[2]=hh; l[2]=ll;
  split2(v.w, hh, ll); h[3]=hh; l[3]=ll;
  *(us4*)&H[base] = h;
  *(us4*)&L[base] = l;
}
__device__ __forceinline__ float4 load_hl(const unsigned short* __restrict__ H,
                                          const unsigned short* __restrict__ L, size_t base){
  us4 h = *(const us4*)&H[base];
  us4 l = *(const us4*)&L[base];
  return make_float4(bf2f(h[0])+bf2f(l[0]), bf2f(h[1])+bf2f(l[1]),
                     bf2f(h[2])+bf2f(l[2]), bf2f(h[3])+bf2f(l[3]));
}
__device__ __forceinline__ void gl_lds16(const unsigned short* g, unsigned short* l){
  __builtin_amdgcn_global_load_lds(
      (const __attribute__((address_space(1))) unsigned int*)g,
      (__attribute__((address_space(3))) unsigned int*)l, 16, 0, 0);
}

// ================= CSR build =================
__global__ void k_count(const int* __restrict__ dst, int* __restrict__ cnt){
  int e = blockIdx.x*blockDim.x + threadIdx.x;
  if (e < NE) atomicAdd(&cnt[dst[e]], 1);
}
// scan + dinv + cursor-zero + apre-zero + segment starts
__global__ void k_scan(const int* __restrict__ cnt, int* __restrict__ rowptr,
                       float* __restrict__ dinv, int* __restrict__ cursor,
                       const int* __restrict__ batch, int* __restrict__ starts,
                       float* __restrict__ apre){
  __shared__ int part[256];
  const int CH = (NN + 255) / 256;
  int t = threadIdx.x;
  int base = t * CH;
  int s = 0;
  for (int i = 0; i < CH; i++){ int idx = base + i; if (idx < NN) s += cnt[idx]; }
  part[t] = s; __syncthreads();
  for (int o = 1; o < 256; o <<= 1){
    int v = 0;
    if (t >= o) v = part[t - o];
    __syncthreads();
    if (t >= o) part[t] += v;
    __syncthreads();
  }
  int pre = (t == 0) ? 0 : part[t - 1];
  for (int i = 0; i < CH; i++){
    int idx = base + i;
    if (idx < NN){
      int c = cnt[idx];
      rowptr[idx] = pre; pre += c;
      dinv[idx] = rsqrtf((float)c + 1.f);
      cursor[idx] = 0;
      apre[idx] = 0.f;
    }
  }
  if (t == 255) rowptr[NN] = part[255];
  if (t <= NB){
    int lo = 0, hi = NN;
    while (lo < hi){ int mid = (lo + hi) >> 1; if (batch[mid] < t) lo = mid + 1; else hi = mid; }
    starts[t] = lo;
  }
}
__global__ void k_fill(const int* __restrict__ src, const int* __restrict__ dst,
                       const int* __restrict__ rowptr, int* __restrict__ cursor,
                       int* __restrict__ colidx){
  int e = blockIdx.x*blockDim.x + threadIdx.x;
  if (e >= NE) return;
  int d = dst[e];
  int pos = atomicAdd(&cursor[d], 1);
  colidx[rowptr[d] + pos] = src[e];
}

// ============ fused conversions: job 0 = x0 pad-convert, jobs 1..7 = W^T ============
struct AllConv {
  const float* src[8];
  unsigned short* dh[8];
  unsigned short* dl[8];
  int K[8], Mm[8], Kp[8], tot[8];
};
__global__ void k_convall(AllConv a){
  int j = blockIdx.y;
  int idx = blockIdx.x*blockDim.x + threadIdx.x;
  if (idx >= a.tot[j]) return;
  float v;
  if (j == 0){
    int n = idx >> 6, c = idx & 63;
    v = (c < 36) ? a.src[0][n*36 + c] : 0.f;
  } else {
    int Kp = a.Kp[j], K = a.K[j], M = a.Mm[j];
    int kk = idx % Kp, m = idx / Kp;
    v = (kk < K) ? a.src[j][(size_t)kk*M + m] : 0.f;
  }
  unsigned short h, l; split2(v, h, l);
  a.dh[j][idx] = h; a.dl[j][idx] = l;
}

// ===== GEMM: C[N,M] = (Ah+Al)[N,Kp] @ (Bh+Bl)^T, bf16x3, m97-style =====
// 64x128 tile, 4 waves x (4m x 2n), global_load_lds staging, chunk swizzle.
// mode 0: plain fp32 -> C
// mode 1: GCN epilogue: relu(acc + bias) -> hi/lo bf16
// mode 2: fp32 -> C + fused per-head alpha dots -> as_o/ad_o
// mode 3: pooling head: atomicAdd(apre, tanh(acc+bias).w2); no C store
#define GBM 64
#define GBN 128
#define GBK 32
__global__ __launch_bounds__(256) void k_gemm_bf3(
    const unsigned short* __restrict__ Ah, const unsigned short* __restrict__ Al,
    const unsigned short* __restrict__ Bh, const unsigned short* __restrict__ Bl,
    float* __restrict__ C, int N, int Kp, int M, int mode,
    const float* __restrict__ bias, unsigned short* __restrict__ outH,
    unsigned short* __restrict__ outL,
    const float* __restrict__ a_s, const float* __restrict__ a_d,
    float* __restrict__ as_o, float* __restrict__ ad_o, int Cdim){
  __shared__ unsigned short AsH[GBM*GBK], AsL[GBM*GBK];
  __shared__ unsigned short BsH[GBN*GBK], BsL[GBN*GBK];
  __shared__ float sred[2][GBM][4];
  int gx = M / GBN;
  int gy = (N + GBM - 1) / GBM;
  const int G = 8;
  int bid = blockIdx.x;
  int full = gy / G;
  int bid_full = full * G * gx;
  int by, bx;
  if (bid < bid_full){
    int g = bid / (G*gx); int rem = bid % (G*gx);
    by = g*G + rem % G; bx = rem / G;
  } else {
    int rem = bid - bid_full; int rows = gy - full*G;
    by = full*G + rem % rows; bx = rem / rows;
  }
  int row0 = by * GBM, col0 = bx * GBN;
  int t = threadIdx.x;
  int w = t >> 6, L = t & 63;
  int lm = L & 15, lq = L >> 4;
  int wc = w * 32;

  int sr = L >> 2, sc = L & 3;
  int art = w*16 + sr;
  int ga  = (sc - ((art >> 1) & 3)) & 3;
  int agrow = min(row0 + art, N-1);
  int brt0 = w*16 + sr;
  int brt1 = (w+4)*16 + sr;
  int gb0 = (sc - ((brt0 >> 1) & 3)) & 3;
  int gb1 = (sc - ((brt1 >> 1) & 3)) & 3;
  int bgrow0 = col0 + brt0, bgrow1 = col0 + brt1;

  int rc = (lq + (lm >> 1)) & 3;
  int aoff[4], boff[2];
#pragma unroll
  for (int mi = 0; mi < 4; mi++) aoff[mi] = (mi*16 + lm)*32 + rc*8;
#pragma unroll
  for (int ni = 0; ni < 2; ni++) boff[ni] = (wc + ni*16 + lm)*32 + rc*8;

  f32x4 acc[4][2];
#pragma unroll
  for (int i = 0; i < 4; i++)
#pragma unroll
    for (int j = 0; j < 2; j++) acc[i][j] = (f32x4){0.f,0.f,0.f,0.f};

  int nk = Kp / GBK;
  for (int kt = 0; kt < nk; kt++){
    int k0 = kt * GBK;
    if (kt) __syncthreads();
    gl_lds16(&Ah[(size_t)agrow*Kp + k0 + ga*8],  &AsH[w*512]);
    gl_lds16(&Al[(size_t)agrow*Kp + k0 + ga*8],  &AsL[w*512]);
    gl_lds16(&Bh[(size_t)bgrow0*Kp + k0 + gb0*8], &BsH[w*512]);
    gl_lds16(&Bh[(size_t)bgrow1*Kp + k0 + gb1*8], &BsH[(w+4)*512]);
    gl_lds16(&Bl[(size_t)bgrow0*Kp + k0 + gb0*8], &BsL[w*512]);
    gl_lds16(&Bl[(size_t)bgrow1*Kp + k0 + gb1*8], &BsL[(w+4)*512]);
    __syncthreads();

    short8 ah[4], al[4], bh[2], bl[2];
#pragma unroll
    for (int mi = 0; mi < 4; mi++){
      ah[mi] = *(const short8*)&AsH[aoff[mi]];
      al[mi] = *(const short8*)&AsL[aoff[mi]];
    }
#pragma unroll
    for (int ni = 0; ni < 2; ni++){
      bh[ni] = *(const short8*)&BsH[boff[ni]];
      bl[ni] = *(const short8*)&BsL[boff[ni]];
    }
#pragma unroll
    for (int mi = 0; mi < 4; mi++)
#pragma unroll
      for (int ni = 0; ni < 2; ni++){
        acc[mi][ni] = __builtin_amdgcn_mfma_f32_16x16x32_bf16(ah[mi], bh[ni], acc[mi][ni], 0, 0, 0);
        acc[mi][ni] = __builtin_amdgcn_mfma_f32_16x16x32_bf16(ah[mi], bl[ni], acc[mi][ni], 0, 0, 0);
        acc[mi][ni] = __builtin_amdgcn_mfma_f32_16x16x32_bf16(al[mi], bh[ni], acc[mi][ni], 0, 0, 0);
      }
  }
  // ---- epilogue; C/D layout col=lane&15, row=(lane>>4)*4+reg ----
  if (mode == 1){
#pragma unroll
    for (int mi = 0; mi < 4; mi++)
#pragma unroll
      for (int ni = 0; ni < 2; ni++){
#pragma unroll
        for (int r = 0; r < 4; r++){
          int row = row0 + mi*16 + lq*4 + r;
          int col = col0 + wc + ni*16 + lm;
          if (row < N){
            float v = fmaxf(acc[mi][ni][r] + bias[col], 0.f);
            unsigned short hh, ll; split2(v, hh, ll);
            outH[(size_t)row*M + col] = hh;
            outL[(size_t)row*M + col] = ll;
          }
        }
      }
  } else if (mode != 3){
#pragma unroll
    for (int mi = 0; mi < 4; mi++)
#pragma unroll
      for (int ni = 0; ni < 2; ni++){
#pragma unroll
        for (int r = 0; r < 4; r++){
          int row = row0 + mi*16 + lq*4 + r;
          int col = col0 + wc + ni*16 + lm;
          if (row < N) C[(size_t)row*M + col] = acc[mi][ni][r];
        }
      }
  }
  if (mode == 2){
    // fused alpha dots: wave covers 32 cols, always within one head (Cdim>=32)
    float sA0 = a_s[col0 + wc + lm], sA1 = a_s[col0 + wc + 16 + lm];
    float dA0 = a_d[col0 + wc + lm], dA1 = a_d[col0 + wc + 16 + lm];
#pragma unroll
    for (int mi = 0; mi < 4; mi++)
#pragma unroll
      for (int r = 0; r < 4; r++){
        float vs = acc[mi][0][r]*sA0 + acc[mi][1][r]*sA1;
        float vd = acc[mi][0][r]*dA0 + acc[mi][1][r]*dA1;
#pragma unroll
        for (int o = 1; o <= 8; o <<= 1){
          vs += __shfl_xor(vs, o);
          vd += __shfl_xor(vd, o);
        }
        if (lm == 0){
          int row = mi*16 + lq*4 + r;
          sred[0][row][w] = vs;
          sred[1][row][w] = vd;
        }
      }
    __syncthreads();
    if (t < GBM){
      int n = row0 + t;
      if (n < N){
        int wph = Cdim >> 5;
        int nheads = 4 / wph;
        for (int g = 0; g < nheads; g++){
          float ss = 0.f, dd = 0.f;
          for (int q = 0; q < wph; q++){
            ss += sred[0][t][g*wph + q];
            dd += sred[1][t][g*wph + q];
          }
          int hd = (col0 + g*wph*32) / Cdim;
          as_o[n*NH + hd] = ss;
          ad_o[n*NH + hd] = dd;
        }
      }
    }
  } else if (mode == 3){
    float b0 = bias[col0 + wc + lm], b1v = bias[col0 + wc + 16 + lm];
    float w0v = a_s[col0 + wc + lm], w1v = a_s[col0 + wc + 16 + lm];
#pragma unroll
    for (int mi = 0; mi < 4; mi++)
#pragma unroll
      for (int r = 0; r < 4; r++){
        float v = tanhf(acc[mi][0][r] + b0)*w0v + tanhf(acc[mi][1][r] + b1v)*w1v;
#pragma unroll
        for (int o = 1; o <= 8; o <<= 1) v += __shfl_xor(v, o);
        if (lm == 0) sred[0][mi*16 + lq*4 + r][w] = v;
      }
    __syncthreads();
    if (t < GBM){
      int n = row0 + t;
      if (n < N){
        float s = sred[0][t][0] + sred[0][t][1] + sred[0][t][2] + sred[0][t][3];
        atomicAdd(&as_o[n], s);
      }
    }
  }
}

// ===== GCN pre-aggregation: aggregate X at input dim (A(XW) = (AX)W) =====
__global__ __launch_bounds__(256) void k_gcn_pre(
    const unsigned short* __restrict__ inH, const unsigned short* __restrict__ inL,
    const float* __restrict__ dinv,
    const int* __restrict__ rowptr, const int* __restrict__ colidx,
    unsigned short* __restrict__ outH, unsigned short* __restrict__ outL,
    int Kp, int nchunk){
  int bid = blockIdx.x;
  int chunk = bid % nchunk, grp = bid / nchunk;
  int t = threadIdx.x;
  int sub = t & 15;
  int n = grp*16 + (t >> 4);
  if (n >= NN) return;
  int f0 = chunk*64 + sub*4;
  int b = rowptr[n], e = rowptr[n+1];
  float dn = dinv[n];
  float4 a0 = make_float4(0,0,0,0), a1 = make_float4(0,0,0,0);
  float4 a2 = make_float4(0,0,0,0), a3 = make_float4(0,0,0,0);
  int j = b;
  for (; j + 3 < e; j += 4){
    int s0 = colidx[j], s1 = colidx[j+1], s2 = colidx[j+2], s3 = colidx[j+3];
    float w0 = dinv[s0], w1 = dinv[s1], w2 = dinv[s2], w3 = dinv[s3];
    float4 v0 = load_hl(inH, inL, (size_t)s0*Kp + f0);
    float4 v1 = load_hl(inH, inL, (size_t)s1*Kp + f0);
    float4 v2 = load_hl(inH, inL, (size_t)s2*Kp + f0);
    float4 v3 = load_hl(inH, inL, (size_t)s3*Kp + f0);
    fma4(a0, v0, w0*dn); fma4(a1, v1, w1*dn);
    fma4(a2, v2, w2*dn); fma4(a3, v3, w3*dn);
  }
  for (; j < e; j++){
    int s = colidx[j];
    float4 v = load_hl(inH, inL, (size_t)s*Kp + f0);
    fma4(a0, v, dinv[s]*dn);
  }
  float4 acc = make_float4(a0.x+a1.x+a2.x+a3.x, a0.y+a1.y+a2.y+a3.y,
                           a0.z+a1.z+a2.z+a3.z, a0.w+a1.w+a2.w+a3.w);
  float4 sv = load_hl(inH, inL, (size_t)n*Kp + f0);
  float dn2 = dn*dn;
  acc.x += sv.x*dn2; acc.y += sv.y*dn2; acc.z += sv.z*dn2; acc.w += sv.w*dn2;
  store_hl(outH, outL, (size_t)n*Kp + f0, acc);
}

// ===== GAT gather: fused online-softmax (flash-style), feature-chunked,
//       XCD-aligned, 4-way edge-unrolled. No maxden pass, no ealpha array. =====
__global__ __launch_bounds__(256) void k_gat_gather(
    const float* __restrict__ hg,
    const unsigned short* __restrict__ inH, const unsigned short* __restrict__ inL,
    const int* __restrict__ rowptr, const int* __restrict__ colidx,
    const float* __restrict__ as_, const float* __restrict__ ad_,
    const float* __restrict__ ab,
    unsigned short* __restrict__ outH, unsigned short* __restrict__ outL,
    int M, int C, int nchunk){
  int bid = blockIdx.x;
  int chunk = bid % nchunk, grp = bid / nchunk;
  int t = threadIdx.x;
  int sub = t & 15;
  int n = grp*16 + (t >> 4);
  if (n >= NN) return;
  int f0 = chunk*64 + sub*4;
  int hd = f0 / C;
  int b = rowptr[n], e = rowptr[n+1];
  int ai = n*NH + hd;
  float adn = ad_[ai];
  float selflog = leakyf(as_[ai] + adn);
  // online softmax: state (m, d) starts at self term (d=1 == exp(selflog-m))
  float m = selflog, d = 1.f;
  float4 a0 = make_float4(0,0,0,0), a1 = make_float4(0,0,0,0);
  float4 a2 = make_float4(0,0,0,0), a3 = make_float4(0,0,0,0);
  int j = b;
  for (; j + 3 < e; j += 4){
    int s0 = colidx[j], s1 = colidx[j+1], s2 = colidx[j+2], s3 = colidx[j+3];
    float l0 = leakyf(as_[s0*NH + hd] + adn), l1 = leakyf(as_[s1*NH + hd] + adn);
    float l2 = leakyf(as_[s2*NH + hd] + adn), l3 = leakyf(as_[s3*NH + hd] + adn);
    float4 v0 = *(const float4*)&hg[(size_t)s0*M + f0];
    float4 v1 = *(const float4*)&hg[(size_t)s1*M + f0];
    float4 v2 = *(const float4*)&hg[(size_t)s2*M + f0];
    float4 v3 = *(const float4*)&hg[(size_t)s3*M + f0];
    float m4 = fmaxf(fmaxf(l0, l1), fmaxf(l2, l3));
    if (m4 > m){
      float sc = expf(m - m4);
      d *= sc; mul4(a0, sc); mul4(a1, sc); mul4(a2, sc); mul4(a3, sc);
      m = m4;
    }
    float w0 = expf(l0 - m), w1 = expf(l1 - m);
    float w2 = expf(l2 - m), w3 = expf(l3 - m);
    d += (w0 + w1) + (w2 + w3);
    fma4(a0, v0, w0); fma4(a1, v1, w1);
    fma4(a2, v2, w2); fma4(a3, v3, w3);
  }
  for (; j < e; j++){
    int s = colidx[j];
    float l = leakyf(as_[s*NH + hd] + adn);
    float4 v = *(const float4*)&hg[(size_t)s*M + f0];
    if (l > m){
      float sc = expf(m - l);
      d *= sc; mul4(a0, sc); mul4(a1, sc); mul4(a2, sc); mul4(a3, sc);
      m = l;
    }
    float ww = expf(l - m);
    d += ww;
    fma4(a0, v, ww);
  }
  float4 acc = make_float4(a0.x+a1.x+a2.x+a3.x, a0.y+a1.y+a2.y+a3.y,
                           a0.z+a1.z+a2.z+a3.z, a0.w+a1.w+a2.w+a3.w);
  float es = expf(selflog - m), inv = 1.f/d;
  float4 sv = *(const float4*)&hg[(size_t)n*M + f0];
  float4 hv = load_hl(inH, inL, (size_t)n*M + f0);
  float4 bb = *(const float4*)&ab[f0];
  float4 r = make_float4(
    hv.x + bb.x + (sv.x*es + acc.x)*inv,
    hv.y + bb.y + (sv.y*es + acc.y)*inv,
    hv.z + bb.z + (sv.z*es + acc.z)*inv,
    hv.w + bb.w + (sv.w*es + acc.w)*inv);
  store_hl(outH, outL, (size_t)n*M + f0, r);
}

// ================= attention pooling (fused prep + gather) =================
__global__ void k_pool(const unsigned short* __restrict__ xH, const unsigned short* __restrict__ xL,
                       const float* __restrict__ apre, const int* __restrict__ starts,
                       float* __restrict__ out){
  __shared__ float red[128];
  int g = blockIdx.x, t = threadIdx.x;   // 128 threads
  int b = starts[g], e = starts[g+1];
  float m = -INFINITY;
  for (int n = b + t; n < e; n += 128) m = fmaxf(m, apre[n]);
  red[t] = m; __syncthreads();
  for (int o = 64; o > 0; o >>= 1){
    if (t < o) red[t] = fmaxf(red[t], red[t + o]);
    __syncthreads();
  }
  m = red[0]; __syncthreads();
  float s = 0.f;
  for (int n = b + t; n < e; n += 128) s += expf(apre[n] - m);
  red[t] = s; __syncthreads();
  for (int o = 64; o > 0; o >>= 1){
    if (t < o) red[t] += red[t + o];
    __syncthreads();
  }
  float inv = 1.f / (red[0] + 1e-8f);
  float4 sum = make_float4(0,0,0,0), wacc = make_float4(0,0,0,0);
  float4 mx = make_float4(-INFINITY,-INFINITY,-INFINITY,-INFINITY);
  for (int n = b; n < e; n++){
    float4 xv = load_hl(xH, xL, (size_t)n*DOUT + t*4);
    float p = expf(apre[n] - m) * inv;
    sum.x += xv.x; sum.y += xv.y; sum.z += xv.z; sum.w += xv.w;
    mx.x = fmaxf(mx.x, xv.x); mx.y = fmaxf(mx.y, xv.y);
    mx.z = fmaxf(mx.z, xv.z); mx.w = fmaxf(mx.w, xv.w);
    fma4(wacc, xv, p);
  }
  float ic = 1.f / fmaxf((float)(e - b), 1.f);
  float4* o = (float4*)(out + (size_t)g*4*DOUT);
  o[t]       = wacc;
  o[128 + t] = make_float4(sum.x*ic, sum.y*ic, sum.z*ic, sum.w*ic);
  o[256 + t] = mx;
  o[384 + t] = sum;
}

extern "C" void kernel_launch(void* const* d_in, const int* in_sizes, int n_in,
                              void* d_out, int out_size, void* d_ws, size_t ws_size,
                              hipStream_t stream) {
  const float* x0   = (const float*)d_in[0];
  const int*   ei   = (const int*)d_in[1];
  const int*   src  = ei;
  const int*   dst  = ei + NE;
  const int*   batch= (const int*)d_in[2];
  const float* gw[3]  = {(const float*)d_in[3],  (const float*)d_in[9],  (const float*)d_in[15]};
  const float* gb[3]  = {(const float*)d_in[4],  (const float*)d_in[10], (const float*)d_in[16]};
  const float* aw[3]  = {(const float*)d_in[5],  (const float*)d_in[11], (const float*)d_in[17]};
  const float* asw[3] = {(const float*)d_in[6],  (const float*)d_in[12], (const float*)d_in[18]};
  const float* adw[3] = {(const float*)d_in[7],  (const float*)d_in[13], (const float*)d_in[19]};
  const float* ab[3]  = {(const float*)d_in[8],  (const float*)d_in[14], (const float*)d_in[20]};
  const float* apw1 = (const float*)d_in[21];
  const float* apb1 = (const float*)d_in[22];
  const float* apw2 = (const float*)d_in[23];
  float* out = (float*)d_out;

  // ---- workspace carve ----
  char* p = (char*)d_ws;
  auto alloc = [&](size_t bytes) -> void* {
    void* r = (void*)p; p += (bytes + 255) & ~(size_t)255; return r;
  };
  float* f1 = (float*)alloc((size_t)NN*512*4);
  unsigned short* actH0 = (unsigned short*)alloc((size_t)NN*512*2);   // h (GCN out)
  unsigned short* actL0 = (unsigned short*)alloc((size_t)NN*512*2);
  unsigned short* actH1 = (unsigned short*)alloc((size_t)NN*512*2);   // x (layer out)
  unsigned short* actL1 = (unsigned short*)alloc((size_t)NN*512*2);
  unsigned short* preH  = (unsigned short*)alloc((size_t)NN*256*2);   // aggregated X
  unsigned short* preL  = (unsigned short*)alloc((size_t)NN*256*2);
  unsigned short* x0h = (unsigned short*)alloc((size_t)NN*64*2);
  unsigned short* x0l = (unsigned short*)alloc((size_t)NN*64*2);
  const int wK[7]  = {36, 128, 128, 256, 256, 512, 512};
  const int wM[7]  = {128, 128, 256, 256, 512, 512, 256};
  const int wKp[7] = {64, 128, 128, 256, 256, 512, 512};
  const float* wsrc[7] = {gw[0], aw[0], gw[1], aw[1], gw[2], aw[2], apw1};
  unsigned short* wTh[7]; unsigned short* wTl[7];
  for (int i = 0; i < 7; i++){
    size_t sz = (size_t)wM[i]*wKp[i]*2;
    wTh[i] = (unsigned short*)alloc(sz);
    wTl[i] = (unsigned short*)alloc(sz);
  }
  float* dinv = (float*)alloc(NN*4);
  float* as_  = (float*)alloc(NN*NH*4);
  float* ad_  = (float*)alloc(NN*NH*4);
  float* apre = (float*)alloc(NN*4);
  int* rowptr = (int*)alloc((NN+1)*4);
  int* colidx = (int*)alloc((size_t)NE*4);
  int* cnt    = (int*)alloc(NN*4);
  int* cursor = (int*)alloc(NN*4);
  int* starts = (int*)alloc((NB+1)*4);

  // ---- CSR build + degrees + starts + apre-zero (fused) ----
  hipMemsetAsync(cnt, 0, NN*sizeof(int), stream);
  k_count<<<(NE+255)/256, 256, 0, stream>>>(dst, cnt);
  k_scan<<<1, 256, 0, stream>>>(cnt, rowptr, dinv, cursor, batch, starts, apre);
  k_fill<<<(NE+255)/256, 256, 0, stream>>>(src, dst, rowptr, cursor, colidx);

  // ---- fused conversions ----
  AllConv ac;
  ac.src[0] = x0; ac.dh[0] = x0h; ac.dl[0] = x0l;
  ac.K[0] = 36; ac.Mm[0] = NN; ac.Kp[0] = 64; ac.tot[0] = NN*64;
  int maxtot = NN*64;
  for (int i = 0; i < 7; i++){
    ac.src[i+1] = wsrc[i]; ac.dh[i+1] = wTh[i]; ac.dl[i+1] = wTl[i];
    ac.K[i+1] = wK[i]; ac.Mm[i+1] = wM[i]; ac.Kp[i+1] = wKp[i];
    ac.tot[i+1] = wKp[i]*wM[i];
    if (ac.tot[i+1] > maxtot) maxtot = ac.tot[i+1];
  }
  k_convall<<<dim3((maxtot+255)/256, 8), 256, 0, stream>>>(ac);

  const int dims[4] = {36, 128, 256, 512};
  const int ngrp = (NN + 15) / 16;
  const unsigned short* curH = x0h; const unsigned short* curL = x0l;
  int wi = 0;
  for (int i = 0; i < 3; i++){
    int Kin = (i == 0) ? 64 : dims[i];
    int M = dims[i+1], C = M/NH;
    int nchunk_in = Kin / 64;
    int nchunk = M / 64;
    int nblk = (M/GBN) * ((NN+GBM-1)/GBM);
    // GCN: aggregate X at input dim, then GEMM with fused bias+relu+split epilogue
    k_gcn_pre<<<nchunk_in*ngrp, 256, 0, stream>>>(curH, curL, dinv, rowptr, colidx,
                                                  preH, preL, Kin, nchunk_in);
    k_gemm_bf3<<<nblk, 256, 0, stream>>>(preH, preL, wTh[wi], wTl[wi], f1, NN, wKp[wi], M,
                                         1, gb[i], actH0, actL0,
                                         nullptr, nullptr, nullptr, nullptr, C);
    wi++;
    // GAT: GEMM with fused alpha-dot epilogue, then fused online-softmax gather
    k_gemm_bf3<<<nblk, 256, 0, stream>>>(actH0, actL0, wTh[wi], wTl[wi], f1, NN, wKp[wi], M,
                                         2, nullptr, nullptr, nullptr,
                                         asw[i], adw[i], as_, ad_, C);
    wi++;
    k_gat_gather<<<nchunk*ngrp, 256, 0, stream>>>(f1, actH0, actL0, rowptr, colidx,
                                                  as_, ad_, ab[i],
                                                  actH1, actL1, M, C, nchunk);
    curH = actH1; curL = actL1;
  }

  // ---- pooling: GEMM with fused tanh-dot epilogue -> apre, then fused pool ----
  {
    int nblk = (256/GBN) * ((NN+GBM-1)/GBM);
    k_gemm_bf3<<<nblk, 256, 0, stream>>>(actH1, actL1, wTh[6], wTl[6], f1, NN, wKp[6], 256,
                                         3, apb1, nullptr, nullptr,
                                         apw2, nullptr, apre, nullptr, 64);
  }
  k_pool<<<NB, 128, 0, stream>>>(actH1, actL1, apre, starts, out);
}

// Round 13
// 410.494 us; speedup vs baseline: 5.6252x; 1.0755x over previous
//
#include <hip/hip_runtime.h>
#include <math.h>

#define NN 10000
#define NE 160000
#define NB 128
#define NH 4
#define DOUT 512
#define NEG 0.2f
#define SCAN_BLKS ((NN + 255) / 256)   // 40

typedef __attribute__((ext_vector_type(8))) short short8;
typedef __attribute__((ext_vector_type(4))) float f32x4;
typedef __attribute__((ext_vector_type(4))) unsigned short us4;

__device__ __forceinline__ float leakyf(float v){ return v > 0.f ? v : NEG*v; }
__device__ __forceinline__ void fma4(float4& a, const float4 v, float w){
  a.x += v.x*w; a.y += v.y*w; a.z += v.z*w; a.w += v.w*w;
}
__device__ __forceinline__ void mul4(float4& a, float s){
  a.x *= s; a.y *= s; a.z *= s; a.w *= s;
}
__device__ __forceinline__ unsigned short f2bf(float f){
  unsigned int u = __float_as_uint(f);
  u += 0x7FFFu + ((u >> 16) & 1u);
  return (unsigned short)(u >> 16);
}
__device__ __forceinline__ float bf2f(unsigned short h){
  return __uint_as_float(((unsigned int)h) << 16);
}
__device__ __forceinline__ void split2(float v, unsigned short& h, unsigned short& l){
  h = f2bf(v);
  l = f2bf(v - bf2f(h));
}
__device__ __forceinline__ void store_hl(unsigned short* H, unsigned short* L,
                                         size_t base, float4 v){
  us4 h, l; unsigned short hh, ll;
  split2(v.x, hh, ll); h[0]=hh; l[0]=ll;
  split2(v.y, hh, ll); h[1]=hh; l[1]=ll;
  split2(v.z, hh, ll); h[2]=hh; l[2]=ll;
  split2(v.w, hh, ll); h[3]=hh; l[3]=ll;
  *(us4*)&H[base] = h;
  *(us4*)&L[base] = l;
}
__device__ __forceinline__ float4 load_hl(const unsigned short* __restrict__ H,
                                          const unsigned short* __restrict__ L, size_t base){
  us4 h = *(const us4*)&H[base];
  us4 l = *(const us4*)&L[base];
  return make_float4(bf2f(h[0])+bf2f(l[0]), bf2f(h[1])+bf2f(l[1]),
                     bf2f(h[2])+bf2f(l[2]), bf2f(h[3])+bf2f(l[3]));
}
__device__ __forceinline__ void gl_lds16(const unsigned short* g, unsigned short* l){
  __builtin_amdgcn_global_load_lds(
      (const __attribute__((address_space(1))) unsigned int*)g,
      (__attribute__((address_space(3))) unsigned int*)l, 16, 0, 0);
}

// ================= CSR build =================
__global__ void k_count(const int* __restrict__ dst, int* __restrict__ cnt){
  int e = blockIdx.x*blockDim.x + threadIdx.x;
  if (e < NE) atomicAdd(&cnt[dst[e]], 1);
}
// stage 1: per-block sums of cnt; block 0 also computes segment starts (independent)
__global__ void k_scan1(const int* __restrict__ cnt, int* __restrict__ bsum,
                        const int* __restrict__ batch, int* __restrict__ starts){
  __shared__ int red[256];
  int blk = blockIdx.x, t = threadIdx.x;
  int idx = blk*256 + t;
  red[t] = (idx < NN) ? cnt[idx] : 0;
  __syncthreads();
  for (int o = 128; o > 0; o >>= 1){
    if (t < o) red[t] += red[t + o];
    __syncthreads();
  }
  if (t == 0) bsum[blk] = red[0];
  if (blk == 0 && t <= NB){
    int lo = 0, hi = NN;
    while (lo < hi){ int mid = (lo + hi) >> 1; if (batch[mid] < t) lo = mid + 1; else hi = mid; }
    starts[t] = lo;
  }
}
// stage 2: scan the 40 block sums (tiny), write rowptr[NN]
__global__ void k_scan2(int* __restrict__ bsum, int* __restrict__ rowptr){
  if (threadIdx.x == 0){
    int acc = 0;
    for (int i = 0; i < SCAN_BLKS; i++){
      int c = bsum[i]; bsum[i] = acc; acc += c;
    }
    rowptr[NN] = acc;
  }
}
// stage 3: in-block exclusive scan + offset; init dinv/cursor/apre
__global__ void k_scan3(const int* __restrict__ cnt, const int* __restrict__ bsum,
                        int* __restrict__ rowptr, float* __restrict__ dinv,
                        int* __restrict__ cursor, float* __restrict__ apre){
  __shared__ int s[256];
  int blk = blockIdx.x, t = threadIdx.x;
  int idx = blk*256 + t;
  int c = (idx < NN) ? cnt[idx] : 0;
  s[t] = c; __syncthreads();
  for (int o = 1; o < 256; o <<= 1){
    int v = 0;
    if (t >= o) v = s[t - o];
    __syncthreads();
    if (t >= o) s[t] += v;
    __syncthreads();
  }
  if (idx < NN){
    rowptr[idx] = bsum[blk] + s[t] - c;   // exclusive
    dinv[idx] = rsqrtf((float)c + 1.f);
    cursor[idx] = 0;
    apre[idx] = 0.f;
  }
}
__global__ void k_fill(const int* __restrict__ src, const int* __restrict__ dst,
                       const int* __restrict__ rowptr, int* __restrict__ cursor,
                       int* __restrict__ colidx){
  int e = blockIdx.x*blockDim.x + threadIdx.x;
  if (e >= NE) return;
  int d = dst[e];
  int pos = atomicAdd(&cursor[d], 1);
  colidx[rowptr[d] + pos] = src[e];
}

// ============ fused conversions: job 0 = x0 pad-convert, jobs 1..7 = W^T ============
struct AllConv {
  const float* src[8];
  unsigned short* dh[8];
  unsigned short* dl[8];
  int K[8], Mm[8], Kp[8], tot[8];
};
__global__ void k_convall(AllConv a){
  int j = blockIdx.y;
  int idx = blockIdx.x*blockDim.x + threadIdx.x;
  if (idx >= a.tot[j]) return;
  float v;
  if (j == 0){
    int n = idx >> 6, c = idx & 63;
    v = (c < 36) ? a.src[0][n*36 + c] : 0.f;
  } else {
    int Kp = a.Kp[j], K = a.K[j], M = a.Mm[j];
    int kk = idx % Kp, m = idx / Kp;
    v = (kk < K) ? a.src[j][(size_t)kk*M + m] : 0.f;
  }
  unsigned short h, l; split2(v, h, l);
  a.dh[j][idx] = h; a.dl[j][idx] = l;
}

// ===== GEMM: C[N,M] = (Ah+Al)[N,Kp] @ (Bh+Bl)^T, bf16x3, m97-style =====
// 64x128 tile, 4 waves x (4m x 2n), global_load_lds staging, chunk swizzle.
// mode 0: plain fp32 -> C
// mode 1: GCN epilogue: relu(acc + bias) -> hi/lo bf16
// mode 2: fp32 -> C + fused per-head alpha dots -> as_o/ad_o
// mode 3: pooling head: atomicAdd(apre, tanh(acc+bias).w2); no C store
#define GBM 64
#define GBN 128
#define GBK 32
__global__ __launch_bounds__(256) void k_gemm_bf3(
    const unsigned short* __restrict__ Ah, const unsigned short* __restrict__ Al,
    const unsigned short* __restrict__ Bh, const unsigned short* __restrict__ Bl,
    float* __restrict__ C, int N, int Kp, int M, int mode,
    const float* __restrict__ bias, unsigned short* __restrict__ outH,
    unsigned short* __restrict__ outL,
    const float* __restrict__ a_s, const float* __restrict__ a_d,
    float* __restrict__ as_o, float* __restrict__ ad_o, int Cdim){
  __shared__ unsigned short AsH[GBM*GBK], AsL[GBM*GBK];
  __shared__ unsigned short BsH[GBN*GBK], BsL[GBN*GBK];
  __shared__ float sred[2][GBM][4];
  int gx = M / GBN;
  int gy = (N + GBM - 1) / GBM;
  const int G = 8;
  int bid = blockIdx.x;
  int full = gy / G;
  int bid_full = full * G * gx;
  int by, bx;
  if (bid < bid_full){
    int g = bid / (G*gx); int rem = bid % (G*gx);
    by = g*G + rem % G; bx = rem / G;
  } else {
    int rem = bid - bid_full; int rows = gy - full*G;
    by = full*G + rem % rows; bx = rem / rows;
  }
  int row0 = by * GBM, col0 = bx * GBN;
  int t = threadIdx.x;
  int w = t >> 6, L = t & 63;
  int lm = L & 15, lq = L >> 4;
  int wc = w * 32;

  int sr = L >> 2, sc = L & 3;
  int art = w*16 + sr;
  int ga  = (sc - ((art >> 1) & 3)) & 3;
  int agrow = min(row0 + art, N-1);
  int brt0 = w*16 + sr;
  int brt1 = (w+4)*16 + sr;
  int gb0 = (sc - ((brt0 >> 1) & 3)) & 3;
  int gb1 = (sc - ((brt1 >> 1) & 3)) & 3;
  int bgrow0 = col0 + brt0, bgrow1 = col0 + brt1;

  int rc = (lq + (lm >> 1)) & 3;
  int aoff[4], boff[2];
#pragma unroll
  for (int mi = 0; mi < 4; mi++) aoff[mi] = (mi*16 + lm)*32 + rc*8;
#pragma unroll
  for (int ni = 0; ni < 2; ni++) boff[ni] = (wc + ni*16 + lm)*32 + rc*8;

  f32x4 acc[4][2];
#pragma unroll
  for (int i = 0; i < 4; i++)
#pragma unroll
    for (int j = 0; j < 2; j++) acc[i][j] = (f32x4){0.f,0.f,0.f,0.f};

  int nk = Kp / GBK;
  for (int kt = 0; kt < nk; kt++){
    int k0 = kt * GBK;
    if (kt) __syncthreads();
    gl_lds16(&Ah[(size_t)agrow*Kp + k0 + ga*8],  &AsH[w*512]);
    gl_lds16(&Al[(size_t)agrow*Kp + k0 + ga*8],  &AsL[w*512]);
    gl_lds16(&Bh[(size_t)bgrow0*Kp + k0 + gb0*8], &BsH[w*512]);
    gl_lds16(&Bh[(size_t)bgrow1*Kp + k0 + gb1*8], &BsH[(w+4)*512]);
    gl_lds16(&Bl[(size_t)bgrow0*Kp + k0 + gb0*8], &BsL[w*512]);
    gl_lds16(&Bl[(size_t)bgrow1*Kp + k0 + gb1*8], &BsL[(w+4)*512]);
    __syncthreads();

    short8 ah[4], al[4], bh[2], bl[2];
#pragma unroll
    for (int mi = 0; mi < 4; mi++){
      ah[mi] = *(const short8*)&AsH[aoff[mi]];
      al[mi] = *(const short8*)&AsL[aoff[mi]];
    }
#pragma unroll
    for (int ni = 0; ni < 2; ni++){
      bh[ni] = *(const short8*)&BsH[boff[ni]];
      bl[ni] = *(const short8*)&BsL[boff[ni]];
    }
#pragma unroll
    for (int mi = 0; mi < 4; mi++)
#pragma unroll
      for (int ni = 0; ni < 2; ni++){
        acc[mi][ni] = __builtin_amdgcn_mfma_f32_16x16x32_bf16(ah[mi], bh[ni], acc[mi][ni], 0, 0, 0);
        acc[mi][ni] = __builtin_amdgcn_mfma_f32_16x16x32_bf16(ah[mi], bl[ni], acc[mi][ni], 0, 0, 0);
        acc[mi][ni] = __builtin_amdgcn_mfma_f32_16x16x32_bf16(al[mi], bh[ni], acc[mi][ni], 0, 0, 0);
      }
  }
  // ---- epilogue; C/D layout col=lane&15, row=(lane>>4)*4+reg ----
  if (mode == 1){
#pragma unroll
    for (int mi = 0; mi < 4; mi++)
#pragma unroll
      for (int ni = 0; ni < 2; ni++){
#pragma unroll
        for (int r = 0; r < 4; r++){
          int row = row0 + mi*16 + lq*4 + r;
          int col = col0 + wc + ni*16 + lm;
          if (row < N){
            float v = fmaxf(acc[mi][ni][r] + bias[col], 0.f);
            unsigned short hh, ll; split2(v, hh, ll);
            outH[(size_t)row*M + col] = hh;
            outL[(size_t)row*M + col] = ll;
          }
        }
      }
  } else if (mode != 3){
#pragma unroll
    for (int mi = 0; mi < 4; mi++)
#pragma unroll
      for (int ni = 0; ni < 2; ni++){
#pragma unroll
        for (int r = 0; r < 4; r++){
          int row = row0 + mi*16 + lq*4 + r;
          int col = col0 + wc + ni*16 + lm;
          if (row < N) C[(size_t)row*M + col] = acc[mi][ni][r];
        }
      }
  }
  if (mode == 2){
    float sA0 = a_s[col0 + wc + lm], sA1 = a_s[col0 + wc + 16 + lm];
    float dA0 = a_d[col0 + wc + lm], dA1 = a_d[col0 + wc + 16 + lm];
#pragma unroll
    for (int mi = 0; mi < 4; mi++)
#pragma unroll
      for (int r = 0; r < 4; r++){
        float vs = acc[mi][0][r]*sA0 + acc[mi][1][r]*sA1;
        float vd = acc[mi][0][r]*dA0 + acc[mi][1][r]*dA1;
#pragma unroll
        for (int o = 1; o <= 8; o <<= 1){
          vs += __shfl_xor(vs, o);
          vd += __shfl_xor(vd, o);
        }
        if (lm == 0){
          int row = mi*16 + lq*4 + r;
          sred[0][row][w] = vs;
          sred[1][row][w] = vd;
        }
      }
    __syncthreads();
    if (t < GBM){
      int n = row0 + t;
      if (n < N){
        int wph = Cdim >> 5;
        int nheads = 4 / wph;
        for (int g = 0; g < nheads; g++){
          float ss = 0.f, dd = 0.f;
          for (int q = 0; q < wph; q++){
            ss += sred[0][t][g*wph + q];
            dd += sred[1][t][g*wph + q];
          }
          int hd = (col0 + g*wph*32) / Cdim;
          as_o[n*NH + hd] = ss;
          ad_o[n*NH + hd] = dd;
        }
      }
    }
  } else if (mode == 3){
    float b0 = bias[col0 + wc + lm], b1v = bias[col0 + wc + 16 + lm];
    float w0v = a_s[col0 + wc + lm], w1v = a_s[col0 + wc + 16 + lm];
#pragma unroll
    for (int mi = 0; mi < 4; mi++)
#pragma unroll
      for (int r = 0; r < 4; r++){
        float v = tanhf(acc[mi][0][r] + b0)*w0v + tanhf(acc[mi][1][r] + b1v)*w1v;
#pragma unroll
        for (int o = 1; o <= 8; o <<= 1) v += __shfl_xor(v, o);
        if (lm == 0) sred[0][mi*16 + lq*4 + r][w] = v;
      }
    __syncthreads();
    if (t < GBM){
      int n = row0 + t;
      if (n < N){
        float s = sred[0][t][0] + sred[0][t][1] + sred[0][t][2] + sred[0][t][3];
        atomicAdd(&as_o[n], s);
      }
    }
  }
}

// ===== GCN pre-aggregation: aggregate X at input dim (A(XW) = (AX)W) =====
__global__ __launch_bounds__(256) void k_gcn_pre(
    const unsigned short* __restrict__ inH, const unsigned short* __restrict__ inL,
    const float* __restrict__ dinv,
    const int* __restrict__ rowptr, const int* __restrict__ colidx,
    unsigned short* __restrict__ outH, unsigned short* __restrict__ outL,
    int Kp, int nchunk){
  int bid = blockIdx.x;
  int chunk = bid % nchunk, grp = bid / nchunk;
  int t = threadIdx.x;
  int sub = t & 15;
  int n = grp*16 + (t >> 4);
  if (n >= NN) return;
  int f0 = chunk*64 + sub*4;
  int b = rowptr[n], e = rowptr[n+1];
  float dn = dinv[n];
  float4 a0 = make_float4(0,0,0,0), a1 = make_float4(0,0,0,0);
  float4 a2 = make_float4(0,0,0,0), a3 = make_float4(0,0,0,0);
  int j = b;
  for (; j + 3 < e; j += 4){
    int s0 = colidx[j], s1 = colidx[j+1], s2 = colidx[j+2], s3 = colidx[j+3];
    float w0 = dinv[s0], w1 = dinv[s1], w2 = dinv[s2], w3 = dinv[s3];
    float4 v0 = load_hl(inH, inL, (size_t)s0*Kp + f0);
    float4 v1 = load_hl(inH, inL, (size_t)s1*Kp + f0);
    float4 v2 = load_hl(inH, inL, (size_t)s2*Kp + f0);
    float4 v3 = load_hl(inH, inL, (size_t)s3*Kp + f0);
    fma4(a0, v0, w0*dn); fma4(a1, v1, w1*dn);
    fma4(a2, v2, w2*dn); fma4(a3, v3, w3*dn);
  }
  for (; j < e; j++){
    int s = colidx[j];
    float4 v = load_hl(inH, inL, (size_t)s*Kp + f0);
    fma4(a0, v, dinv[s]*dn);
  }
  float4 acc = make_float4(a0.x+a1.x+a2.x+a3.x, a0.y+a1.y+a2.y+a3.y,
                           a0.z+a1.z+a2.z+a3.z, a0.w+a1.w+a2.w+a3.w);
  float4 sv = load_hl(inH, inL, (size_t)n*Kp + f0);
  float dn2 = dn*dn;
  acc.x += sv.x*dn2; acc.y += sv.y*dn2; acc.z += sv.z*dn2; acc.w += sv.w*dn2;
  store_hl(outH, outL, (size_t)n*Kp + f0, acc);
}

// ===== GAT gather: fused online-softmax (flash-style), feature-chunked,
//       XCD-aligned, 4-way edge-unrolled =====
__global__ __launch_bounds__(256) void k_gat_gather(
    const float* __restrict__ hg,
    const unsigned short* __restrict__ inH, const unsigned short* __restrict__ inL,
    const int* __restrict__ rowptr, const int* __restrict__ colidx,
    const float* __restrict__ as_, const float* __restrict__ ad_,
    const float* __restrict__ ab,
    unsigned short* __restrict__ outH, unsigned short* __restrict__ outL,
    int M, int C, int nchunk){
  int bid = blockIdx.x;
  int chunk = bid % nchunk, grp = bid / nchunk;
  int t = threadIdx.x;
  int sub = t & 15;
  int n = grp*16 + (t >> 4);
  if (n >= NN) return;
  int f0 = chunk*64 + sub*4;
  int hd = f0 / C;
  int b = rowptr[n], e = rowptr[n+1];
  int ai = n*NH + hd;
  float adn = ad_[ai];
  float selflog = leakyf(as_[ai] + adn);
  float m = selflog, d = 1.f;
  float4 a0 = make_float4(0,0,0,0), a1 = make_float4(0,0,0,0);
  float4 a2 = make_float4(0,0,0,0), a3 = make_float4(0,0,0,0);
  int j = b;
  for (; j + 3 < e; j += 4){
    int s0 = colidx[j], s1 = colidx[j+1], s2 = colidx[j+2], s3 = colidx[j+3];
    float l0 = leakyf(as_[s0*NH + hd] + adn), l1 = leakyf(as_[s1*NH + hd] + adn);
    float l2 = leakyf(as_[s2*NH + hd] + adn), l3 = leakyf(as_[s3*NH + hd] + adn);
    float4 v0 = *(const float4*)&hg[(size_t)s0*M + f0];
    float4 v1 = *(const float4*)&hg[(size_t)s1*M + f0];
    float4 v2 = *(const float4*)&hg[(size_t)s2*M + f0];
    float4 v3 = *(const float4*)&hg[(size_t)s3*M + f0];
    float m4 = fmaxf(fmaxf(l0, l1), fmaxf(l2, l3));
    if (m4 > m){
      float sc = expf(m - m4);
      d *= sc; mul4(a0, sc); mul4(a1, sc); mul4(a2, sc); mul4(a3, sc);
      m = m4;
    }
    float w0 = expf(l0 - m), w1 = expf(l1 - m);
    float w2 = expf(l2 - m), w3 = expf(l3 - m);
    d += (w0 + w1) + (w2 + w3);
    fma4(a0, v0, w0); fma4(a1, v1, w1);
    fma4(a2, v2, w2); fma4(a3, v3, w3);
  }
  for (; j < e; j++){
    int s = colidx[j];
    float l = leakyf(as_[s*NH + hd] + adn);
    float4 v = *(const float4*)&hg[(size_t)s*M + f0];
    if (l > m){
      float sc = expf(m - l);
      d *= sc; mul4(a0, sc); mul4(a1, sc); mul4(a2, sc); mul4(a3, sc);
      m = l;
    }
    float ww = expf(l - m);
    d += ww;
    fma4(a0, v, ww);
  }
  float4 acc = make_float4(a0.x+a1.x+a2.x+a3.x, a0.y+a1.y+a2.y+a3.y,
                           a0.z+a1.z+a2.z+a3.z, a0.w+a1.w+a2.w+a3.w);
  float es = expf(selflog - m), inv = 1.f/d;
  float4 sv = *(const float4*)&hg[(size_t)n*M + f0];
  float4 hv = load_hl(inH, inL, (size_t)n*M + f0);
  float4 bb = *(const float4*)&ab[f0];
  float4 r = make_float4(
    hv.x + bb.x + (sv.x*es + acc.x)*inv,
    hv.y + bb.y + (sv.y*es + acc.y)*inv,
    hv.z + bb.z + (sv.z*es + acc.z)*inv,
    hv.w + bb.w + (sv.w*es + acc.w)*inv);
  store_hl(outH, outL, (size_t)n*M + f0, r);
}

// ================= attention pooling (fused prep + gather) =================
__global__ void k_pool(const unsigned short* __restrict__ xH, const unsigned short* __restrict__ xL,
                       const float* __restrict__ apre, const int* __restrict__ starts,
                       float* __restrict__ out){
  __shared__ float red[128];
  int g = blockIdx.x, t = threadIdx.x;
  int b = starts[g], e = starts[g+1];
  float m = -INFINITY;
  for (int n = b + t; n < e; n += 128) m = fmaxf(m, apre[n]);
  red[t] = m; __syncthreads();
  for (int o = 64; o > 0; o >>= 1){
    if (t < o) red[t] = fmaxf(red[t], red[t + o]);
    __syncthreads();
  }
  m = red[0]; __syncthreads();
  float s = 0.f;
  for (int n = b + t; n < e; n += 128) s += expf(apre[n] - m);
  red[t] = s; __syncthreads();
  for (int o = 64; o > 0; o >>= 1){
    if (t < o) red[t] += red[t + o];
    __syncthreads();
  }
  float inv = 1.f / (red[0] + 1e-8f);
  float4 sum = make_float4(0,0,0,0), wacc = make_float4(0,0,0,0);
  float4 mx = make_float4(-INFINITY,-INFINITY,-INFINITY,-INFINITY);
  for (int n = b; n < e; n++){
    float4 xv = load_hl(xH, xL, (size_t)n*DOUT + t*4);
    float p = expf(apre[n] - m) * inv;
    sum.x += xv.x; sum.y += xv.y; sum.z += xv.z; sum.w += xv.w;
    mx.x = fmaxf(mx.x, xv.x); mx.y = fmaxf(mx.y, xv.y);
    mx.z = fmaxf(mx.z, xv.z); mx.w = fmaxf(mx.w, xv.w);
    fma4(wacc, xv, p);
  }
  float ic = 1.f / fmaxf((float)(e - b), 1.f);
  float4* o = (float4*)(out + (size_t)g*4*DOUT);
  o[t]       = wacc;
  o[128 + t] = make_float4(sum.x*ic, sum.y*ic, sum.z*ic, sum.w*ic);
  o[256 + t] = mx;
  o[384 + t] = sum;
}

extern "C" void kernel_launch(void* const* d_in, const int* in_sizes, int n_in,
                              void* d_out, int out_size, void* d_ws, size_t ws_size,
                              hipStream_t stream) {
  const float* x0   = (const float*)d_in[0];
  const int*   ei   = (const int*)d_in[1];
  const int*   src  = ei;
  const int*   dst  = ei + NE;
  const int*   batch= (const int*)d_in[2];
  const float* gw[3]  = {(const float*)d_in[3],  (const float*)d_in[9],  (const float*)d_in[15]};
  const float* gb[3]  = {(const float*)d_in[4],  (const float*)d_in[10], (const float*)d_in[16]};
  const float* aw[3]  = {(const float*)d_in[5],  (const float*)d_in[11], (const float*)d_in[17]};
  const float* asw[3] = {(const float*)d_in[6],  (const float*)d_in[12], (const float*)d_in[18]};
  const float* adw[3] = {(const float*)d_in[7],  (const float*)d_in[13], (const float*)d_in[19]};
  const float* ab[3]  = {(const float*)d_in[8],  (const float*)d_in[14], (const float*)d_in[20]};
  const float* apw1 = (const float*)d_in[21];
  const float* apb1 = (const float*)d_in[22];
  const float* apw2 = (const float*)d_in[23];
  float* out = (float*)d_out;

  // ---- workspace carve ----
  char* p = (char*)d_ws;
  auto alloc = [&](size_t bytes) -> void* {
    void* r = (void*)p; p += (bytes + 255) & ~(size_t)255; return r;
  };
  float* f1 = (float*)alloc((size_t)NN*512*4);
  unsigned short* actH0 = (unsigned short*)alloc((size_t)NN*512*2);
  unsigned short* actL0 = (unsigned short*)alloc((size_t)NN*512*2);
  unsigned short* actH1 = (unsigned short*)alloc((size_t)NN*512*2);
  unsigned short* actL1 = (unsigned short*)alloc((size_t)NN*512*2);
  unsigned short* preH  = (unsigned short*)alloc((size_t)NN*256*2);
  unsigned short* preL  = (unsigned short*)alloc((size_t)NN*256*2);
  unsigned short* x0h = (unsigned short*)alloc((size_t)NN*64*2);
  unsigned short* x0l = (unsigned short*)alloc((size_t)NN*64*2);
  const int wK[7]  = {36, 128, 128, 256, 256, 512, 512};
  const int wM[7]  = {128, 128, 256, 256, 512, 512, 256};
  const int wKp[7] = {64, 128, 128, 256, 256, 512, 512};
  const float* wsrc[7] = {gw[0], aw[0], gw[1], aw[1], gw[2], aw[2], apw1};
  unsigned short* wTh[7]; unsigned short* wTl[7];
  for (int i = 0; i < 7; i++){
    size_t sz = (size_t)wM[i]*wKp[i]*2;
    wTh[i] = (unsigned short*)alloc(sz);
    wTl[i] = (unsigned short*)alloc(sz);
  }
  float* dinv = (float*)alloc(NN*4);
  float* as_  = (float*)alloc(NN*NH*4);
  float* ad_  = (float*)alloc(NN*NH*4);
  float* apre = (float*)alloc(NN*4);
  int* rowptr = (int*)alloc((NN+1)*4);
  int* colidx = (int*)alloc((size_t)NE*4);
  int* cnt    = (int*)alloc(NN*4);
  int* cursor = (int*)alloc(NN*4);
  int* starts = (int*)alloc((NB+1)*4);
  int* bsum   = (int*)alloc(SCAN_BLKS*4);

  // ---- CSR build: count -> hierarchical scan -> fill ----
  hipMemsetAsync(cnt, 0, NN*sizeof(int), stream);
  k_count<<<(NE+255)/256, 256, 0, stream>>>(dst, cnt);
  k_scan1<<<SCAN_BLKS, 256, 0, stream>>>(cnt, bsum, batch, starts);
  k_scan2<<<1, 64, 0, stream>>>(bsum, rowptr);
  k_scan3<<<SCAN_BLKS, 256, 0, stream>>>(cnt, bsum, rowptr, dinv, cursor, apre);
  k_fill<<<(NE+255)/256, 256, 0, stream>>>(src, dst, rowptr, cursor, colidx);

  // ---- fused conversions ----
  AllConv ac;
  ac.src[0] = x0; ac.dh[0] = x0h; ac.dl[0] = x0l;
  ac.K[0] = 36; ac.Mm[0] = NN; ac.Kp[0] = 64; ac.tot[0] = NN*64;
  int maxtot = NN*64;
  for (int i = 0; i < 7; i++){
    ac.src[i+1] = wsrc[i]; ac.dh[i+1] = wTh[i]; ac.dl[i+1] = wTl[i];
    ac.K[i+1] = wK[i]; ac.Mm[i+1] = wM[i]; ac.Kp[i+1] = wKp[i];
    ac.tot[i+1] = wKp[i]*wM[i];
    if (ac.tot[i+1] > maxtot) maxtot = ac.tot[i+1];
  }
  k_convall<<<dim3((maxtot+255)/256, 8), 256, 0, stream>>>(ac);

  const int dims[4] = {36, 128, 256, 512};
  const int ngrp = (NN + 15) / 16;
  const unsigned short* curH = x0h; const unsigned short* curL = x0l;
  int wi = 0;
  for (int i = 0; i < 3; i++){
    int Kin = (i == 0) ? 64 : dims[i];
    int M = dims[i+1], C = M/NH;
    int nchunk_in = Kin / 64;
    int nchunk = M / 64;
    int nblk = (M/GBN) * ((NN+GBM-1)/GBM);
    k_gcn_pre<<<nchunk_in*ngrp, 256, 0, stream>>>(curH, curL, dinv, rowptr, colidx,
                                                  preH, preL, Kin, nchunk_in);
    k_gemm_bf3<<<nblk, 256, 0, stream>>>(preH, preL, wTh[wi], wTl[wi], f1, NN, wKp[wi], M,
                                         1, gb[i], actH0, actL0,
                                         nullptr, nullptr, nullptr, nullptr, C);
    wi++;
    k_gemm_bf3<<<nblk, 256, 0, stream>>>(actH0, actL0, wTh[wi], wTl[wi], f1, NN, wKp[wi], M,
                                         2, nullptr, nullptr, nullptr,
                                         asw[i], adw[i], as_, ad_, C);
    wi++;
    k_gat_gather<<<nchunk*ngrp, 256, 0, stream>>>(f1, actH0, actL0, rowptr, colidx,
                                                  as_, ad_, ab[i],
                                                  actH1, actL1, M, C, nchunk);
    curH = actH1; curL = actL1;
  }

  // ---- pooling ----
  {
    int nblk = (256/GBN) * ((NN+GBM-1)/GBM);
    k_gemm_bf3<<<nblk, 256, 0, stream>>>(actH1, actL1, wTh[6], wTl[6], f1, NN, wKp[6], 256,
                                         3, apb1, nullptr, nullptr,
                                         apw2, nullptr, apre, nullptr, 64);
  }
  k_pool<<<NB, 128, 0, stream>>>(actH1, actL1, apre, starts, out);
}

// Round 14
// 400.688 us; speedup vs baseline: 5.7629x; 1.0245x over previous
//
#include <hip/hip_runtime.h>
#include <math.h>

#define NN 10000
#define NE 160000
#define NB 128
#define NH 4
#define DOUT 512
#define NEG 0.2f
#define SCAN_BLKS ((NN + 255) / 256)   // 40
#define CNT_BLKS ((NE + 255) / 256)    // 625

typedef __attribute__((ext_vector_type(8))) short short8;
typedef __attribute__((ext_vector_type(4))) float f32x4;
typedef __attribute__((ext_vector_type(4))) unsigned short us4;

__device__ __forceinline__ float leakyf(float v){ return v > 0.f ? v : NEG*v; }
__device__ __forceinline__ void fma4(float4& a, const float4 v, float w){
  a.x += v.x*w; a.y += v.y*w; a.z += v.z*w; a.w += v.w*w;
}
__device__ __forceinline__ void mul4(float4& a, float s){
  a.x *= s; a.y *= s; a.z *= s; a.w *= s;
}
__device__ __forceinline__ unsigned short f2bf(float f){
  unsigned int u = __float_as_uint(f);
  u += 0x7FFFu + ((u >> 16) & 1u);
  return (unsigned short)(u >> 16);
}
__device__ __forceinline__ float bf2f(unsigned short h){
  return __uint_as_float(((unsigned int)h) << 16);
}
__device__ __forceinline__ void split2(float v, unsigned short& h, unsigned short& l){
  h = f2bf(v);
  l = f2bf(v - bf2f(h));
}
__device__ __forceinline__ void store_hl(unsigned short* H, unsigned short* L,
                                         size_t base, float4 v){
  us4 h, l; unsigned short hh, ll;
  split2(v.x, hh, ll); h[0]=hh; l[0]=ll;
  split2(v.y, hh, ll); h[1]=hh; l[1]=ll;
  split2(v.z, hh, ll); h[2]=hh; l[2]=ll;
  split2(v.w, hh, ll); h[3]=hh; l[3]=ll;
  *(us4*)&H[base] = h;
  *(us4*)&L[base] = l;
}
__device__ __forceinline__ float4 load_hl(const unsigned short* __restrict__ H,
                                          const unsigned short* __restrict__ L, size_t base){
  us4 h = *(const us4*)&H[base];
  us4 l = *(const us4*)&L[base];
  return make_float4(bf2f(h[0])+bf2f(l[0]), bf2f(h[1])+bf2f(l[1]),
                     bf2f(h[2])+bf2f(l[2]), bf2f(h[3])+bf2f(l[3]));
}
__device__ __forceinline__ void gl_lds16(const unsigned short* g, unsigned short* l){
  __builtin_amdgcn_global_load_lds(
      (const __attribute__((address_space(1))) unsigned int*)g,
      (__attribute__((address_space(3))) unsigned int*)l, 16, 0, 0);
}

// ============ conversions descriptor (weights only; x0 handled by k_gcn_pre0) ============
struct AllConv {
  const float* src[7];
  unsigned short* dh[7];
  unsigned short* dl[7];
  int K[7], Mm[7], Kp[7], tot[7];
};

// ===== merged: edge count (blocks [0,CNT_BLKS)) + weight conversions (rest) =====
__global__ void k_count_conv(const int* __restrict__ dst, int* __restrict__ cnt,
                             AllConv a, int convTot){
  int bid = blockIdx.x;
  if (bid < CNT_BLKS){
    int e = bid*256 + threadIdx.x;
    if (e < NE) atomicAdd(&cnt[dst[e]], 1);
  } else {
    int idx = (bid - CNT_BLKS)*256 + threadIdx.x;
    if (idx >= convTot) return;
    int j = 0;
    while (idx >= a.tot[j]){ idx -= a.tot[j]; j++; }
    int Kp = a.Kp[j], K = a.K[j], M = a.Mm[j];
    int kk = idx % Kp, m = idx / Kp;
    float v = (kk < K) ? a.src[j][(size_t)kk*M + m] : 0.f;
    unsigned short h, l; split2(v, h, l);
    a.dh[j][idx] = h; a.dl[j][idx] = l;
  }
}
// stage 1: per-block sums of cnt; block 0 also computes segment starts (independent)
__global__ void k_scan1(const int* __restrict__ cnt, int* __restrict__ bsum,
                        const int* __restrict__ batch, int* __restrict__ starts){
  __shared__ int red[256];
  int blk = blockIdx.x, t = threadIdx.x;
  int idx = blk*256 + t;
  red[t] = (idx < NN) ? cnt[idx] : 0;
  __syncthreads();
  for (int o = 128; o > 0; o >>= 1){
    if (t < o) red[t] += red[t + o];
    __syncthreads();
  }
  if (t == 0) bsum[blk] = red[0];
  if (blk == 0 && t <= NB){
    int lo = 0, hi = NN;
    while (lo < hi){ int mid = (lo + hi) >> 1; if (batch[mid] < t) lo = mid + 1; else hi = mid; }
    starts[t] = lo;
  }
}
// stage 2+3 merged: each block locally scans the 40 partials, then in-block scan;
// inits dinv/cursor/apre; last block writes rowptr[NN]
__global__ void k_scan3(const int* __restrict__ cnt, const int* __restrict__ bsum,
                        int* __restrict__ rowptr, float* __restrict__ dinv,
                        int* __restrict__ cursor, float* __restrict__ apre){
  __shared__ int s[256];
  __shared__ int base_s;
  int blk = blockIdx.x, t = threadIdx.x;
  int idx = blk*256 + t;
  int c = (idx < NN) ? cnt[idx] : 0;
  s[t] = c;
  if (t == 0){
    int acc = 0;
    for (int i = 0; i < blk; i++) acc += bsum[i];
    base_s = acc;
    if (blk == SCAN_BLKS - 1){
      int tot = acc;
      for (int i = blk; i < SCAN_BLKS; i++) tot += bsum[i];
      rowptr[NN] = tot;
    }
  }
  __syncthreads();
  for (int o = 1; o < 256; o <<= 1){
    int v = 0;
    if (t >= o) v = s[t - o];
    __syncthreads();
    if (t >= o) s[t] += v;
    __syncthreads();
  }
  if (idx < NN){
    rowptr[idx] = base_s + s[t] - c;   // exclusive
    dinv[idx] = rsqrtf((float)c + 1.f);
    cursor[idx] = 0;
    apre[idx] = 0.f;
  }
}
__global__ void k_fill(const int* __restrict__ src, const int* __restrict__ dst,
                       const int* __restrict__ rowptr, int* __restrict__ cursor,
                       int* __restrict__ colidx){
  int e = blockIdx.x*blockDim.x + threadIdx.x;
  if (e >= NE) return;
  int d = dst[e];
  int pos = atomicAdd(&cursor[d], 1);
  colidx[rowptr[d] + pos] = src[e];
}

// ===== GEMM: C[N,M] = (Ah+Al)[N,Kp] @ (Bh+Bl)^T, bf16x3, m97-style =====
// 64x128 tile, 4 waves x (4m x 2n), global_load_lds staging, chunk swizzle.
// mode 0: plain fp32 -> C
// mode 1: GCN epilogue: relu(acc + bias) -> hi/lo bf16
// mode 2: fp32 -> C + fused per-head alpha dots -> as_o/ad_o
// mode 3: pooling head: atomicAdd(apre, tanh(acc+bias).w2); no C store
#define GBM 64
#define GBN 128
#define GBK 32
__global__ __launch_bounds__(256) void k_gemm_bf3(
    const unsigned short* __restrict__ Ah, const unsigned short* __restrict__ Al,
    const unsigned short* __restrict__ Bh, const unsigned short* __restrict__ Bl,
    float* __restrict__ C, int N, int Kp, int M, int mode,
    const float* __restrict__ bias, unsigned short* __restrict__ outH,
    unsigned short* __restrict__ outL,
    const float* __restrict__ a_s, const float* __restrict__ a_d,
    float* __restrict__ as_o, float* __restrict__ ad_o, int Cdim){
  __shared__ unsigned short AsH[GBM*GBK], AsL[GBM*GBK];
  __shared__ unsigned short BsH[GBN*GBK], BsL[GBN*GBK];
  __shared__ float sred[2][GBM][4];
  int gx = M / GBN;
  int gy = (N + GBM - 1) / GBM;
  const int G = 8;
  int bid = blockIdx.x;
  int full = gy / G;
  int bid_full = full * G * gx;
  int by, bx;
  if (bid < bid_full){
    int g = bid / (G*gx); int rem = bid % (G*gx);
    by = g*G + rem % G; bx = rem / G;
  } else {
    int rem = bid - bid_full; int rows = gy - full*G;
    by = full*G + rem % rows; bx = rem / rows;
  }
  int row0 = by * GBM, col0 = bx * GBN;
  int t = threadIdx.x;
  int w = t >> 6, L = t & 63;
  int lm = L & 15, lq = L >> 4;
  int wc = w * 32;

  int sr = L >> 2, sc = L & 3;
  int art = w*16 + sr;
  int ga  = (sc - ((art >> 1) & 3)) & 3;
  int agrow = min(row0 + art, N-1);
  int brt0 = w*16 + sr;
  int brt1 = (w+4)*16 + sr;
  int gb0 = (sc - ((brt0 >> 1) & 3)) & 3;
  int gb1 = (sc - ((brt1 >> 1) & 3)) & 3;
  int bgrow0 = col0 + brt0, bgrow1 = col0 + brt1;

  int rc = (lq + (lm >> 1)) & 3;
  int aoff[4], boff[2];
#pragma unroll
  for (int mi = 0; mi < 4; mi++) aoff[mi] = (mi*16 + lm)*32 + rc*8;
#pragma unroll
  for (int ni = 0; ni < 2; ni++) boff[ni] = (wc + ni*16 + lm)*32 + rc*8;

  f32x4 acc[4][2];
#pragma unroll
  for (int i = 0; i < 4; i++)
#pragma unroll
    for (int j = 0; j < 2; j++) acc[i][j] = (f32x4){0.f,0.f,0.f,0.f};

  int nk = Kp / GBK;
  for (int kt = 0; kt < nk; kt++){
    int k0 = kt * GBK;
    if (kt) __syncthreads();
    gl_lds16(&Ah[(size_t)agrow*Kp + k0 + ga*8],  &AsH[w*512]);
    gl_lds16(&Al[(size_t)agrow*Kp + k0 + ga*8],  &AsL[w*512]);
    gl_lds16(&Bh[(size_t)bgrow0*Kp + k0 + gb0*8], &BsH[w*512]);
    gl_lds16(&Bh[(size_t)bgrow1*Kp + k0 + gb1*8], &BsH[(w+4)*512]);
    gl_lds16(&Bl[(size_t)bgrow0*Kp + k0 + gb0*8], &BsL[w*512]);
    gl_lds16(&Bl[(size_t)bgrow1*Kp + k0 + gb1*8], &BsL[(w+4)*512]);
    __syncthreads();

    short8 ah[4], al[4], bh[2], bl[2];
#pragma unroll
    for (int mi = 0; mi < 4; mi++){
      ah[mi] = *(const short8*)&AsH[aoff[mi]];
      al[mi] = *(const short8*)&AsL[aoff[mi]];
    }
#pragma unroll
    for (int ni = 0; ni < 2; ni++){
      bh[ni] = *(const short8*)&BsH[boff[ni]];
      bl[ni] = *(const short8*)&BsL[boff[ni]];
    }
#pragma unroll
    for (int mi = 0; mi < 4; mi++)
#pragma unroll
      for (int ni = 0; ni < 2; ni++){
        acc[mi][ni] = __builtin_amdgcn_mfma_f32_16x16x32_bf16(ah[mi], bh[ni], acc[mi][ni], 0, 0, 0);
        acc[mi][ni] = __builtin_amdgcn_mfma_f32_16x16x32_bf16(ah[mi], bl[ni], acc[mi][ni], 0, 0, 0);
        acc[mi][ni] = __builtin_amdgcn_mfma_f32_16x16x32_bf16(al[mi], bh[ni], acc[mi][ni], 0, 0, 0);
      }
  }
  // ---- epilogue; C/D layout col=lane&15, row=(lane>>4)*4+reg ----
  if (mode == 1){
#pragma unroll
    for (int mi = 0; mi < 4; mi++)
#pragma unroll
      for (int ni = 0; ni < 2; ni++){
#pragma unroll
        for (int r = 0; r < 4; r++){
          int row = row0 + mi*16 + lq*4 + r;
          int col = col0 + wc + ni*16 + lm;
          if (row < N){
            float v = fmaxf(acc[mi][ni][r] + bias[col], 0.f);
            unsigned short hh, ll; split2(v, hh, ll);
            outH[(size_t)row*M + col] = hh;
            outL[(size_t)row*M + col] = ll;
          }
        }
      }
  } else if (mode != 3){
#pragma unroll
    for (int mi = 0; mi < 4; mi++)
#pragma unroll
      for (int ni = 0; ni < 2; ni++){
#pragma unroll
        for (int r = 0; r < 4; r++){
          int row = row0 + mi*16 + lq*4 + r;
          int col = col0 + wc + ni*16 + lm;
          if (row < N) C[(size_t)row*M + col] = acc[mi][ni][r];
        }
      }
  }
  if (mode == 2){
    float sA0 = a_s[col0 + wc + lm], sA1 = a_s[col0 + wc + 16 + lm];
    float dA0 = a_d[col0 + wc + lm], dA1 = a_d[col0 + wc + 16 + lm];
#pragma unroll
    for (int mi = 0; mi < 4; mi++)
#pragma unroll
      for (int r = 0; r < 4; r++){
        float vs = acc[mi][0][r]*sA0 + acc[mi][1][r]*sA1;
        float vd = acc[mi][0][r]*dA0 + acc[mi][1][r]*dA1;
#pragma unroll
        for (int o = 1; o <= 8; o <<= 1){
          vs += __shfl_xor(vs, o);
          vd += __shfl_xor(vd, o);
        }
        if (lm == 0){
          int row = mi*16 + lq*4 + r;
          sred[0][row][w] = vs;
          sred[1][row][w] = vd;
        }
      }
    __syncthreads();
    if (t < GBM){
      int n = row0 + t;
      if (n < N){
        int wph = Cdim >> 5;
        int nheads = 4 / wph;
        for (int g = 0; g < nheads; g++){
          float ss = 0.f, dd = 0.f;
          for (int q = 0; q < wph; q++){
            ss += sred[0][t][g*wph + q];
            dd += sred[1][t][g*wph + q];
          }
          int hd = (col0 + g*wph*32) / Cdim;
          as_o[n*NH + hd] = ss;
          ad_o[n*NH + hd] = dd;
        }
      }
    }
  } else if (mode == 3){
    float b0 = bias[col0 + wc + lm], b1v = bias[col0 + wc + 16 + lm];
    float w0v = a_s[col0 + wc + lm], w1v = a_s[col0 + wc + 16 + lm];
#pragma unroll
    for (int mi = 0; mi < 4; mi++)
#pragma unroll
      for (int r = 0; r < 4; r++){
        float v = tanhf(acc[mi][0][r] + b0)*w0v + tanhf(acc[mi][1][r] + b1v)*w1v;
#pragma unroll
        for (int o = 1; o <= 8; o <<= 1) v += __shfl_xor(v, o);
        if (lm == 0) sred[0][mi*16 + lq*4 + r][w] = v;
      }
    __syncthreads();
    if (t < GBM){
      int n = row0 + t;
      if (n < N){
        float s = sred[0][t][0] + sred[0][t][1] + sred[0][t][2] + sred[0][t][3];
        atomicAdd(&as_o[n], s);
      }
    }
  }
}

// ===== GCN pre-aggregation layer 0: reads fp32 x0 (36 cols) directly, pads to 64 =====
__global__ __launch_bounds__(256) void k_gcn_pre0(
    const float* __restrict__ x0, const float* __restrict__ dinv,
    const int* __restrict__ rowptr, const int* __restrict__ colidx,
    unsigned short* __restrict__ outH, unsigned short* __restrict__ outL){
  int t = threadIdx.x;
  int sub = t & 15;
  int n = blockIdx.x*16 + (t >> 4);
  if (n >= NN) return;
  int f0 = sub*4;                 // 0..60; cols >=36 are zero pad
  bool act = f0 < 36;             // f0=32 covers 32..35 (row stride 144B, 16B-aligned)
  int b = rowptr[n], e = rowptr[n+1];
  float dn = dinv[n];
  float4 a0 = make_float4(0,0,0,0), a1 = make_float4(0,0,0,0);
  float4 a2 = make_float4(0,0,0,0), a3 = make_float4(0,0,0,0);
  if (act){
    int j = b;
    for (; j + 3 < e; j += 4){
      int s0 = colidx[j], s1 = colidx[j+1], s2 = colidx[j+2], s3 = colidx[j+3];
      float w0 = dinv[s0], w1 = dinv[s1], w2 = dinv[s2], w3 = dinv[s3];
      float4 v0 = *(const float4*)&x0[(size_t)s0*36 + f0];
      float4 v1 = *(const float4*)&x0[(size_t)s1*36 + f0];
      float4 v2 = *(const float4*)&x0[(size_t)s2*36 + f0];
      float4 v3 = *(const float4*)&x0[(size_t)s3*36 + f0];
      fma4(a0, v0, w0*dn); fma4(a1, v1, w1*dn);
      fma4(a2, v2, w2*dn); fma4(a3, v3, w3*dn);
    }
    for (; j < e; j++){
      int s = colidx[j];
      float4 v = *(const float4*)&x0[(size_t)s*36 + f0];
      fma4(a0, v, dinv[s]*dn);
    }
  }
  float4 acc = make_float4(a0.x+a1.x+a2.x+a3.x, a0.y+a1.y+a2.y+a3.y,
                           a0.z+a1.z+a2.z+a3.z, a0.w+a1.w+a2.w+a3.w);
  if (act){
    float4 sv = *(const float4*)&x0[(size_t)n*36 + f0];
    float dn2 = dn*dn;
    acc.x += sv.x*dn2; acc.y += sv.y*dn2; acc.z += sv.z*dn2; acc.w += sv.w*dn2;
  }
  store_hl(outH, outL, (size_t)n*64 + f0, acc);
}

// ===== GCN pre-aggregation (layers 1..2): aggregate act at input dim =====
__global__ __launch_bounds__(256) void k_gcn_pre(
    const unsigned short* __restrict__ inH, const unsigned short* __restrict__ inL,
    const float* __restrict__ dinv,
    const int* __restrict__ rowptr, const int* __restrict__ colidx,
    unsigned short* __restrict__ outH, unsigned short* __restrict__ outL,
    int Kp, int nchunk){
  int bid = blockIdx.x;
  int chunk = bid % nchunk, grp = bid / nchunk;
  int t = threadIdx.x;
  int sub = t & 15;
  int n = grp*16 + (t >> 4);
  if (n >= NN) return;
  int f0 = chunk*64 + sub*4;
  int b = rowptr[n], e = rowptr[n+1];
  float dn = dinv[n];
  float4 a0 = make_float4(0,0,0,0), a1 = make_float4(0,0,0,0);
  float4 a2 = make_float4(0,0,0,0), a3 = make_float4(0,0,0,0);
  int j = b;
  for (; j + 3 < e; j += 4){
    int s0 = colidx[j], s1 = colidx[j+1], s2 = colidx[j+2], s3 = colidx[j+3];
    float w0 = dinv[s0], w1 = dinv[s1], w2 = dinv[s2], w3 = dinv[s3];
    float4 v0 = load_hl(inH, inL, (size_t)s0*Kp + f0);
    float4 v1 = load_hl(inH, inL, (size_t)s1*Kp + f0);
    float4 v2 = load_hl(inH, inL, (size_t)s2*Kp + f0);
    float4 v3 = load_hl(inH, inL, (size_t)s3*Kp + f0);
    fma4(a0, v0, w0*dn); fma4(a1, v1, w1*dn);
    fma4(a2, v2, w2*dn); fma4(a3, v3, w3*dn);
  }
  for (; j < e; j++){
    int s = colidx[j];
    float4 v = load_hl(inH, inL, (size_t)s*Kp + f0);
    fma4(a0, v, dinv[s]*dn);
  }
  float4 acc = make_float4(a0.x+a1.x+a2.x+a3.x, a0.y+a1.y+a2.y+a3.y,
                           a0.z+a1.z+a2.z+a3.z, a0.w+a1.w+a2.w+a3.w);
  float4 sv = load_hl(inH, inL, (size_t)n*Kp + f0);
  float dn2 = dn*dn;
  acc.x += sv.x*dn2; acc.y += sv.y*dn2; acc.z += sv.z*dn2; acc.w += sv.w*dn2;
  store_hl(outH, outL, (size_t)n*Kp + f0, acc);
}

// ===== GAT gather: fused online-softmax (flash-style), feature-chunked,
//       XCD-aligned, 4-way edge-unrolled =====
__global__ __launch_bounds__(256) void k_gat_gather(
    const float* __restrict__ hg,
    const unsigned short* __restrict__ inH, const unsigned short* __restrict__ inL,
    const int* __restrict__ rowptr, const int* __restrict__ colidx,
    const float* __restrict__ as_, const float* __restrict__ ad_,
    const float* __restrict__ ab,
    unsigned short* __restrict__ outH, unsigned short* __restrict__ outL,
    int M, int C, int nchunk){
  int bid = blockIdx.x;
  int chunk = bid % nchunk, grp = bid / nchunk;
  int t = threadIdx.x;
  int sub = t & 15;
  int n = grp*16 + (t >> 4);
  if (n >= NN) return;
  int f0 = chunk*64 + sub*4;
  int hd = f0 / C;
  int b = rowptr[n], e = rowptr[n+1];
  int ai = n*NH + hd;
  float adn = ad_[ai];
  float selflog = leakyf(as_[ai] + adn);
  float m = selflog, d = 1.f;
  float4 a0 = make_float4(0,0,0,0), a1 = make_float4(0,0,0,0);
  float4 a2 = make_float4(0,0,0,0), a3 = make_float4(0,0,0,0);
  int j = b;
  for (; j + 3 < e; j += 4){
    int s0 = colidx[j], s1 = colidx[j+1], s2 = colidx[j+2], s3 = colidx[j+3];
    float l0 = leakyf(as_[s0*NH + hd] + adn), l1 = leakyf(as_[s1*NH + hd] + adn);
    float l2 = leakyf(as_[s2*NH + hd] + adn), l3 = leakyf(as_[s3*NH + hd] + adn);
    float4 v0 = *(const float4*)&hg[(size_t)s0*M + f0];
    float4 v1 = *(const float4*)&hg[(size_t)s1*M + f0];
    float4 v2 = *(const float4*)&hg[(size_t)s2*M + f0];
    float4 v3 = *(const float4*)&hg[(size_t)s3*M + f0];
    float m4 = fmaxf(fmaxf(l0, l1), fmaxf(l2, l3));
    if (m4 > m){
      float sc = expf(m - m4);
      d *= sc; mul4(a0, sc); mul4(a1, sc); mul4(a2, sc); mul4(a3, sc);
      m = m4;
    }
    float w0 = expf(l0 - m), w1 = expf(l1 - m);
    float w2 = expf(l2 - m), w3 = expf(l3 - m);
    d += (w0 + w1) + (w2 + w3);
    fma4(a0, v0, w0); fma4(a1, v1, w1);
    fma4(a2, v2, w2); fma4(a3, v3, w3);
  }
  for (; j < e; j++){
    int s = colidx[j];
    float l = leakyf(as_[s*NH + hd] + adn);
    float4 v = *(const float4*)&hg[(size_t)s*M + f0];
    if (l > m){
      float sc = expf(m - l);
      d *= sc; mul4(a0, sc); mul4(a1, sc); mul4(a2, sc); mul4(a3, sc);
      m = l;
    }
    float ww = expf(l - m);
    d += ww;
    fma4(a0, v, ww);
  }
  float4 acc = make_float4(a0.x+a1.x+a2.x+a3.x, a0.y+a1.y+a2.y+a3.y,
                           a0.z+a1.z+a2.z+a3.z, a0.w+a1.w+a2.w+a3.w);
  float es = expf(selflog - m), inv = 1.f/d;
  float4 sv = *(const float4*)&hg[(size_t)n*M + f0];
  float4 hv = load_hl(inH, inL, (size_t)n*M + f0);
  float4 bb = *(const float4*)&ab[f0];
  float4 r = make_float4(
    hv.x + bb.x + (sv.x*es + acc.x)*inv,
    hv.y + bb.y + (sv.y*es + acc.y)*inv,
    hv.z + bb.z + (sv.z*es + acc.z)*inv,
    hv.w + bb.w + (sv.w*es + acc.w)*inv);
  store_hl(outH, outL, (size_t)n*M + f0, r);
}

// ================= attention pooling (fused prep + gather) =================
__global__ void k_pool(const unsigned short* __restrict__ xH, const unsigned short* __restrict__ xL,
                       const float* __restrict__ apre, const int* __restrict__ starts,
                       float* __restrict__ out){
  __shared__ float red[128];
  int g = blockIdx.x, t = threadIdx.x;
  int b = starts[g], e = starts[g+1];
  float m = -INFINITY;
  for (int n = b + t; n < e; n += 128) m = fmaxf(m, apre[n]);
  red[t] = m; __syncthreads();
  for (int o = 64; o > 0; o >>= 1){
    if (t < o) red[t] = fmaxf(red[t], red[t + o]);
    __syncthreads();
  }
  m = red[0]; __syncthreads();
  float s = 0.f;
  for (int n = b + t; n < e; n += 128) s += expf(apre[n] - m);
  red[t] = s; __syncthreads();
  for (int o = 64; o > 0; o >>= 1){
    if (t < o) red[t] += red[t + o];
    __syncthreads();
  }
  float inv = 1.f / (red[0] + 1e-8f);
  float4 sum = make_float4(0,0,0,0), wacc = make_float4(0,0,0,0);
  float4 mx = make_float4(-INFINITY,-INFINITY,-INFINITY,-INFINITY);
  for (int n = b; n < e; n++){
    float4 xv = load_hl(xH, xL, (size_t)n*DOUT + t*4);
    float p = expf(apre[n] - m) * inv;
    sum.x += xv.x; sum.y += xv.y; sum.z += xv.z; sum.w += xv.w;
    mx.x = fmaxf(mx.x, xv.x); mx.y = fmaxf(mx.y, xv.y);
    mx.z = fmaxf(mx.z, xv.z); mx.w = fmaxf(mx.w, xv.w);
    fma4(wacc, xv, p);
  }
  float ic = 1.f / fmaxf((float)(e - b), 1.f);
  float4* o = (float4*)(out + (size_t)g*4*DOUT);
  o[t]       = wacc;
  o[128 + t] = make_float4(sum.x*ic, sum.y*ic, sum.z*ic, sum.w*ic);
  o[256 + t] = mx;
  o[384 + t] = sum;
}

extern "C" void kernel_launch(void* const* d_in, const int* in_sizes, int n_in,
                              void* d_out, int out_size, void* d_ws, size_t ws_size,
                              hipStream_t stream) {
  const float* x0   = (const float*)d_in[0];
  const int*   ei   = (const int*)d_in[1];
  const int*   src  = ei;
  const int*   dst  = ei + NE;
  const int*   batch= (const int*)d_in[2];
  const float* gw[3]  = {(const float*)d_in[3],  (const float*)d_in[9],  (const float*)d_in[15]};
  const float* gb[3]  = {(const float*)d_in[4],  (const float*)d_in[10], (const float*)d_in[16]};
  const float* aw[3]  = {(const float*)d_in[5],  (const float*)d_in[11], (const float*)d_in[17]};
  const float* asw[3] = {(const float*)d_in[6],  (const float*)d_in[12], (const float*)d_in[18]};
  const float* adw[3] = {(const float*)d_in[7],  (const float*)d_in[13], (const float*)d_in[19]};
  const float* ab[3]  = {(const float*)d_in[8],  (const float*)d_in[14], (const float*)d_in[20]};
  const float* apw1 = (const float*)d_in[21];
  const float* apb1 = (const float*)d_in[22];
  const float* apw2 = (const float*)d_in[23];
  float* out = (float*)d_out;

  // ---- workspace carve ----
  char* p = (char*)d_ws;
  auto alloc = [&](size_t bytes) -> void* {
    void* r = (void*)p; p += (bytes + 255) & ~(size_t)255; return r;
  };
  float* f1 = (float*)alloc((size_t)NN*512*4);
  unsigned short* actH0 = (unsigned short*)alloc((size_t)NN*512*2);
  unsigned short* actL0 = (unsigned short*)alloc((size_t)NN*512*2);
  unsigned short* actH1 = (unsigned short*)alloc((size_t)NN*512*2);
  unsigned short* actL1 = (unsigned short*)alloc((size_t)NN*512*2);
  unsigned short* preH  = (unsigned short*)alloc((size_t)NN*256*2);
  unsigned short* preL  = (unsigned short*)alloc((size_t)NN*256*2);
  const int wK[7]  = {36, 128, 128, 256, 256, 512, 512};
  const int wM[7]  = {128, 128, 256, 256, 512, 512, 256};
  const int wKp[7] = {64, 128, 128, 256, 256, 512, 512};
  const float* wsrc[7] = {gw[0], aw[0], gw[1], aw[1], gw[2], aw[2], apw1};
  unsigned short* wTh[7]; unsigned short* wTl[7];
  for (int i = 0; i < 7; i++){
    size_t sz = (size_t)wM[i]*wKp[i]*2;
    wTh[i] = (unsigned short*)alloc(sz);
    wTl[i] = (unsigned short*)alloc(sz);
  }
  float* dinv = (float*)alloc(NN*4);
  float* as_  = (float*)alloc(NN*NH*4);
  float* ad_  = (float*)alloc(NN*NH*4);
  float* apre = (float*)alloc(NN*4);
  int* rowptr = (int*)alloc((NN+1)*4);
  int* colidx = (int*)alloc((size_t)NE*4);
  int* cnt    = (int*)alloc(NN*4);
  int* cursor = (int*)alloc(NN*4);
  int* starts = (int*)alloc((NB+1)*4);
  int* bsum   = (int*)alloc(SCAN_BLKS*4);

  // ---- conv descriptor (weights only) ----
  AllConv ac;
  int convTot = 0;
  for (int i = 0; i < 7; i++){
    ac.src[i] = wsrc[i]; ac.dh[i] = wTh[i]; ac.dl[i] = wTl[i];
    ac.K[i] = wK[i]; ac.Mm[i] = wM[i]; ac.Kp[i] = wKp[i];
    ac.tot[i] = wKp[i]*wM[i];
    convTot += ac.tot[i];
  }

  // ---- CSR build (count merged with conversions) -> scans -> fill ----
  hipMemsetAsync(cnt, 0, NN*sizeof(int), stream);
  int convBlks = (convTot + 255) / 256;
  k_count_conv<<<CNT_BLKS + convBlks, 256, 0, stream>>>(dst, cnt, ac, convTot);
  k_scan1<<<SCAN_BLKS, 256, 0, stream>>>(cnt, bsum, batch, starts);
  k_scan3<<<SCAN_BLKS, 256, 0, stream>>>(cnt, bsum, rowptr, dinv, cursor, apre);
  k_fill<<<(NE+255)/256, 256, 0, stream>>>(src, dst, rowptr, cursor, colidx);

  const int dims[4] = {36, 128, 256, 512};
  const int ngrp = (NN + 15) / 16;
  const unsigned short* curH = nullptr; const unsigned short* curL = nullptr;
  int wi = 0;
  for (int i = 0; i < 3; i++){
    int Kin = (i == 0) ? 64 : dims[i];
    int M = dims[i+1], C = M/NH;
    int nchunk_in = Kin / 64;
    int nchunk = M / 64;
    int nblk = (M/GBN) * ((NN+GBM-1)/GBM);
    // GCN: aggregate inputs at input dim, then GEMM with fused bias+relu+split epilogue
    if (i == 0){
      k_gcn_pre0<<<ngrp, 256, 0, stream>>>(x0, dinv, rowptr, colidx, preH, preL);
    } else {
      k_gcn_pre<<<nchunk_in*ngrp, 256, 0, stream>>>(curH, curL, dinv, rowptr, colidx,
                                                    preH, preL, Kin, nchunk_in);
    }
    k_gemm_bf3<<<nblk, 256, 0, stream>>>(preH, preL, wTh[wi], wTl[wi], f1, NN, wKp[wi], M,
                                         1, gb[i], actH0, actL0,
                                         nullptr, nullptr, nullptr, nullptr, C);
    wi++;
    // GAT: GEMM with fused alpha-dot epilogue, then fused online-softmax gather
    k_gemm_bf3<<<nblk, 256, 0, stream>>>(actH0, actL0, wTh[wi], wTl[wi], f1, NN, wKp[wi], M,
                                         2, nullptr, nullptr, nullptr,
                                         asw[i], adw[i], as_, ad_, C);
    wi++;
    k_gat_gather<<<nchunk*ngrp, 256, 0, stream>>>(f1, actH0, actL0, rowptr, colidx,
                                                  as_, ad_, ab[i],
                                                  actH1, actL1, M, C, nchunk);
    curH = actH1; curL = actL1;
  }

  // ---- pooling: GEMM with fused tanh-dot epilogue -> apre, then fused pool ----
  {
    int nblk = (256/GBN) * ((NN+GBM-1)/GBM);
    k_gemm_bf3<<<nblk, 256, 0, stream>>>(actH1, actL1, wTh[6], wTl[6], f1, NN, wKp[6], 256,
                                         3, apb1, nullptr, nullptr,
                                         apw2, nullptr, apre, nullptr, 64);
  }
  k_pool<<<NB, 128, 0, stream>>>(actH1, actL1, apre, starts, out);
}